// Round 9
// baseline (736.271 us; speedup 1.0000x reference)
//
#include <hip/hip_runtime.h>
#include <hip/hip_fp16.h>

#define N_DRUG 20000
#define N_DIS  10000
#define N_ATTR 2000
#define T_ATTR 8
#define E_MT   500000
#define E_HA   100000
#define E_LBL  200000
#define HC     128
#define NB     16   // chunk blocks per edge segment in CSR build

__device__ __forceinline__ float leakyf(float x) { return x >= 0.f ? x : 0.01f * x; }

// bf16 helpers: RNE encode, exact decode
__device__ __forceinline__ unsigned short f2bf(float f) {
  unsigned int u = __float_as_uint(f);
  return (unsigned short)((u + 0x7fffu + ((u >> 16) & 1u)) >> 16);
}
__device__ __forceinline__ float bflo(unsigned int u) { return __uint_as_float(u << 16); }
__device__ __forceinline__ float bfhi(unsigned int u) { return __uint_as_float(u & 0xffff0000u); }

// ---------------- CSR build ----------------
// 18 hist segments z: 0: mt_dst(10000) | 1: mt_src(20000) | 2-9: ha_dst[t](2000) | 10-17: ha_src[t](20000)
// chunk-hist bases (NB x bins per z):
#define HB0 0
#define HB1 160000
#define HB2(t) (480000 + (t) * 32000)
#define HB10(t) (736000 + (t) * 320000)
// wtab (f16 1/count per bin) bases = old cnt layout:
#define WB0 0
#define WB1 10000
#define WB2(t) (30000 + (t) * 2000)
#define WB10(t) (46000 + (t) * 20000)
#define WTOT 206000
// off layout: z0 flat (10001) | drug-merged d-major flat (d*9+s, 180001) | z2 per t (2001 each)
#define OFF_Z0 0
#define OFF_D  10001
#define OFF_Z2(t) (190002 + (t) * 2001)
#define OFF_TOT 206010

struct SegB { int bins; int hbase; int wbase; int obase; int ostride; };
__device__ __forceinline__ SegB segb(int z) {
  SegB s;
  if (z == 0)      { s.bins = N_DIS;  s.hbase = HB0;  s.wbase = WB0;  s.obase = OFF_Z0;    s.ostride = 1; }
  else if (z == 1) { s.bins = N_DRUG; s.hbase = HB1;  s.wbase = WB1;  s.obase = OFF_D;     s.ostride = 9; }
  else if (z < 10) { int t = z - 2;  s.bins = N_ATTR; s.hbase = HB2(t);  s.wbase = WB2(t);  s.obase = OFF_Z2(t);   s.ostride = 1; }
  else             { int t = z - 10; s.bins = N_DRUG; s.hbase = HB10(t); s.wbase = WB10(t); s.obase = OFF_D + 1 + t; s.ostride = 9; }
  return s;
}

// key/edge resolve: which edge list, gather-row source, packed-row offset, dest val array
struct SegE { const int* key; const int* oth; int n; int roff; int* val; };
__device__ __forceinline__ SegE sege(int z,
    const int* mt_src, const int* mt_dst, const int* ha_src, const int* ha_dst,
    int* vmd, int* vdrug, int* vhd) {
  SegE s;
  if (z == 0)      { s.key = mt_dst; s.oth = mt_src; s.n = E_MT; s.roff = 0; s.val = vmd; }
  else if (z == 1) { s.key = mt_src; s.oth = mt_dst; s.n = E_MT; s.roff = 0; s.val = vdrug; }
  else if (z < 10) { int t = z - 2;
    s.key = ha_dst + (size_t)t * E_HA; s.oth = ha_src + (size_t)t * E_HA; s.n = E_HA;
    s.roff = 0; s.val = vhd + (size_t)t * E_HA; }
  else { int t = z - 10;
    s.key = ha_src + (size_t)t * E_HA; s.oth = ha_dst + (size_t)t * E_HA; s.n = E_HA;
    s.roff = 10000 + t * N_ATTR; s.val = vdrug; }
  return s;
}

__global__ __launch_bounds__(256) void k_hist(
    const int* __restrict__ mt_src, const int* __restrict__ mt_dst,
    const int* __restrict__ ha_src, const int* __restrict__ ha_dst,
    int* __restrict__ hist) {
  SegB g = segb(blockIdx.z);
  SegE s = sege(blockIdx.z, mt_src, mt_dst, ha_src, ha_dst, nullptr, nullptr, nullptr);
  __shared__ int h[N_DRUG];
  int tid = threadIdx.x, b = blockIdx.x;
  for (int i = tid; i < g.bins; i += 256) h[i] = 0;
  __syncthreads();
  int ch = (s.n + NB - 1) / NB;
  int lo = b * ch, hi = min(s.n, lo + ch);
  for (int i = lo + tid; i < hi; i += 256) atomicAdd(&h[s.key[i]], 1);
  __syncthreads();
  int* hz = hist + g.hbase + (size_t)b * g.bins;
  for (int i = tid; i < g.bins; i += 256) hz[i] = h[i];
}

// thread = bin: chunk-block prefix; total -> off[obase+i*ostride]; f16(1/count) -> wtab
__global__ __launch_bounds__(256) void k_blkpfx(int* __restrict__ hist, int* __restrict__ off,
                                                unsigned short* __restrict__ wtab) {
  SegB g = segb(blockIdx.z);
  int i = blockIdx.x * 256 + threadIdx.x;
  if (i >= g.bins) return;
  int run = 0;
  #pragma unroll
  for (int b = 0; b < NB; b++) {
    int idx = g.hbase + b * g.bins + i;
    int v = hist[idx];
    hist[idx] = run;
    run += v;
  }
  off[g.obase + i * g.ostride] = run;
  __half hw = __float2half(1.0f / (float)(run > 0 ? run : 1));
  wtab[g.wbase + i] = __half_as_ushort(hw);
}

// 10 scan regions: z0 flat | drug-merged flat (180000) | 8x attr
__global__ __launch_bounds__(1024) void k_scan_bins(int* __restrict__ off) {
  int z = blockIdx.x;
  int base, L;
  if (z == 0)      { base = OFF_Z0; L = 10000; }
  else if (z == 1) { base = OFF_D;  L = 180000; }
  else             { int t = z - 2; base = OFF_Z2(t); L = 2000; }
  __shared__ int ssum[1024];
  int tid = threadIdx.x;
  int per = (L + 1023) >> 10;
  int lo = min(L, tid * per), hi = min(L, lo + per);
  int s = 0;
  for (int i = lo; i < hi; i++) s += off[base + i];
  ssum[tid] = s;
  __syncthreads();
  if (tid == 0) {
    int run = 0;
    for (int i = 0; i < 1024; i++) { int v = ssum[i]; ssum[i] = run; run += v; }
    off[base + L] = run;
  }
  __syncthreads();
  int run = ssum[tid];
  for (int i = lo; i < hi; i++) {
    int v = off[base + i];
    off[base + i] = run;
    run += v;
  }
}

__global__ __launch_bounds__(256) void k_fill2(
    const int* __restrict__ mt_src, const int* __restrict__ mt_dst,
    const int* __restrict__ ha_src, const int* __restrict__ ha_dst,
    const int* __restrict__ hist, const int* __restrict__ off,
    const unsigned short* __restrict__ wtab,
    int* vmd, int* vdrug, int* vhd) {
  SegB g = segb(blockIdx.z);
  SegE s = sege(blockIdx.z, mt_src, mt_dst, ha_src, ha_dst, vmd, vdrug, vhd);
  __shared__ int h[N_DRUG];
  __shared__ unsigned short hw[N_DRUG];
  int tid = threadIdx.x, b = blockIdx.x;
  const int* hz = hist + g.hbase + (size_t)b * g.bins;
  for (int i = tid; i < g.bins; i += 256) {
    h[i] = hz[i] + off[g.obase + i * g.ostride];
    hw[i] = wtab[g.wbase + i];
  }
  __syncthreads();
  int ch = (s.n + NB - 1) / NB;
  int lo = b * ch, hi = min(s.n, lo + ch);
  for (int i = lo + tid; i < hi; i += 256) {
    int k = s.key[i];
    int pos = atomicAdd(&h[k], 1);
    s.val[pos] = (int)(((unsigned int)hw[k] << 16) | (unsigned int)(s.oth[i] + s.roff));
  }
}

// ---------------- x_dis init ----------------
__global__ void k_dis0(const float* __restrict__ dx, const float* __restrict__ w,
                       const float* __restrict__ b, const float* __restrict__ emb,
                       float* __restrict__ out) {
  int i = blockIdx.x;
  int j = threadIdx.x;
  float s = b[j] + emb[(size_t)i * HC + j];
  #pragma unroll
  for (int k = 0; k < 10; k++) s += dx[i * 10 + k] * w[k * HC + j];
  out[(size_t)i * HC + j] = s;
}

// ---------------- Wc = rmt_wr + sum_t rha_wr ; biasc = rmt_bl + sum_t rha_bl ----------------
__global__ void k_wc(const float* __restrict__ wr_main, const float* __restrict__ wr_t,
                     const float* __restrict__ bl_main, const float* __restrict__ bl_t,
                     float* __restrict__ Wc, float* __restrict__ biasc) {
  int i = blockIdx.x * blockDim.x + threadIdx.x;
  if (i < HC * HC) {
    float s = wr_main[i];
    #pragma unroll
    for (int t = 0; t < T_ATTR; t++) s += wr_t[(size_t)t * HC * HC + i];
    Wc[i] = s;
  }
  if (i < HC) {
    float s = bl_main[i];
    #pragma unroll
    for (int t = 0; t < T_ATTR; t++) s += bl_t[t * HC + i];
    biasc[i] = s;
  }
}

// ---------------- f32 -> bf16 convert (4 elems/thread) ----------------
__global__ __launch_bounds__(256) void k_cvt(const float* __restrict__ src,
                                             unsigned short* __restrict__ dst, int n4) {
  int i = blockIdx.x * 256 + threadIdx.x;
  if (i >= n4) return;
  float4 v = ((const float4*)src)[i];
  uint2 w;
  w.x = (unsigned int)f2bf(v.x) | ((unsigned int)f2bf(v.y) << 16);
  w.y = (unsigned int)f2bf(v.z) | ((unsigned int)f2bf(v.w) << 16);
  ((uint2*)dst)[i] = w;
}

// ---------------- weighted gather accumulate: packed (f16 w | u16 row), bf16 table ----------------
__device__ __forceinline__ void gacc_w(const unsigned short* __restrict__ T, const int* __restrict__ val,
                                       int b, int e, int lane, float& ax, float& ay) {
  int i = b;
  for (; i + 8 <= e; i += 8) {
    unsigned int pv[8], rv[8];
    #pragma unroll
    for (int q = 0; q < 8; q++) pv[q] = ((const unsigned int*)val)[i + q];
    #pragma unroll
    for (int q = 0; q < 8; q++)
      rv[q] = ((const unsigned int*)(T + (size_t)(pv[q] & 0xffffu) * HC))[lane];
    #pragma unroll
    for (int q = 0; q < 8; q++) {
      float w = __half2float(__ushort_as_half((unsigned short)(pv[q] >> 16)));
      ax = fmaf(w, bflo(rv[q]), ax);
      ay = fmaf(w, bfhi(rv[q]), ay);
    }
  }
  for (; i < e; i++) {
    unsigned int pv = ((const unsigned int*)val)[i];
    unsigned int rv = ((const unsigned int*)(T + (size_t)(pv & 0xffffu) * HC))[lane];
    float w = __half2float(__ushort_as_half((unsigned short)(pv >> 16)));
    ax = fmaf(w, bflo(rv), ax);
    ay = fmaf(w, bfhi(rv), ay);
  }
}

// ---------------- mega segment-mean: uniform weighted-sum gathers ----------------
// wave w: [0,10000) m2dis (xdb) | [10000,30000) drug merged flat (Ytab) | [30000,46000) m2a (xdb)
__global__ __launch_bounds__(256) void k_seg_mega(
    const int* __restrict__ off,
    const int* __restrict__ vmd, const int* __restrict__ vdrug, const int* __restrict__ vhd,
    const unsigned short* __restrict__ xdb, const unsigned short* __restrict__ Ytab,
    float* __restrict__ m2dis, float* __restrict__ accd, float* __restrict__ m2a) {
  int lane = threadIdx.x & 63;
  int lane2 = lane * 2;
  int w = blockIdx.x * 4 + (threadIdx.x >> 6);
  if (w < N_DIS) {
    int lo = off[OFF_Z0 + w], hi = off[OFF_Z0 + w + 1];
    float ax = 0.f, ay = 0.f;
    gacc_w(xdb, vmd, lo, hi, lane, ax, ay);
    *(float2*)(m2dis + (size_t)w * HC + lane2) = make_float2(ax, ay);
  } else if (w < N_DIS + N_DRUG) {
    int d = w - N_DIS;
    int lo = off[OFF_D + d * 9], hi = off[OFF_D + d * 9 + 9];
    float ax = 0.f, ay = 0.f;
    gacc_w(Ytab, vdrug, lo, hi, lane, ax, ay);
    *(float2*)(accd + (size_t)d * HC + lane2) = make_float2(ax, ay);
  } else {
    int idx = w - (N_DIS + N_DRUG);
    int t = idx / N_ATTR, r = idx - t * N_ATTR;
    int lo = off[OFF_Z2(t) + r], hi = off[OFF_Z2(t) + r + 1];
    float ax = 0.f, ay = 0.f;
    gacc_w(xdb, vhd + (size_t)t * E_HA, lo, hi, lane, ax, ay);
    *(float2*)(m2a + ((size_t)t * N_ATTR + r) * HC + lane2) = make_float2(ax, ay);
  }
}

// ---------------- generalized batched GEMM ----------------
// D = [leaky]( A1@B1 [+ A2@B2] [+ ACC] [+ bias] ); bf16out: D is ushort* (RNE)
struct GemmJob {
  const float* A1; const float* B1;
  const float* A2; const float* B2;
  const float* bias; const float* ACC;
  float* D;
  int M; int leaky; int bf16out;
};
struct GemmJobs { GemmJob j[10]; };

__global__ __launch_bounds__(256) void k_gemm_multi(GemmJobs jobs) {
  GemmJob jb = jobs.j[blockIdx.z];
  int m0 = blockIdx.x * 64;
  if (m0 >= jb.M) return;
  __shared__ float As[16][68];
  __shared__ float Bs[16][132];
  int tid = threadIdx.x;
  int tx = tid & 31, ty = tid >> 5;
  float acc[8][4];
  #pragma unroll
  for (int i = 0; i < 8; i++)
    #pragma unroll
    for (int j = 0; j < 4; j++) acc[i][j] = 0.f;

  int K = jb.A2 ? 256 : 128;
  for (int kk = 0; kk < K; kk += 16) {
    const float* A = (kk < 128) ? jb.A1 : jb.A2;
    const float* B = (kk < 128) ? jb.B1 : jb.B2;
    int kb = kk & 127;
    {
      int r = tid >> 2, kq = (tid & 3) * 4;
      int gr = m0 + r;
      float4 v = make_float4(0.f, 0.f, 0.f, 0.f);
      if (gr < jb.M) v = *(const float4*)(A + (size_t)gr * HC + kb + kq);
      As[kq + 0][r] = v.x; As[kq + 1][r] = v.y; As[kq + 2][r] = v.z; As[kq + 3][r] = v.w;
    }
    #pragma unroll
    for (int i = 0; i < 2; i++) {
      int idx = i * 256 + tid;
      int k = idx >> 5, c = (idx & 31) * 4;
      *(float4*)&Bs[k][c] = *(const float4*)(B + (size_t)(kb + k) * HC + c);
    }
    __syncthreads();
    #pragma unroll
    for (int k = 0; k < 16; k++) {
      float4 a0 = *(const float4*)&As[k][ty * 8];
      float4 a1 = *(const float4*)&As[k][ty * 8 + 4];
      float4 bv = *(const float4*)&Bs[k][tx * 4];
      float av[8] = {a0.x, a0.y, a0.z, a0.w, a1.x, a1.y, a1.z, a1.w};
      float bb[4] = {bv.x, bv.y, bv.z, bv.w};
      #pragma unroll
      for (int i = 0; i < 8; i++)
        #pragma unroll
        for (int j = 0; j < 4; j++) acc[i][j] += av[i] * bb[j];
    }
    __syncthreads();
  }

  int c0 = tx * 4;
  float4 bs = make_float4(0.f, 0.f, 0.f, 0.f);
  if (jb.bias) bs = *(const float4*)(jb.bias + c0);
  #pragma unroll
  for (int i = 0; i < 8; i++) {
    int gr = m0 + ty * 8 + i;
    if (gr >= jb.M) break;
    float r0 = acc[i][0] + bs.x, r1 = acc[i][1] + bs.y, r2 = acc[i][2] + bs.z, r3 = acc[i][3] + bs.w;
    if (jb.ACC) {
      float4 ac = *(const float4*)(jb.ACC + (size_t)gr * HC + c0);
      r0 += ac.x; r1 += ac.y; r2 += ac.z; r3 += ac.w;
    }
    if (jb.leaky) { r0 = leakyf(r0); r1 = leakyf(r1); r2 = leakyf(r2); r3 = leakyf(r3); }
    if (jb.bf16out) {
      unsigned short* Db = (unsigned short*)jb.D;
      uint2 w;
      w.x = (unsigned int)f2bf(r0) | ((unsigned int)f2bf(r1) << 16);
      w.y = (unsigned int)f2bf(r2) | ((unsigned int)f2bf(r3) << 16);
      *(uint2*)(Db + (size_t)gr * 128 + c0) = w;
    } else {
      float4 rv = make_float4(r0, r1, r2, r3);
      *(float4*)(jb.D + (size_t)gr * 128 + c0) = rv;
    }
  }
}

// ---------------- classifier head GEMMs ----------------
struct G64Job { const float* X; const float* W; const float* bias; float* D; int M; };

__global__ __launch_bounds__(256) void k_gemm64(G64Job j0, G64Job j1) {
  G64Job jb = blockIdx.z ? j1 : j0;
  int m0 = blockIdx.x * 64;
  if (m0 >= jb.M) return;
  __shared__ float As[16][68];
  __shared__ float Bs[16][68];
  int tid = threadIdx.x;
  int tx = tid & 15, ty = tid >> 4;
  float acc[4][4];
  #pragma unroll
  for (int i = 0; i < 4; i++)
    #pragma unroll
    for (int j = 0; j < 4; j++) acc[i][j] = 0.f;

  for (int kk = 0; kk < 128; kk += 16) {
    {
      int r = tid >> 2, kq = (tid & 3) * 4;
      int gr = m0 + r;
      float4 v = make_float4(0.f, 0.f, 0.f, 0.f);
      if (gr < jb.M) v = *(const float4*)(jb.X + (size_t)gr * HC + kk + kq);
      As[kq + 0][r] = v.x; As[kq + 1][r] = v.y; As[kq + 2][r] = v.z; As[kq + 3][r] = v.w;
    }
    {
      int k = tid >> 4, c = (tid & 15) * 4;
      *(float4*)&Bs[k][c] = *(const float4*)(jb.W + (size_t)(kk + k) * 64 + c);
    }
    __syncthreads();
    #pragma unroll
    for (int k = 0; k < 16; k++) {
      float4 a = *(const float4*)&As[k][ty * 4];
      float4 b = *(const float4*)&Bs[k][tx * 4];
      float av[4] = {a.x, a.y, a.z, a.w};
      float bb[4] = {b.x, b.y, b.z, b.w};
      #pragma unroll
      for (int i = 0; i < 4; i++)
        #pragma unroll
        for (int j = 0; j < 4; j++) acc[i][j] += av[i] * bb[j];
    }
    __syncthreads();
  }
  float4 bs = make_float4(0.f, 0.f, 0.f, 0.f);
  if (jb.bias) bs = *(const float4*)(jb.bias + tx * 4);
  #pragma unroll
  for (int i = 0; i < 4; i++) {
    int gr = m0 + ty * 4 + i;
    if (gr < jb.M) {
      float4 r = make_float4(acc[i][0] + bs.x, acc[i][1] + bs.y, acc[i][2] + bs.z, acc[i][3] + bs.w);
      *(float4*)(jb.D + (size_t)gr * 64 + tx * 4) = r;
    }
  }
}

// ---------------- per-edge tail MLP (LDS weights, fully unrolled, registers only) ----------------
__global__ __launch_bounds__(256) void k_tail(
    const float* __restrict__ U, const float* __restrict__ V,
    const int* __restrict__ es, const int* __restrict__ ed,
    const float* __restrict__ cw1, const float* __restrict__ cb1,
    const float* __restrict__ cw2, const float* __restrict__ cb2,
    const float* __restrict__ cw3, const float* __restrict__ cb3,
    const float* __restrict__ cw4, const float* __restrict__ cb4,
    float* __restrict__ out, int n) {
  __shared__ float w1[64 * 32];
  __shared__ float w2[32 * 16];
  __shared__ float w3[16 * 8];
  __shared__ float w4[8];
  __shared__ float b1[32], b2[16], b3[8];
  int tid = threadIdx.x;
  #pragma unroll
  for (int q = 0; q < 8; q++) w1[tid + q * 256] = cw1[tid + q * 256];
  #pragma unroll
  for (int q = 0; q < 2; q++) w2[tid + q * 256] = cw2[tid + q * 256];
  if (tid < 128) w3[tid] = cw3[tid];
  if (tid < 8)  w4[tid] = cw4[tid];
  if (tid < 32) b1[tid] = cb1[tid];
  if (tid < 16) b2[tid] = cb2[tid];
  if (tid < 8)  b3[tid] = cb3[tid];
  __syncthreads();
  int i = blockIdx.x * 256 + tid;
  if (i >= n) return;
  int s = es[i], d = ed[i];
  const float4* up = (const float4*)(U + (size_t)s * 64);
  const float4* vp = (const float4*)(V + (size_t)d * 64);
  float h1[64];
  #pragma unroll
  for (int q = 0; q < 16; q++) {
    float4 a = up[q], b = vp[q];
    h1[4 * q + 0] = leakyf(a.x + b.x);
    h1[4 * q + 1] = leakyf(a.y + b.y);
    h1[4 * q + 2] = leakyf(a.z + b.z);
    h1[4 * q + 3] = leakyf(a.w + b.w);
  }
  float h2[32];
  #pragma unroll
  for (int j = 0; j < 32; j++) h2[j] = b1[j];
  #pragma unroll
  for (int k = 0; k < 64; k++) {
    float hv = h1[k];
    #pragma unroll
    for (int jq = 0; jq < 8; jq++) {
      float4 w = *(const float4*)&w1[k * 32 + jq * 4];
      h2[4 * jq + 0] = fmaf(hv, w.x, h2[4 * jq + 0]);
      h2[4 * jq + 1] = fmaf(hv, w.y, h2[4 * jq + 1]);
      h2[4 * jq + 2] = fmaf(hv, w.z, h2[4 * jq + 2]);
      h2[4 * jq + 3] = fmaf(hv, w.w, h2[4 * jq + 3]);
    }
  }
  float h3[16];
  #pragma unroll
  for (int j = 0; j < 16; j++) h3[j] = b2[j];
  #pragma unroll
  for (int k = 0; k < 32; k++) {
    float hv = leakyf(h2[k]);
    #pragma unroll
    for (int jq = 0; jq < 4; jq++) {
      float4 w = *(const float4*)&w2[k * 16 + jq * 4];
      h3[4 * jq + 0] = fmaf(hv, w.x, h3[4 * jq + 0]);
      h3[4 * jq + 1] = fmaf(hv, w.y, h3[4 * jq + 1]);
      h3[4 * jq + 2] = fmaf(hv, w.z, h3[4 * jq + 2]);
      h3[4 * jq + 3] = fmaf(hv, w.w, h3[4 * jq + 3]);
    }
  }
  float h4[8];
  #pragma unroll
  for (int j = 0; j < 8; j++) h4[j] = b3[j];
  #pragma unroll
  for (int k = 0; k < 16; k++) {
    float hv = leakyf(h3[k]);
    #pragma unroll
    for (int jq = 0; jq < 2; jq++) {
      float4 w = *(const float4*)&w3[k * 8 + jq * 4];
      h4[4 * jq + 0] = fmaf(hv, w.x, h4[4 * jq + 0]);
      h4[4 * jq + 1] = fmaf(hv, w.y, h4[4 * jq + 1]);
      h4[4 * jq + 2] = fmaf(hv, w.z, h4[4 * jq + 2]);
      h4[4 * jq + 3] = fmaf(hv, w.w, h4[4 * jq + 3]);
    }
  }
  float p = cb4[0];
  #pragma unroll
  for (int k = 0; k < 8; k++) p = fmaf(leakyf(h4[k]), w4[k], p);
  out[i] = p;
}

extern "C" void kernel_launch(void* const* d_in, const int* in_sizes, int n_in,
                              void* d_out, int out_size, void* d_ws, size_t ws_size,
                              hipStream_t stream) {
  const float* disease_x   = (const float*)d_in[0];
  const float* drug_emb    = (const float*)d_in[1];
  const float* disease_emb = (const float*)d_in[2];
  const float* attr_emb    = (const float*)d_in[3];
  const float* dis_lin_w   = (const float*)d_in[4];
  const float* dis_lin_b   = (const float*)d_in[5];
  const float* mt_wl  = (const float*)d_in[6];
  const float* mt_bl  = (const float*)d_in[7];
  const float* mt_wr  = (const float*)d_in[8];
  const float* rmt_wl = (const float*)d_in[9];
  const float* rmt_bl = (const float*)d_in[10];
  const float* rmt_wr = (const float*)d_in[11];
  const float* ha_wl  = (const float*)d_in[12];
  const float* ha_bl  = (const float*)d_in[13];
  const float* ha_wr  = (const float*)d_in[14];
  const float* rha_wl = (const float*)d_in[15];
  const float* rha_bl = (const float*)d_in[16];
  const float* rha_wr = (const float*)d_in[17];
  const float* cw0 = (const float*)d_in[18];
  const float* cb0 = (const float*)d_in[19];
  const float* cw1 = (const float*)d_in[20];
  const float* cb1 = (const float*)d_in[21];
  const float* cw2 = (const float*)d_in[22];
  const float* cb2 = (const float*)d_in[23];
  const float* cw3 = (const float*)d_in[24];
  const float* cb3 = (const float*)d_in[25];
  const float* cw4 = (const float*)d_in[26];
  const float* cb4 = (const float*)d_in[27];
  const int* mt_src = (const int*)d_in[28];
  const int* mt_dst = (const int*)d_in[29];
  const int* ha_src = (const int*)d_in[30];
  const int* ha_dst = (const int*)d_in[31];
  const int* ell_src = (const int*)d_in[32];
  const int* ell_dst = (const int*)d_in[33];
  float* out = (float*)d_out;

  const long long ATTR_S = (long long)N_ATTR * HC;
  const long long W_S = HC * HC;

  // ---------- workspace carve ----------
  float* fws = (float*)d_ws;
  size_t o = 0;
  float* x_drug = fws + o; o += (size_t)N_DRUG * HC;
  float* x_dis  = fws + o; o += (size_t)N_DIS * HC;
  float* x_attr = fws + o; o += (size_t)T_ATTR * N_ATTR * HC;
  float* m2dis  = fws + o; o += (size_t)N_DIS * HC;          // | m2dis+m2a (3.328M floats)
  float* m2a    = fws + o; o += (size_t)T_ATTR * N_ATTR * HC;// | overlaid by hist (3.296M ints)
  float* accd   = fws + o; o += (size_t)N_DRUG * HC;
  float* Wc     = fws + o; o += HC * HC;
  float* biasc  = fws + o; o += HC;
  float* Ucls   = fws + o; o += (size_t)N_DRUG * 64;
  float* Vcls   = fws + o; o += (size_t)N_DIS * 64;
  // bf16 gather tables: Ytab = concat(Ydisb[10000], Yattrb[8x2000]) must be contiguous
  unsigned short* xdb    = (unsigned short*)(fws + o);
  unsigned short* Ytab   = xdb + (size_t)N_DRUG * HC;
  unsigned short* Ydisb  = Ytab;
  unsigned short* Yattrb = Ytab + (size_t)N_DIS * HC;
  o += ((size_t)N_DRUG * HC + (size_t)N_DIS * HC + (size_t)T_ATTR * N_ATTR * HC) / 2;
  int* iws = (int*)(fws + o);
  int* off = iws;                               // OFF_TOT = 206010
  int* vmd   = off + OFF_TOT;                   // 500000 (m2dis edges)
  int* vdrug = vmd + E_MT;                      // 1300000 (drug merged edges)
  int* vhd   = vdrug + (E_MT + T_ATTR * E_HA);  // 800000 (m2a edges)
  unsigned short* wtab = (unsigned short*)(vhd + (size_t)T_ATTR * E_HA); // 206000 ushorts
  int* hist = (int*)m2dis;   // 3.296M ints over m2dis+m2a (dead during CSR build)

  dim3 b256(256);
  // ---------- CSR build ----------
  k_hist<<<dim3(NB, 1, 18), b256, 0, stream>>>(mt_src, mt_dst, ha_src, ha_dst, hist);
  k_blkpfx<<<dim3((N_DRUG + 255) / 256, 1, 18), b256, 0, stream>>>(hist, off, wtab);
  k_scan_bins<<<10, 1024, 0, stream>>>(off);
  k_fill2<<<dim3(NB, 1, 18), b256, 0, stream>>>(mt_src, mt_dst, ha_src, ha_dst, hist, off, wtab,
                                                vmd, vdrug, vhd);

  // ---------- node init ----------
  k_dis0<<<N_DIS, 128, 0, stream>>>(disease_x, dis_lin_w, dis_lin_b, disease_emb, x_dis);

  for (int l = 0; l < 2; l++) {
    const float* xd = l ? (const float*)x_drug : drug_emb;
    const float* xa = l ? (const float*)x_attr : attr_emb;
    const float* mt_wl_l  = mt_wl  + (size_t)l * W_S;
    const float* mt_bl_l  = mt_bl  + (size_t)l * HC;
    const float* mt_wr_l  = mt_wr  + (size_t)l * W_S;
    const float* rmt_wl_l = rmt_wl + (size_t)l * W_S;
    const float* ha_wl_l  = ha_wl  + (size_t)l * T_ATTR * W_S;
    const float* ha_bl_l  = ha_bl  + (size_t)l * T_ATTR * HC;
    const float* ha_wr_l  = ha_wr  + (size_t)l * T_ATTR * W_S;
    const float* rha_wl_l = rha_wl + (size_t)l * T_ATTR * W_S;

    k_wc<<<64, 256, 0, stream>>>(rmt_wr + (size_t)l * W_S, rha_wr + (size_t)l * T_ATTR * W_S,
                                 rmt_bl + (size_t)l * HC, rha_bl + (size_t)l * T_ATTR * HC, Wc, biasc);

    // pre-transform GEMMs on the small side -> bf16 tables for the gather
    {
      GemmJobs J{};
      J.j[0] = {x_dis, rmt_wl_l, nullptr, nullptr, nullptr, nullptr, (float*)Ydisb, N_DIS, 0, 1};
      for (int t = 0; t < T_ATTR; t++)
        J.j[1 + t] = {xa + (size_t)t * ATTR_S, rha_wl_l + (size_t)t * W_S,
                      nullptr, nullptr, nullptr, nullptr,
                      (float*)(Yattrb + (size_t)t * ATTR_S), N_ATTR, 0, 1};
      k_gemm_multi<<<dim3((N_DIS + 63) / 64, 1, 9), b256, 0, stream>>>(J);
    }
    // xd -> bf16
    k_cvt<<<dim3((N_DRUG * HC / 4 + 255) / 256), b256, 0, stream>>>(xd, xdb, N_DRUG * HC / 4);

    // all gathers of this layer (weighted sums, bf16 tables, f32 accumulate)
    k_seg_mega<<<dim3((46000 + 3) / 4, 1, 1), b256, 0, stream>>>(
        off, vmd, vdrug, vhd, xdb, Ytab, m2dis, accd, m2a);

    // combine GEMMs (f32)
    {
      GemmJobs J{};
      J.j[0] = {xd, Wc, nullptr, nullptr, biasc, accd, x_drug, N_DRUG, 1, 0};
      J.j[1] = {m2dis, mt_wl_l, x_dis, mt_wr_l, mt_bl_l, nullptr, x_dis, N_DIS, 1, 0};
      for (int t = 0; t < T_ATTR; t++)
        J.j[2 + t] = {m2a + (size_t)t * ATTR_S, ha_wl_l + (size_t)t * W_S,
                      xa + (size_t)t * ATTR_S, ha_wr_l + (size_t)t * W_S,
                      ha_bl_l + (size_t)t * HC, nullptr, x_attr + (size_t)t * ATTR_S, N_ATTR, 1, 0};
      k_gemm_multi<<<dim3((N_DRUG + 63) / 64, 1, 10), b256, 0, stream>>>(J);
    }
  }

  // ---------- classifier: U/V precompute then per-edge tail ----------
  {
    G64Job ju = {x_drug, cw0, cb0, Ucls, N_DRUG};
    G64Job jv = {x_dis, cw0 + 128 * 64, nullptr, Vcls, N_DIS};
    k_gemm64<<<dim3((N_DRUG + 63) / 64, 1, 2), b256, 0, stream>>>(ju, jv);
    k_tail<<<dim3((E_LBL + 255) / 256, 1, 1), b256, 0, stream>>>(
        Ucls, Vcls, ell_src, ell_dst,
        cw1, cb1, cw2, cb2, cw3, cb3, cw4, cb4, out, E_LBL);
  }
}

// Round 10
// 478.744 us; speedup vs baseline: 1.5379x; 1.5379x over previous
//
#include <hip/hip_runtime.h>
#include <hip/hip_fp16.h>

#define N_DRUG 20000
#define N_DIS  10000
#define N_ATTR 2000
#define T_ATTR 8
#define E_MT   500000
#define E_HA   100000
#define E_LBL  200000
#define HC     128
#define NB     16   // chunk blocks per edge segment in CSR build

__device__ __forceinline__ float leakyf(float x) { return x >= 0.f ? x : 0.01f * x; }

// bf16 helpers: RNE encode, exact decode
__device__ __forceinline__ unsigned short f2bf(float f) {
  unsigned int u = __float_as_uint(f);
  return (unsigned short)((u + 0x7fffu + ((u >> 16) & 1u)) >> 16);
}
__device__ __forceinline__ float bflo(unsigned int u) { return __uint_as_float(u << 16); }
__device__ __forceinline__ float bfhi(unsigned int u) { return __uint_as_float(u & 0xffff0000u); }

// ---------------- CSR build ----------------
// 18 hist segments z: 0: mt_dst(10000) | 1: mt_src(20000) | 2-9: ha_dst[t](2000) | 10-17: ha_src[t](20000)
#define HB0 0
#define HB1 160000
#define HB2(t) (480000 + (t) * 32000)
#define HB10(t) (736000 + (t) * 320000)
// wtab (f16 1/count per bin) bases:
#define WB0 0
#define WB1 10000
#define WB2(t) (30000 + (t) * 2000)
#define WB10(t) (46000 + (t) * 20000)
#define WTOT 206000
// off layout: z0 flat (10001) | drug-merged d-major flat (d*9+s, 180001) | z2 per t (2001 each)
#define OFF_Z0 0
#define OFF_D  10001
#define OFF_Z2(t) (190002 + (t) * 2001)
#define OFF_TOT 206010
// scan geometry: 10 regions, 2048-elem chunks, <=88 chunks (region 1: 180000)
#define SCH 2048
#define SMAXC 128

struct SegB { int bins; int hbase; int wbase; int obase; int ostride; };
__device__ __forceinline__ SegB segb(int z) {
  SegB s;
  if (z == 0)      { s.bins = N_DIS;  s.hbase = HB0;  s.wbase = WB0;  s.obase = OFF_Z0;    s.ostride = 1; }
  else if (z == 1) { s.bins = N_DRUG; s.hbase = HB1;  s.wbase = WB1;  s.obase = OFF_D;     s.ostride = 9; }
  else if (z < 10) { int t = z - 2;  s.bins = N_ATTR; s.hbase = HB2(t);  s.wbase = WB2(t);  s.obase = OFF_Z2(t);   s.ostride = 1; }
  else             { int t = z - 10; s.bins = N_DRUG; s.hbase = HB10(t); s.wbase = WB10(t); s.obase = OFF_D + 1 + t; s.ostride = 9; }
  return s;
}

struct SegE { const int* key; const int* oth; int n; int roff; int* val; };
__device__ __forceinline__ SegE sege(int z,
    const int* mt_src, const int* mt_dst, const int* ha_src, const int* ha_dst,
    int* vmd, int* vdrug, int* vhd) {
  SegE s;
  if (z == 0)      { s.key = mt_dst; s.oth = mt_src; s.n = E_MT; s.roff = 0; s.val = vmd; }
  else if (z == 1) { s.key = mt_src; s.oth = mt_dst; s.n = E_MT; s.roff = 0; s.val = vdrug; }
  else if (z < 10) { int t = z - 2;
    s.key = ha_dst + (size_t)t * E_HA; s.oth = ha_src + (size_t)t * E_HA; s.n = E_HA;
    s.roff = 0; s.val = vhd + (size_t)t * E_HA; }
  else { int t = z - 10;
    s.key = ha_src + (size_t)t * E_HA; s.oth = ha_dst + (size_t)t * E_HA; s.n = E_HA;
    s.roff = 10000 + t * N_ATTR; s.val = vdrug; }
  return s;
}

__global__ __launch_bounds__(256) void k_hist(
    const int* __restrict__ mt_src, const int* __restrict__ mt_dst,
    const int* __restrict__ ha_src, const int* __restrict__ ha_dst,
    int* __restrict__ hist) {
  SegB g = segb(blockIdx.z);
  SegE s = sege(blockIdx.z, mt_src, mt_dst, ha_src, ha_dst, nullptr, nullptr, nullptr);
  __shared__ int h[N_DRUG];
  int tid = threadIdx.x, b = blockIdx.x;
  for (int i = tid; i < g.bins; i += 256) h[i] = 0;
  __syncthreads();
  int ch = (s.n + NB - 1) / NB;
  int lo = b * ch, hi = min(s.n, lo + ch);
  for (int i = lo + tid; i < hi; i += 256) atomicAdd(&h[s.key[i]], 1);
  __syncthreads();
  int* hz = hist + g.hbase + (size_t)b * g.bins;
  for (int i = tid; i < g.bins; i += 256) hz[i] = h[i];
}

// thread = bin: chunk-block prefix; total -> off[obase+i*ostride]; f16(1/count) -> wtab
__global__ __launch_bounds__(256) void k_blkpfx(int* __restrict__ hist, int* __restrict__ off,
                                                unsigned short* __restrict__ wtab) {
  SegB g = segb(blockIdx.z);
  int i = blockIdx.x * 256 + threadIdx.x;
  if (i >= g.bins) return;
  int run = 0;
  #pragma unroll
  for (int b = 0; b < NB; b++) {
    int idx = g.hbase + b * g.bins + i;
    int v = hist[idx];
    hist[idx] = run;
    run += v;
  }
  off[g.obase + i * g.ostride] = run;
  __half hw = __float2half(1.0f / (float)(run > 0 ? run : 1));
  wtab[g.wbase + i] = __half_as_ushort(hw);
}

// ---- 2-level parallel scan over 10 regions of off ----
__device__ __forceinline__ void scan_region(int r, int& base, int& L) {
  if (r == 0)      { base = OFF_Z0; L = 10000; }
  else if (r == 1) { base = OFF_D;  L = 180000; }
  else             { int t = r - 2; base = OFF_Z2(t); L = 2000; }
}

// pass 1: in-chunk exclusive scan (2048 = 256 threads x 8), chunk total -> csum[r*SMAXC+c]
__global__ __launch_bounds__(256) void k_scan_l1(int* __restrict__ off, int* __restrict__ csum) {
  int base, L;
  scan_region(blockIdx.y, base, L);
  int c = blockIdx.x;
  int c0 = c * SCH;
  if (c0 >= L) { if (threadIdx.x == 0 && c0 == 0) {} return; }
  int tid = threadIdx.x;
  int i0 = c0 + tid * 8;
  int v[8];
  int s = 0;
  #pragma unroll
  for (int j = 0; j < 8; j++) {
    int i = i0 + j;
    v[j] = (i < L) ? off[base + i] : 0;
    s += v[j];
  }
  __shared__ int ssum[256];
  ssum[tid] = s;
  __syncthreads();
  if (tid == 0) {
    int run = 0;
    #pragma unroll 8
    for (int i = 0; i < 256; i++) { int x = ssum[i]; ssum[i] = run; run += x; }
    csum[blockIdx.y * SMAXC + c] = run;
  }
  __syncthreads();
  int run = ssum[tid];
  #pragma unroll
  for (int j = 0; j < 8; j++) {
    int i = i0 + j;
    if (i < L) { off[base + i] = run; run += v[j]; }
  }
}

// pass 2: per region, serial exclusive scan of chunk totals; sentinel off[base+L] = total
__global__ void k_scan_l2(int* __restrict__ off, int* __restrict__ csum) {
  int r = blockIdx.x;
  int base, L;
  scan_region(r, base, L);
  if (threadIdx.x == 0) {
    int nc = (L + SCH - 1) / SCH;
    int run = 0;
    for (int c = 0; c < nc; c++) {
      int v = csum[r * SMAXC + c];
      csum[r * SMAXC + c] = run;
      run += v;
    }
    off[base + L] = run;
  }
}

// pass 3: add chunk prefix
__global__ __launch_bounds__(256) void k_scan_l3(int* __restrict__ off, const int* __restrict__ csum) {
  int base, L;
  scan_region(blockIdx.y, base, L);
  int c = blockIdx.x;
  int c0 = c * SCH;
  if (c0 >= L || c == 0) return;
  int add = csum[blockIdx.y * SMAXC + c];
  int i0 = c0 + threadIdx.x * 8;
  #pragma unroll
  for (int j = 0; j < 8; j++) {
    int i = i0 + j;
    if (i < L) off[base + i] += add;
  }
}

__global__ __launch_bounds__(256) void k_fill2(
    const int* __restrict__ mt_src, const int* __restrict__ mt_dst,
    const int* __restrict__ ha_src, const int* __restrict__ ha_dst,
    const int* __restrict__ hist, const int* __restrict__ off,
    const unsigned short* __restrict__ wtab,
    int* vmd, int* vdrug, int* vhd) {
  SegB g = segb(blockIdx.z);
  SegE s = sege(blockIdx.z, mt_src, mt_dst, ha_src, ha_dst, vmd, vdrug, vhd);
  __shared__ int h[N_DRUG];
  __shared__ unsigned short hw[N_DRUG];
  int tid = threadIdx.x, b = blockIdx.x;
  const int* hz = hist + g.hbase + (size_t)b * g.bins;
  for (int i = tid; i < g.bins; i += 256) {
    h[i] = hz[i] + off[g.obase + i * g.ostride];
    hw[i] = wtab[g.wbase + i];
  }
  __syncthreads();
  int ch = (s.n + NB - 1) / NB;
  int lo = b * ch, hi = min(s.n, lo + ch);
  for (int i = lo + tid; i < hi; i += 256) {
    int k = s.key[i];
    int pos = atomicAdd(&h[k], 1);
    s.val[pos] = (int)(((unsigned int)hw[k] << 16) | (unsigned int)(s.oth[i] + s.roff));
  }
}

// ---------------- x_dis init ----------------
__global__ void k_dis0(const float* __restrict__ dx, const float* __restrict__ w,
                       const float* __restrict__ b, const float* __restrict__ emb,
                       float* __restrict__ out) {
  int i = blockIdx.x;
  int j = threadIdx.x;
  float s = b[j] + emb[(size_t)i * HC + j];
  #pragma unroll
  for (int k = 0; k < 10; k++) s += dx[i * 10 + k] * w[k * HC + j];
  out[(size_t)i * HC + j] = s;
}

// ---------------- Wc = rmt_wr + sum_t rha_wr ; biasc = rmt_bl + sum_t rha_bl ----------------
__global__ void k_wc(const float* __restrict__ wr_main, const float* __restrict__ wr_t,
                     const float* __restrict__ bl_main, const float* __restrict__ bl_t,
                     float* __restrict__ Wc, float* __restrict__ biasc) {
  int i = blockIdx.x * blockDim.x + threadIdx.x;
  if (i < HC * HC) {
    float s = wr_main[i];
    #pragma unroll
    for (int t = 0; t < T_ATTR; t++) s += wr_t[(size_t)t * HC * HC + i];
    Wc[i] = s;
  }
  if (i < HC) {
    float s = bl_main[i];
    #pragma unroll
    for (int t = 0; t < T_ATTR; t++) s += bl_t[t * HC + i];
    biasc[i] = s;
  }
}

// ---------------- f32 -> bf16 convert (4 elems/thread) ----------------
__global__ __launch_bounds__(256) void k_cvt(const float* __restrict__ src,
                                             unsigned short* __restrict__ dst, int n4) {
  int i = blockIdx.x * 256 + threadIdx.x;
  if (i >= n4) return;
  float4 v = ((const float4*)src)[i];
  uint2 w;
  w.x = (unsigned int)f2bf(v.x) | ((unsigned int)f2bf(v.y) << 16);
  w.y = (unsigned int)f2bf(v.z) | ((unsigned int)f2bf(v.w) << 16);
  ((uint2*)dst)[i] = w;
}

// ---------------- weighted gather accumulate: packed (f16 w | u16 row), bf16 table ----------------
__device__ __forceinline__ void gacc_w(const unsigned short* __restrict__ T, const int* __restrict__ val,
                                       int b, int e, int lane, float& ax, float& ay) {
  int i = b;
  for (; i + 8 <= e; i += 8) {
    unsigned int pv[8], rv[8];
    #pragma unroll
    for (int q = 0; q < 8; q++) pv[q] = ((const unsigned int*)val)[i + q];
    #pragma unroll
    for (int q = 0; q < 8; q++)
      rv[q] = ((const unsigned int*)(T + (size_t)(pv[q] & 0xffffu) * HC))[lane];
    #pragma unroll
    for (int q = 0; q < 8; q++) {
      float w = __half2float(__ushort_as_half((unsigned short)(pv[q] >> 16)));
      ax = fmaf(w, bflo(rv[q]), ax);
      ay = fmaf(w, bfhi(rv[q]), ay);
    }
  }
  for (; i < e; i++) {
    unsigned int pv = ((const unsigned int*)val)[i];
    unsigned int rv = ((const unsigned int*)(T + (size_t)(pv & 0xffffu) * HC))[lane];
    float w = __half2float(__ushort_as_half((unsigned short)(pv >> 16)));
    ax = fmaf(w, bflo(rv), ax);
    ay = fmaf(w, bfhi(rv), ay);
  }
}

// ---------------- mega segment-mean: uniform weighted-sum gathers ----------------
// wave w: [0,10000) m2dis (xdb) | [10000,30000) drug merged flat (Ytab) | [30000,46000) m2a (xdb)
__global__ __launch_bounds__(256) void k_seg_mega(
    const int* __restrict__ off,
    const int* __restrict__ vmd, const int* __restrict__ vdrug, const int* __restrict__ vhd,
    const unsigned short* __restrict__ xdb, const unsigned short* __restrict__ Ytab,
    float* __restrict__ m2dis, float* __restrict__ accd, float* __restrict__ m2a) {
  int lane = threadIdx.x & 63;
  int lane2 = lane * 2;
  int w = blockIdx.x * 4 + (threadIdx.x >> 6);
  if (w < N_DIS) {
    int lo = off[OFF_Z0 + w], hi = off[OFF_Z0 + w + 1];
    float ax = 0.f, ay = 0.f;
    gacc_w(xdb, vmd, lo, hi, lane, ax, ay);
    *(float2*)(m2dis + (size_t)w * HC + lane2) = make_float2(ax, ay);
  } else if (w < N_DIS + N_DRUG) {
    int d = w - N_DIS;
    int lo = off[OFF_D + d * 9], hi = off[OFF_D + d * 9 + 9];
    float ax = 0.f, ay = 0.f;
    gacc_w(Ytab, vdrug, lo, hi, lane, ax, ay);
    *(float2*)(accd + (size_t)d * HC + lane2) = make_float2(ax, ay);
  } else {
    int idx = w - (N_DIS + N_DRUG);
    int t = idx / N_ATTR, r = idx - t * N_ATTR;
    int lo = off[OFF_Z2(t) + r], hi = off[OFF_Z2(t) + r + 1];
    float ax = 0.f, ay = 0.f;
    gacc_w(xdb, vhd + (size_t)t * E_HA, lo, hi, lane, ax, ay);
    *(float2*)(m2a + ((size_t)t * N_ATTR + r) * HC + lane2) = make_float2(ax, ay);
  }
}

// ---------------- generalized batched GEMM ----------------
// D = [leaky]( A1@B1 [+ A2@B2] [+ ACC] [+ bias] ); bf16out: D is ushort* (RNE)
struct GemmJob {
  const float* A1; const float* B1;
  const float* A2; const float* B2;
  const float* bias; const float* ACC;
  float* D;
  int M; int leaky; int bf16out;
};
struct GemmJobs { GemmJob j[10]; };

__global__ __launch_bounds__(256) void k_gemm_multi(GemmJobs jobs) {
  GemmJob jb = jobs.j[blockIdx.z];
  int m0 = blockIdx.x * 64;
  if (m0 >= jb.M) return;
  __shared__ float As[16][68];
  __shared__ float Bs[16][132];
  int tid = threadIdx.x;
  int tx = tid & 31, ty = tid >> 5;
  float acc[8][4];
  #pragma unroll
  for (int i = 0; i < 8; i++)
    #pragma unroll
    for (int j = 0; j < 4; j++) acc[i][j] = 0.f;

  int K = jb.A2 ? 256 : 128;
  for (int kk = 0; kk < K; kk += 16) {
    const float* A = (kk < 128) ? jb.A1 : jb.A2;
    const float* B = (kk < 128) ? jb.B1 : jb.B2;
    int kb = kk & 127;
    {
      int r = tid >> 2, kq = (tid & 3) * 4;
      int gr = m0 + r;
      float4 v = make_float4(0.f, 0.f, 0.f, 0.f);
      if (gr < jb.M) v = *(const float4*)(A + (size_t)gr * HC + kb + kq);
      As[kq + 0][r] = v.x; As[kq + 1][r] = v.y; As[kq + 2][r] = v.z; As[kq + 3][r] = v.w;
    }
    #pragma unroll
    for (int i = 0; i < 2; i++) {
      int idx = i * 256 + tid;
      int k = idx >> 5, c = (idx & 31) * 4;
      *(float4*)&Bs[k][c] = *(const float4*)(B + (size_t)(kb + k) * HC + c);
    }
    __syncthreads();
    #pragma unroll
    for (int k = 0; k < 16; k++) {
      float4 a0 = *(const float4*)&As[k][ty * 8];
      float4 a1 = *(const float4*)&As[k][ty * 8 + 4];
      float4 bv = *(const float4*)&Bs[k][tx * 4];
      float av[8] = {a0.x, a0.y, a0.z, a0.w, a1.x, a1.y, a1.z, a1.w};
      float bb[4] = {bv.x, bv.y, bv.z, bv.w};
      #pragma unroll
      for (int i = 0; i < 8; i++)
        #pragma unroll
        for (int j = 0; j < 4; j++) acc[i][j] += av[i] * bb[j];
    }
    __syncthreads();
  }

  int c0 = tx * 4;
  float4 bs = make_float4(0.f, 0.f, 0.f, 0.f);
  if (jb.bias) bs = *(const float4*)(jb.bias + c0);
  #pragma unroll
  for (int i = 0; i < 8; i++) {
    int gr = m0 + ty * 8 + i;
    if (gr >= jb.M) break;
    float r0 = acc[i][0] + bs.x, r1 = acc[i][1] + bs.y, r2 = acc[i][2] + bs.z, r3 = acc[i][3] + bs.w;
    if (jb.ACC) {
      float4 ac = *(const float4*)(jb.ACC + (size_t)gr * HC + c0);
      r0 += ac.x; r1 += ac.y; r2 += ac.z; r3 += ac.w;
    }
    if (jb.leaky) { r0 = leakyf(r0); r1 = leakyf(r1); r2 = leakyf(r2); r3 = leakyf(r3); }
    if (jb.bf16out) {
      unsigned short* Db = (unsigned short*)jb.D;
      uint2 w;
      w.x = (unsigned int)f2bf(r0) | ((unsigned int)f2bf(r1) << 16);
      w.y = (unsigned int)f2bf(r2) | ((unsigned int)f2bf(r3) << 16);
      *(uint2*)(Db + (size_t)gr * 128 + c0) = w;
    } else {
      float4 rv = make_float4(r0, r1, r2, r3);
      *(float4*)(jb.D + (size_t)gr * 128 + c0) = rv;
    }
  }
}

// ---------------- classifier head GEMMs ----------------
struct G64Job { const float* X; const float* W; const float* bias; float* D; int M; };

__global__ __launch_bounds__(256) void k_gemm64(G64Job j0, G64Job j1) {
  G64Job jb = blockIdx.z ? j1 : j0;
  int m0 = blockIdx.x * 64;
  if (m0 >= jb.M) return;
  __shared__ float As[16][68];
  __shared__ float Bs[16][68];
  int tid = threadIdx.x;
  int tx = tid & 15, ty = tid >> 4;
  float acc[4][4];
  #pragma unroll
  for (int i = 0; i < 4; i++)
    #pragma unroll
    for (int j = 0; j < 4; j++) acc[i][j] = 0.f;

  for (int kk = 0; kk < 128; kk += 16) {
    {
      int r = tid >> 2, kq = (tid & 3) * 4;
      int gr = m0 + r;
      float4 v = make_float4(0.f, 0.f, 0.f, 0.f);
      if (gr < jb.M) v = *(const float4*)(jb.X + (size_t)gr * HC + kk + kq);
      As[kq + 0][r] = v.x; As[kq + 1][r] = v.y; As[kq + 2][r] = v.z; As[kq + 3][r] = v.w;
    }
    {
      int k = tid >> 4, c = (tid & 15) * 4;
      *(float4*)&Bs[k][c] = *(const float4*)(jb.W + (size_t)(kk + k) * 64 + c);
    }
    __syncthreads();
    #pragma unroll
    for (int k = 0; k < 16; k++) {
      float4 a = *(const float4*)&As[k][ty * 4];
      float4 b = *(const float4*)&Bs[k][tx * 4];
      float av[4] = {a.x, a.y, a.z, a.w};
      float bb[4] = {b.x, b.y, b.z, b.w};
      #pragma unroll
      for (int i = 0; i < 4; i++)
        #pragma unroll
        for (int j = 0; j < 4; j++) acc[i][j] += av[i] * bb[j];
    }
    __syncthreads();
  }
  float4 bs = make_float4(0.f, 0.f, 0.f, 0.f);
  if (jb.bias) bs = *(const float4*)(jb.bias + tx * 4);
  #pragma unroll
  for (int i = 0; i < 4; i++) {
    int gr = m0 + ty * 4 + i;
    if (gr < jb.M) {
      float4 r = make_float4(acc[i][0] + bs.x, acc[i][1] + bs.y, acc[i][2] + bs.z, acc[i][3] + bs.w);
      *(float4*)(jb.D + (size_t)gr * 64 + tx * 4) = r;
    }
  }
}

// ---------------- per-edge tail MLP (LDS weights, fully unrolled, registers only) ----------------
__global__ __launch_bounds__(256) void k_tail(
    const float* __restrict__ U, const float* __restrict__ V,
    const int* __restrict__ es, const int* __restrict__ ed,
    const float* __restrict__ cw1, const float* __restrict__ cb1,
    const float* __restrict__ cw2, const float* __restrict__ cb2,
    const float* __restrict__ cw3, const float* __restrict__ cb3,
    const float* __restrict__ cw4, const float* __restrict__ cb4,
    float* __restrict__ out, int n) {
  __shared__ float w1[64 * 32];
  __shared__ float w2[32 * 16];
  __shared__ float w3[16 * 8];
  __shared__ float w4[8];
  __shared__ float b1[32], b2[16], b3[8];
  int tid = threadIdx.x;
  #pragma unroll
  for (int q = 0; q < 8; q++) w1[tid + q * 256] = cw1[tid + q * 256];
  #pragma unroll
  for (int q = 0; q < 2; q++) w2[tid + q * 256] = cw2[tid + q * 256];
  if (tid < 128) w3[tid] = cw3[tid];
  if (tid < 8)  w4[tid] = cw4[tid];
  if (tid < 32) b1[tid] = cb1[tid];
  if (tid < 16) b2[tid] = cb2[tid];
  if (tid < 8)  b3[tid] = cb3[tid];
  __syncthreads();
  int i = blockIdx.x * 256 + tid;
  if (i >= n) return;
  int s = es[i], d = ed[i];
  const float4* up = (const float4*)(U + (size_t)s * 64);
  const float4* vp = (const float4*)(V + (size_t)d * 64);
  float h1[64];
  #pragma unroll
  for (int q = 0; q < 16; q++) {
    float4 a = up[q], b = vp[q];
    h1[4 * q + 0] = leakyf(a.x + b.x);
    h1[4 * q + 1] = leakyf(a.y + b.y);
    h1[4 * q + 2] = leakyf(a.z + b.z);
    h1[4 * q + 3] = leakyf(a.w + b.w);
  }
  float h2[32];
  #pragma unroll
  for (int j = 0; j < 32; j++) h2[j] = b1[j];
  #pragma unroll
  for (int k = 0; k < 64; k++) {
    float hv = h1[k];
    #pragma unroll
    for (int jq = 0; jq < 8; jq++) {
      float4 w = *(const float4*)&w1[k * 32 + jq * 4];
      h2[4 * jq + 0] = fmaf(hv, w.x, h2[4 * jq + 0]);
      h2[4 * jq + 1] = fmaf(hv, w.y, h2[4 * jq + 1]);
      h2[4 * jq + 2] = fmaf(hv, w.z, h2[4 * jq + 2]);
      h2[4 * jq + 3] = fmaf(hv, w.w, h2[4 * jq + 3]);
    }
  }
  float h3[16];
  #pragma unroll
  for (int j = 0; j < 16; j++) h3[j] = b2[j];
  #pragma unroll
  for (int k = 0; k < 32; k++) {
    float hv = leakyf(h2[k]);
    #pragma unroll
    for (int jq = 0; jq < 4; jq++) {
      float4 w = *(const float4*)&w2[k * 16 + jq * 4];
      h3[4 * jq + 0] = fmaf(hv, w.x, h3[4 * jq + 0]);
      h3[4 * jq + 1] = fmaf(hv, w.y, h3[4 * jq + 1]);
      h3[4 * jq + 2] = fmaf(hv, w.z, h3[4 * jq + 2]);
      h3[4 * jq + 3] = fmaf(hv, w.w, h3[4 * jq + 3]);
    }
  }
  float h4[8];
  #pragma unroll
  for (int j = 0; j < 8; j++) h4[j] = b3[j];
  #pragma unroll
  for (int k = 0; k < 16; k++) {
    float hv = leakyf(h3[k]);
    #pragma unroll
    for (int jq = 0; jq < 2; jq++) {
      float4 w = *(const float4*)&w3[k * 8 + jq * 4];
      h4[4 * jq + 0] = fmaf(hv, w.x, h4[4 * jq + 0]);
      h4[4 * jq + 1] = fmaf(hv, w.y, h4[4 * jq + 1]);
      h4[4 * jq + 2] = fmaf(hv, w.z, h4[4 * jq + 2]);
      h4[4 * jq + 3] = fmaf(hv, w.w, h4[4 * jq + 3]);
    }
  }
  float p = cb4[0];
  #pragma unroll
  for (int k = 0; k < 8; k++) p = fmaf(leakyf(h4[k]), w4[k], p);
  out[i] = p;
}

extern "C" void kernel_launch(void* const* d_in, const int* in_sizes, int n_in,
                              void* d_out, int out_size, void* d_ws, size_t ws_size,
                              hipStream_t stream) {
  const float* disease_x   = (const float*)d_in[0];
  const float* drug_emb    = (const float*)d_in[1];
  const float* disease_emb = (const float*)d_in[2];
  const float* attr_emb    = (const float*)d_in[3];
  const float* dis_lin_w   = (const float*)d_in[4];
  const float* dis_lin_b   = (const float*)d_in[5];
  const float* mt_wl  = (const float*)d_in[6];
  const float* mt_bl  = (const float*)d_in[7];
  const float* mt_wr  = (const float*)d_in[8];
  const float* rmt_wl = (const float*)d_in[9];
  const float* rmt_bl = (const float*)d_in[10];
  const float* rmt_wr = (const float*)d_in[11];
  const float* ha_wl  = (const float*)d_in[12];
  const float* ha_bl  = (const float*)d_in[13];
  const float* ha_wr  = (const float*)d_in[14];
  const float* rha_wl = (const float*)d_in[15];
  const float* rha_bl = (const float*)d_in[16];
  const float* rha_wr = (const float*)d_in[17];
  const float* cw0 = (const float*)d_in[18];
  const float* cb0 = (const float*)d_in[19];
  const float* cw1 = (const float*)d_in[20];
  const float* cb1 = (const float*)d_in[21];
  const float* cw2 = (const float*)d_in[22];
  const float* cb2 = (const float*)d_in[23];
  const float* cw3 = (const float*)d_in[24];
  const float* cb3 = (const float*)d_in[25];
  const float* cw4 = (const float*)d_in[26];
  const float* cb4 = (const float*)d_in[27];
  const int* mt_src = (const int*)d_in[28];
  const int* mt_dst = (const int*)d_in[29];
  const int* ha_src = (const int*)d_in[30];
  const int* ha_dst = (const int*)d_in[31];
  const int* ell_src = (const int*)d_in[32];
  const int* ell_dst = (const int*)d_in[33];
  float* out = (float*)d_out;

  const long long ATTR_S = (long long)N_ATTR * HC;
  const long long W_S = HC * HC;

  // ---------- workspace carve ----------
  float* fws = (float*)d_ws;
  size_t o = 0;
  float* x_drug = fws + o; o += (size_t)N_DRUG * HC;
  float* x_dis  = fws + o; o += (size_t)N_DIS * HC;
  float* x_attr = fws + o; o += (size_t)T_ATTR * N_ATTR * HC;
  float* m2dis  = fws + o; o += (size_t)N_DIS * HC;          // | m2dis+m2a (3.328M floats)
  float* m2a    = fws + o; o += (size_t)T_ATTR * N_ATTR * HC;// | overlaid by hist (3.296M ints)
  float* accd   = fws + o; o += (size_t)N_DRUG * HC;
  float* Wc     = fws + o; o += HC * HC;
  float* biasc  = fws + o; o += HC;
  float* Ucls   = fws + o; o += (size_t)N_DRUG * 64;
  float* Vcls   = fws + o; o += (size_t)N_DIS * 64;
  // bf16 gather tables: Ytab = concat(Ydisb[10000], Yattrb[8x2000]) must be contiguous
  unsigned short* xdb    = (unsigned short*)(fws + o);
  unsigned short* Ytab   = xdb + (size_t)N_DRUG * HC;
  unsigned short* Ydisb  = Ytab;
  unsigned short* Yattrb = Ytab + (size_t)N_DIS * HC;
  o += ((size_t)N_DRUG * HC + (size_t)N_DIS * HC + (size_t)T_ATTR * N_ATTR * HC) / 2;
  int* iws = (int*)(fws + o);
  int* off = iws;                               // OFF_TOT = 206010
  int* vmd   = off + OFF_TOT;                   // 500000 (m2dis edges)
  int* vdrug = vmd + E_MT;                      // 1300000 (drug merged edges)
  int* vhd   = vdrug + (E_MT + T_ATTR * E_HA);  // 800000 (m2a edges)
  unsigned short* wtab = (unsigned short*)(vhd + (size_t)T_ATTR * E_HA); // 206000 ushorts
  int* csum = (int*)(wtab + WTOT + (WTOT & 1)); // 10*SMAXC ints
  int* hist = (int*)m2dis;   // 3.296M ints over m2dis+m2a (dead during CSR build)

  dim3 b256(256);
  // ---------- CSR build ----------
  k_hist<<<dim3(NB, 1, 18), b256, 0, stream>>>(mt_src, mt_dst, ha_src, ha_dst, hist);
  k_blkpfx<<<dim3((N_DRUG + 255) / 256, 1, 18), b256, 0, stream>>>(hist, off, wtab);
  {
    dim3 sg((180000 + SCH - 1) / SCH, 10);
    k_scan_l1<<<sg, b256, 0, stream>>>(off, csum);
    k_scan_l2<<<10, 64, 0, stream>>>(off, csum);
    k_scan_l3<<<sg, b256, 0, stream>>>(off, csum);
  }
  k_fill2<<<dim3(NB, 1, 18), b256, 0, stream>>>(mt_src, mt_dst, ha_src, ha_dst, hist, off, wtab,
                                                vmd, vdrug, vhd);

  // ---------- node init ----------
  k_dis0<<<N_DIS, 128, 0, stream>>>(disease_x, dis_lin_w, dis_lin_b, disease_emb, x_dis);

  for (int l = 0; l < 2; l++) {
    const float* xd = l ? (const float*)x_drug : drug_emb;
    const float* xa = l ? (const float*)x_attr : attr_emb;
    const float* mt_wl_l  = mt_wl  + (size_t)l * W_S;
    const float* mt_bl_l  = mt_bl  + (size_t)l * HC;
    const float* mt_wr_l  = mt_wr  + (size_t)l * W_S;
    const float* rmt_wl_l = rmt_wl + (size_t)l * W_S;
    const float* ha_wl_l  = ha_wl  + (size_t)l * T_ATTR * W_S;
    const float* ha_bl_l  = ha_bl  + (size_t)l * T_ATTR * HC;
    const float* ha_wr_l  = ha_wr  + (size_t)l * T_ATTR * W_S;
    const float* rha_wl_l = rha_wl + (size_t)l * T_ATTR * W_S;

    k_wc<<<64, 256, 0, stream>>>(rmt_wr + (size_t)l * W_S, rha_wr + (size_t)l * T_ATTR * W_S,
                                 rmt_bl + (size_t)l * HC, rha_bl + (size_t)l * T_ATTR * HC, Wc, biasc);

    // pre-transform GEMMs on the small side -> bf16 tables for the gather
    {
      GemmJobs J{};
      J.j[0] = {x_dis, rmt_wl_l, nullptr, nullptr, nullptr, nullptr, (float*)Ydisb, N_DIS, 0, 1};
      for (int t = 0; t < T_ATTR; t++)
        J.j[1 + t] = {xa + (size_t)t * ATTR_S, rha_wl_l + (size_t)t * W_S,
                      nullptr, nullptr, nullptr, nullptr,
                      (float*)(Yattrb + (size_t)t * ATTR_S), N_ATTR, 0, 1};
      k_gemm_multi<<<dim3((N_DIS + 63) / 64, 1, 9), b256, 0, stream>>>(J);
    }
    // xd -> bf16
    k_cvt<<<dim3((N_DRUG * HC / 4 + 255) / 256), b256, 0, stream>>>(xd, xdb, N_DRUG * HC / 4);

    // all gathers of this layer (weighted sums, bf16 tables, f32 accumulate)
    k_seg_mega<<<dim3((46000 + 3) / 4, 1, 1), b256, 0, stream>>>(
        off, vmd, vdrug, vhd, xdb, Ytab, m2dis, accd, m2a);

    // combine GEMMs (f32)
    {
      GemmJobs J{};
      J.j[0] = {xd, Wc, nullptr, nullptr, biasc, accd, x_drug, N_DRUG, 1, 0};
      J.j[1] = {m2dis, mt_wl_l, x_dis, mt_wr_l, mt_bl_l, nullptr, x_dis, N_DIS, 1, 0};
      for (int t = 0; t < T_ATTR; t++)
        J.j[2 + t] = {m2a + (size_t)t * ATTR_S, ha_wl_l + (size_t)t * W_S,
                      xa + (size_t)t * ATTR_S, ha_wr_l + (size_t)t * W_S,
                      ha_bl_l + (size_t)t * HC, nullptr, x_attr + (size_t)t * ATTR_S, N_ATTR, 1, 0};
      k_gemm_multi<<<dim3((N_DRUG + 63) / 64, 1, 10), b256, 0, stream>>>(J);
    }
  }

  // ---------- classifier: U/V precompute then per-edge tail ----------
  {
    G64Job ju = {x_drug, cw0, cb0, Ucls, N_DRUG};
    G64Job jv = {x_dis, cw0 + 128 * 64, nullptr, Vcls, N_DIS};
    k_gemm64<<<dim3((N_DRUG + 63) / 64, 1, 2), b256, 0, stream>>>(ju, jv);
    k_tail<<<dim3((E_LBL + 255) / 256, 1, 1), b256, 0, stream>>>(
        Ucls, Vcls, ell_src, ell_dst,
        cw1, cb1, cw2, cb2, cw3, cb3, cw4, cb4, out, E_LBL);
  }
}

// Round 11
// 466.465 us; speedup vs baseline: 1.5784x; 1.0263x over previous
//
#include <hip/hip_runtime.h>
#include <hip/hip_fp16.h>

#define N_DRUG 20000
#define N_DIS  10000
#define N_ATTR 2000
#define T_ATTR 8
#define E_MT   500000
#define E_HA   100000
#define E_LBL  200000
#define HC     128
#define NB     16   // chunk blocks per edge segment in CSR build

__device__ __forceinline__ float leakyf(float x) { return x >= 0.f ? x : 0.01f * x; }

// bf16 helpers: RNE encode, exact decode
__device__ __forceinline__ unsigned short f2bf(float f) {
  unsigned int u = __float_as_uint(f);
  return (unsigned short)((u + 0x7fffu + ((u >> 16) & 1u)) >> 16);
}
__device__ __forceinline__ float bflo(unsigned int u) { return __uint_as_float(u << 16); }
__device__ __forceinline__ float bfhi(unsigned int u) { return __uint_as_float(u & 0xffff0000u); }

typedef __attribute__((ext_vector_type(8))) short bf16x8;
typedef __attribute__((ext_vector_type(4))) float f32x4;

// ---------------- CSR build ----------------
// 18 hist segments z: 0: mt_dst(10000) | 1: mt_src(20000) | 2-9: ha_dst[t](2000) | 10-17: ha_src[t](20000)
#define HB0 0
#define HB1 160000
#define HB2(t) (480000 + (t) * 32000)
#define HB10(t) (736000 + (t) * 320000)
// wtab (f16 1/count per bin) bases:
#define WB0 0
#define WB1 10000
#define WB2(t) (30000 + (t) * 2000)
#define WB10(t) (46000 + (t) * 20000)
#define WTOT 206000
// off layout: z0 flat (10001) | drug-merged d-major flat (d*9+s, 180001) | z2 per t (2001 each)
#define OFF_Z0 0
#define OFF_D  10001
#define OFF_Z2(t) (190002 + (t) * 2001)
#define OFF_TOT 206010
// scan geometry
#define SCH 2048
#define SMAXC 128

struct SegB { int bins; int hbase; int wbase; int obase; int ostride; };
__device__ __forceinline__ SegB segb(int z) {
  SegB s;
  if (z == 0)      { s.bins = N_DIS;  s.hbase = HB0;  s.wbase = WB0;  s.obase = OFF_Z0;    s.ostride = 1; }
  else if (z == 1) { s.bins = N_DRUG; s.hbase = HB1;  s.wbase = WB1;  s.obase = OFF_D;     s.ostride = 9; }
  else if (z < 10) { int t = z - 2;  s.bins = N_ATTR; s.hbase = HB2(t);  s.wbase = WB2(t);  s.obase = OFF_Z2(t);   s.ostride = 1; }
  else             { int t = z - 10; s.bins = N_DRUG; s.hbase = HB10(t); s.wbase = WB10(t); s.obase = OFF_D + 1 + t; s.ostride = 9; }
  return s;
}

struct SegE { const int* key; const int* oth; int n; int roff; int* val; };
__device__ __forceinline__ SegE sege(int z,
    const int* mt_src, const int* mt_dst, const int* ha_src, const int* ha_dst,
    int* vmd, int* vdrug, int* vhd) {
  SegE s;
  if (z == 0)      { s.key = mt_dst; s.oth = mt_src; s.n = E_MT; s.roff = 0; s.val = vmd; }
  else if (z == 1) { s.key = mt_src; s.oth = mt_dst; s.n = E_MT; s.roff = 0; s.val = vdrug; }
  else if (z < 10) { int t = z - 2;
    s.key = ha_dst + (size_t)t * E_HA; s.oth = ha_src + (size_t)t * E_HA; s.n = E_HA;
    s.roff = 0; s.val = vhd + (size_t)t * E_HA; }
  else { int t = z - 10;
    s.key = ha_src + (size_t)t * E_HA; s.oth = ha_dst + (size_t)t * E_HA; s.n = E_HA;
    s.roff = 10000 + t * N_ATTR; s.val = vdrug; }
  return s;
}

__global__ __launch_bounds__(256) void k_hist(
    const int* __restrict__ mt_src, const int* __restrict__ mt_dst,
    const int* __restrict__ ha_src, const int* __restrict__ ha_dst,
    int* __restrict__ hist) {
  SegB g = segb(blockIdx.z);
  SegE s = sege(blockIdx.z, mt_src, mt_dst, ha_src, ha_dst, nullptr, nullptr, nullptr);
  __shared__ int h[N_DRUG];
  int tid = threadIdx.x, b = blockIdx.x;
  for (int i = tid; i < g.bins; i += 256) h[i] = 0;
  __syncthreads();
  int ch = (s.n + NB - 1) / NB;
  int lo = b * ch, hi = min(s.n, lo + ch);
  for (int i = lo + tid; i < hi; i += 256) atomicAdd(&h[s.key[i]], 1);
  __syncthreads();
  int* hz = hist + g.hbase + (size_t)b * g.bins;
  for (int i = tid; i < g.bins; i += 256) hz[i] = h[i];
}

__global__ __launch_bounds__(256) void k_blkpfx(int* __restrict__ hist, int* __restrict__ off,
                                                unsigned short* __restrict__ wtab) {
  SegB g = segb(blockIdx.z);
  int i = blockIdx.x * 256 + threadIdx.x;
  if (i >= g.bins) return;
  int run = 0;
  #pragma unroll
  for (int b = 0; b < NB; b++) {
    int idx = g.hbase + b * g.bins + i;
    int v = hist[idx];
    hist[idx] = run;
    run += v;
  }
  off[g.obase + i * g.ostride] = run;
  __half hw = __float2half(1.0f / (float)(run > 0 ? run : 1));
  wtab[g.wbase + i] = __half_as_ushort(hw);
}

__device__ __forceinline__ void scan_region(int r, int& base, int& L) {
  if (r == 0)      { base = OFF_Z0; L = 10000; }
  else if (r == 1) { base = OFF_D;  L = 180000; }
  else             { int t = r - 2; base = OFF_Z2(t); L = 2000; }
}

__global__ __launch_bounds__(256) void k_scan_l1(int* __restrict__ off, int* __restrict__ csum) {
  int base, L;
  scan_region(blockIdx.y, base, L);
  int c = blockIdx.x;
  int c0 = c * SCH;
  if (c0 >= L) return;
  int tid = threadIdx.x;
  int i0 = c0 + tid * 8;
  int v[8];
  int s = 0;
  #pragma unroll
  for (int j = 0; j < 8; j++) {
    int i = i0 + j;
    v[j] = (i < L) ? off[base + i] : 0;
    s += v[j];
  }
  __shared__ int ssum[256];
  ssum[tid] = s;
  __syncthreads();
  if (tid == 0) {
    int run = 0;
    #pragma unroll 8
    for (int i = 0; i < 256; i++) { int x = ssum[i]; ssum[i] = run; run += x; }
    csum[blockIdx.y * SMAXC + c] = run;
  }
  __syncthreads();
  int run = ssum[tid];
  #pragma unroll
  for (int j = 0; j < 8; j++) {
    int i = i0 + j;
    if (i < L) { off[base + i] = run; run += v[j]; }
  }
}

__global__ void k_scan_l2(int* __restrict__ off, int* __restrict__ csum) {
  int r = blockIdx.x;
  int base, L;
  scan_region(r, base, L);
  if (threadIdx.x == 0) {
    int nc = (L + SCH - 1) / SCH;
    int run = 0;
    for (int c = 0; c < nc; c++) {
      int v = csum[r * SMAXC + c];
      csum[r * SMAXC + c] = run;
      run += v;
    }
    off[base + L] = run;
  }
}

__global__ __launch_bounds__(256) void k_scan_l3(int* __restrict__ off, const int* __restrict__ csum) {
  int base, L;
  scan_region(blockIdx.y, base, L);
  int c = blockIdx.x;
  int c0 = c * SCH;
  if (c0 >= L || c == 0) return;
  int add = csum[blockIdx.y * SMAXC + c];
  int i0 = c0 + threadIdx.x * 8;
  #pragma unroll
  for (int j = 0; j < 8; j++) {
    int i = i0 + j;
    if (i < L) off[base + i] += add;
  }
}

// fill: wtab read from GLOBAL (L2-resident) -> LDS back to 80KB -> 2 blocks/CU
__global__ __launch_bounds__(256) void k_fill2(
    const int* __restrict__ mt_src, const int* __restrict__ mt_dst,
    const int* __restrict__ ha_src, const int* __restrict__ ha_dst,
    const int* __restrict__ hist, const int* __restrict__ off,
    const unsigned short* __restrict__ wtab,
    int* vmd, int* vdrug, int* vhd) {
  SegB g = segb(blockIdx.z);
  SegE s = sege(blockIdx.z, mt_src, mt_dst, ha_src, ha_dst, vmd, vdrug, vhd);
  __shared__ int h[N_DRUG];
  int tid = threadIdx.x, b = blockIdx.x;
  const int* hz = hist + g.hbase + (size_t)b * g.bins;
  for (int i = tid; i < g.bins; i += 256) h[i] = hz[i] + off[g.obase + i * g.ostride];
  __syncthreads();
  int ch = (s.n + NB - 1) / NB;
  int lo = b * ch, hi = min(s.n, lo + ch);
  const unsigned short* wz = wtab + g.wbase;
  for (int i = lo + tid; i < hi; i += 256) {
    int k = s.key[i];
    unsigned int w = wz[k];
    int pos = atomicAdd(&h[k], 1);
    s.val[pos] = (int)((w << 16) | (unsigned int)(s.oth[i] + s.roff));
  }
}

// ---------------- x_dis init ----------------
__global__ void k_dis0(const float* __restrict__ dx, const float* __restrict__ w,
                       const float* __restrict__ b, const float* __restrict__ emb,
                       float* __restrict__ out) {
  int i = blockIdx.x;
  int j = threadIdx.x;
  float s = b[j] + emb[(size_t)i * HC + j];
  #pragma unroll
  for (int k = 0; k < 10; k++) s += dx[i * 10 + k] * w[k * HC + j];
  out[(size_t)i * HC + j] = s;
}

// ---------------- Wct = bf16 transpose of (rmt_wr + sum_t rha_wr); biasc ----------------
__global__ void k_wc(const float* __restrict__ wr_main, const float* __restrict__ wr_t,
                     const float* __restrict__ bl_main, const float* __restrict__ bl_t,
                     unsigned short* __restrict__ Wct, float* __restrict__ biasc) {
  int i = blockIdx.x * blockDim.x + threadIdx.x;
  if (i < HC * HC) {
    float s = wr_main[i];
    #pragma unroll
    for (int t = 0; t < T_ATTR; t++) s += wr_t[(size_t)t * HC * HC + i];
    int k = i >> 7, n = i & 127;
    Wct[n * 128 + k] = f2bf(s);
  }
  if (i < HC) {
    float s = bl_main[i];
    #pragma unroll
    for (int t = 0; t < T_ATTR; t++) s += bl_t[t * HC + i];
    biasc[i] = s;
  }
}

// ---------------- weight transpose f32 [128][128] -> bf16 Wt[n][k] ----------------
struct WtJobs { const float* s[27]; };
__global__ __launch_bounds__(256) void k_wt(WtJobs J, unsigned short* __restrict__ dst) {
  const float* src = J.s[blockIdx.z];
  unsigned short* d = dst + (size_t)blockIdx.z * 16384;
  __shared__ float t[32][33];
  int tx = threadIdx.x & 31, ty = threadIdx.x >> 5;  // 32 x 8
  int i0 = blockIdx.x * 32, j0 = blockIdx.y * 32;    // i = k, j = n
  #pragma unroll
  for (int q = 0; q < 4; q++) {
    int k = i0 + ty + q * 8;
    t[ty + q * 8][tx] = src[k * 128 + j0 + tx];
  }
  __syncthreads();
  #pragma unroll
  for (int q = 0; q < 4; q++) {
    int n = j0 + ty + q * 8;
    d[(size_t)n * 128 + i0 + tx] = f2bf(t[tx][ty + q * 8]);
  }
}

// ---------------- f32 -> bf16 convert (4 elems/thread) ----------------
__global__ __launch_bounds__(256) void k_cvt(const float* __restrict__ src,
                                             unsigned short* __restrict__ dst, int n4) {
  int i = blockIdx.x * 256 + threadIdx.x;
  if (i >= n4) return;
  float4 v = ((const float4*)src)[i];
  uint2 w;
  w.x = (unsigned int)f2bf(v.x) | ((unsigned int)f2bf(v.y) << 16);
  w.y = (unsigned int)f2bf(v.z) | ((unsigned int)f2bf(v.w) << 16);
  ((uint2*)dst)[i] = w;
}

// ---------------- weighted gather accumulate: packed (f16 w | u16 row), bf16 table ----------------
__device__ __forceinline__ void gacc_w(const unsigned short* __restrict__ T, const int* __restrict__ val,
                                       int b, int e, int lane, float& ax, float& ay) {
  int i = b;
  for (; i + 8 <= e; i += 8) {
    unsigned int pv[8], rv[8];
    #pragma unroll
    for (int q = 0; q < 8; q++) pv[q] = ((const unsigned int*)val)[i + q];
    #pragma unroll
    for (int q = 0; q < 8; q++)
      rv[q] = ((const unsigned int*)(T + (size_t)(pv[q] & 0xffffu) * HC))[lane];
    #pragma unroll
    for (int q = 0; q < 8; q++) {
      float w = __half2float(__ushort_as_half((unsigned short)(pv[q] >> 16)));
      ax = fmaf(w, bflo(rv[q]), ax);
      ay = fmaf(w, bfhi(rv[q]), ay);
    }
  }
  for (; i < e; i++) {
    unsigned int pv = ((const unsigned int*)val)[i];
    unsigned int rv = ((const unsigned int*)(T + (size_t)(pv & 0xffffu) * HC))[lane];
    float w = __half2float(__ushort_as_half((unsigned short)(pv >> 16)));
    ax = fmaf(w, bflo(rv), ax);
    ay = fmaf(w, bfhi(rv), ay);
  }
}

// ---------------- mega segment-mean: m2dis/m2a out bf16 (GEMM A-operands), accd out f32 (ACC) ----------------
__global__ __launch_bounds__(256) void k_seg_mega(
    const int* __restrict__ off,
    const int* __restrict__ vmd, const int* __restrict__ vdrug, const int* __restrict__ vhd,
    const unsigned short* __restrict__ xdb, const unsigned short* __restrict__ Ytab,
    unsigned short* __restrict__ m2disb, float* __restrict__ accd, unsigned short* __restrict__ m2ab) {
  int lane = threadIdx.x & 63;
  int lane2 = lane * 2;
  int w = blockIdx.x * 4 + (threadIdx.x >> 6);
  if (w < N_DIS) {
    int lo = off[OFF_Z0 + w], hi = off[OFF_Z0 + w + 1];
    float ax = 0.f, ay = 0.f;
    gacc_w(xdb, vmd, lo, hi, lane, ax, ay);
    *(unsigned int*)(m2disb + (size_t)w * HC + lane2) =
        (unsigned int)f2bf(ax) | ((unsigned int)f2bf(ay) << 16);
  } else if (w < N_DIS + N_DRUG) {
    int d = w - N_DIS;
    int lo = off[OFF_D + d * 9], hi = off[OFF_D + d * 9 + 9];
    float ax = 0.f, ay = 0.f;
    gacc_w(Ytab, vdrug, lo, hi, lane, ax, ay);
    *(float2*)(accd + (size_t)d * HC + lane2) = make_float2(ax, ay);
  } else {
    int idx = w - (N_DIS + N_DRUG);
    int t = idx / N_ATTR, r = idx - t * N_ATTR;
    int lo = off[OFF_Z2(t) + r], hi = off[OFF_Z2(t) + r + 1];
    float ax = 0.f, ay = 0.f;
    gacc_w(xdb, vhd + (size_t)t * E_HA, lo, hi, lane, ax, ay);
    *(unsigned int*)(m2ab + ((size_t)t * N_ATTR + r) * HC + lane2) =
        (unsigned int)f2bf(ax) | ((unsigned int)f2bf(ay) << 16);
  }
}

// ---------------- MFMA GEMM: out[M][128] = X@W via D^T = Wt-frags x X-frags ----------------
// Wt is W transposed [n][k] bf16. Both operand frags are contiguous 16B loads. No LDS.
// A-op (Wt): row n = f*16 + (lane&15), k = k0 + 8*(lane>>4) + j
// B-op (X):  col m-slot = lane&15 (row m = m0+wave*16+(lane&15)), same k
// D: lane holds out[m][f*16 + 4*(lane>>4) + i], i=0..3  (HW-verified C/D map)
struct MJob {
  const unsigned short* X1; const unsigned short* Wt1;
  const unsigned short* X2; const unsigned short* Wt2;
  const float* bias; const float* ACC;
  float* D;
  int M; int leaky; int bf16out;
};
struct MJobs { MJob j[10]; };

__global__ __launch_bounds__(256) void k_gemm_mfma(MJobs jobs) {
  MJob jb = jobs.j[blockIdx.z];
  int m0 = blockIdx.x * 64;
  if (m0 >= jb.M) return;
  int wave = threadIdx.x >> 6;
  int lane = threadIdx.x & 63;
  int l15 = lane & 15, g = lane >> 4;
  int m = m0 + wave * 16 + l15;
  bool mok = m < jb.M;
  int mrow = mok ? m : 0;

  f32x4 acc[8] = {};
  #pragma unroll
  for (int part = 0; part < 2; part++) {
    const unsigned short* X = part ? jb.X2 : jb.X1;
    const unsigned short* Wt = part ? jb.Wt2 : jb.Wt1;
    if (!X) break;
    #pragma unroll
    for (int ks = 0; ks < 4; ks++) {
      int k0 = ks * 32 + g * 8;
      bf16x8 xb = {};
      if (mok) xb = *(const bf16x8*)(X + (size_t)mrow * 128 + k0);
      #pragma unroll
      for (int f = 0; f < 8; f++) {
        bf16x8 wb = *(const bf16x8*)(Wt + (size_t)(f * 16 + l15) * 128 + k0);
        acc[f] = __builtin_amdgcn_mfma_f32_16x16x32_bf16(wb, xb, acc[f], 0, 0, 0);
      }
    }
  }
  if (!mok) return;
  #pragma unroll
  for (int f = 0; f < 8; f++) {
    int n0 = f * 16 + 4 * g;
    float r0 = acc[f][0], r1 = acc[f][1], r2 = acc[f][2], r3 = acc[f][3];
    if (jb.bias) {
      float4 bs = *(const float4*)(jb.bias + n0);
      r0 += bs.x; r1 += bs.y; r2 += bs.z; r3 += bs.w;
    }
    if (jb.ACC) {
      float4 a = *(const float4*)(jb.ACC + (size_t)m * 128 + n0);
      r0 += a.x; r1 += a.y; r2 += a.z; r3 += a.w;
    }
    if (jb.leaky) { r0 = leakyf(r0); r1 = leakyf(r1); r2 = leakyf(r2); r3 = leakyf(r3); }
    if (jb.bf16out) {
      unsigned short* Db = (unsigned short*)jb.D;
      uint2 w;
      w.x = (unsigned int)f2bf(r0) | ((unsigned int)f2bf(r1) << 16);
      w.y = (unsigned int)f2bf(r2) | ((unsigned int)f2bf(r3) << 16);
      *(uint2*)(Db + (size_t)m * 128 + n0) = w;
    } else {
      *(float4*)(jb.D + (size_t)m * 128 + n0) = make_float4(r0, r1, r2, r3);
    }
  }
}

// ---------------- classifier head GEMMs (SIMT f32, small) ----------------
struct G64Job { const float* X; const float* W; const float* bias; float* D; int M; };

__global__ __launch_bounds__(256) void k_gemm64(G64Job j0, G64Job j1) {
  G64Job jb = blockIdx.z ? j1 : j0;
  int m0 = blockIdx.x * 64;
  if (m0 >= jb.M) return;
  __shared__ float As[16][68];
  __shared__ float Bs[16][68];
  int tid = threadIdx.x;
  int tx = tid & 15, ty = tid >> 4;
  float acc[4][4];
  #pragma unroll
  for (int i = 0; i < 4; i++)
    #pragma unroll
    for (int j = 0; j < 4; j++) acc[i][j] = 0.f;

  for (int kk = 0; kk < 128; kk += 16) {
    {
      int r = tid >> 2, kq = (tid & 3) * 4;
      int gr = m0 + r;
      float4 v = make_float4(0.f, 0.f, 0.f, 0.f);
      if (gr < jb.M) v = *(const float4*)(jb.X + (size_t)gr * HC + kk + kq);
      As[kq + 0][r] = v.x; As[kq + 1][r] = v.y; As[kq + 2][r] = v.z; As[kq + 3][r] = v.w;
    }
    {
      int k = tid >> 4, c = (tid & 15) * 4;
      *(float4*)&Bs[k][c] = *(const float4*)(jb.W + (size_t)(kk + k) * 64 + c);
    }
    __syncthreads();
    #pragma unroll
    for (int k = 0; k < 16; k++) {
      float4 a = *(const float4*)&As[k][ty * 4];
      float4 b = *(const float4*)&Bs[k][tx * 4];
      float av[4] = {a.x, a.y, a.z, a.w};
      float bb[4] = {b.x, b.y, b.z, b.w};
      #pragma unroll
      for (int i = 0; i < 4; i++)
        #pragma unroll
        for (int j = 0; j < 4; j++) acc[i][j] += av[i] * bb[j];
    }
    __syncthreads();
  }
  float4 bs = make_float4(0.f, 0.f, 0.f, 0.f);
  if (jb.bias) bs = *(const float4*)(jb.bias + tx * 4);
  #pragma unroll
  for (int i = 0; i < 4; i++) {
    int gr = m0 + ty * 4 + i;
    if (gr < jb.M) {
      float4 r = make_float4(acc[i][0] + bs.x, acc[i][1] + bs.y, acc[i][2] + bs.z, acc[i][3] + bs.w);
      *(float4*)(jb.D + (size_t)gr * 64 + tx * 4) = r;
    }
  }
}

// ---------------- per-edge tail MLP (LDS weights, fully unrolled, registers only) ----------------
__global__ __launch_bounds__(256) void k_tail(
    const float* __restrict__ U, const float* __restrict__ V,
    const int* __restrict__ es, const int* __restrict__ ed,
    const float* __restrict__ cw1, const float* __restrict__ cb1,
    const float* __restrict__ cw2, const float* __restrict__ cb2,
    const float* __restrict__ cw3, const float* __restrict__ cb3,
    const float* __restrict__ cw4, const float* __restrict__ cb4,
    float* __restrict__ out, int n) {
  __shared__ float w1[64 * 32];
  __shared__ float w2[32 * 16];
  __shared__ float w3[16 * 8];
  __shared__ float w4[8];
  __shared__ float b1[32], b2[16], b3[8];
  int tid = threadIdx.x;
  #pragma unroll
  for (int q = 0; q < 8; q++) w1[tid + q * 256] = cw1[tid + q * 256];
  #pragma unroll
  for (int q = 0; q < 2; q++) w2[tid + q * 256] = cw2[tid + q * 256];
  if (tid < 128) w3[tid] = cw3[tid];
  if (tid < 8)  w4[tid] = cw4[tid];
  if (tid < 32) b1[tid] = cb1[tid];
  if (tid < 16) b2[tid] = cb2[tid];
  if (tid < 8)  b3[tid] = cb3[tid];
  __syncthreads();
  int i = blockIdx.x * 256 + tid;
  if (i >= n) return;
  int s = es[i], d = ed[i];
  const float4* up = (const float4*)(U + (size_t)s * 64);
  const float4* vp = (const float4*)(V + (size_t)d * 64);
  float h1[64];
  #pragma unroll
  for (int q = 0; q < 16; q++) {
    float4 a = up[q], b = vp[q];
    h1[4 * q + 0] = leakyf(a.x + b.x);
    h1[4 * q + 1] = leakyf(a.y + b.y);
    h1[4 * q + 2] = leakyf(a.z + b.z);
    h1[4 * q + 3] = leakyf(a.w + b.w);
  }
  float h2[32];
  #pragma unroll
  for (int j = 0; j < 32; j++) h2[j] = b1[j];
  #pragma unroll
  for (int k = 0; k < 64; k++) {
    float hv = h1[k];
    #pragma unroll
    for (int jq = 0; jq < 8; jq++) {
      float4 w = *(const float4*)&w1[k * 32 + jq * 4];
      h2[4 * jq + 0] = fmaf(hv, w.x, h2[4 * jq + 0]);
      h2[4 * jq + 1] = fmaf(hv, w.y, h2[4 * jq + 1]);
      h2[4 * jq + 2] = fmaf(hv, w.z, h2[4 * jq + 2]);
      h2[4 * jq + 3] = fmaf(hv, w.w, h2[4 * jq + 3]);
    }
  }
  float h3[16];
  #pragma unroll
  for (int j = 0; j < 16; j++) h3[j] = b2[j];
  #pragma unroll
  for (int k = 0; k < 32; k++) {
    float hv = leakyf(h2[k]);
    #pragma unroll
    for (int jq = 0; jq < 4; jq++) {
      float4 w = *(const float4*)&w2[k * 16 + jq * 4];
      h3[4 * jq + 0] = fmaf(hv, w.x, h3[4 * jq + 0]);
      h3[4 * jq + 1] = fmaf(hv, w.y, h3[4 * jq + 1]);
      h3[4 * jq + 2] = fmaf(hv, w.z, h3[4 * jq + 2]);
      h3[4 * jq + 3] = fmaf(hv, w.w, h3[4 * jq + 3]);
    }
  }
  float h4[8];
  #pragma unroll
  for (int j = 0; j < 8; j++) h4[j] = b3[j];
  #pragma unroll
  for (int k = 0; k < 16; k++) {
    float hv = leakyf(h3[k]);
    #pragma unroll
    for (int jq = 0; jq < 2; jq++) {
      float4 w = *(const float4*)&w3[k * 8 + jq * 4];
      h4[4 * jq + 0] = fmaf(hv, w.x, h4[4 * jq + 0]);
      h4[4 * jq + 1] = fmaf(hv, w.y, h4[4 * jq + 1]);
      h4[4 * jq + 2] = fmaf(hv, w.z, h4[4 * jq + 2]);
      h4[4 * jq + 3] = fmaf(hv, w.w, h4[4 * jq + 3]);
    }
  }
  float p = cb4[0];
  #pragma unroll
  for (int k = 0; k < 8; k++) p = fmaf(leakyf(h4[k]), w4[k], p);
  out[i] = p;
}

extern "C" void kernel_launch(void* const* d_in, const int* in_sizes, int n_in,
                              void* d_out, int out_size, void* d_ws, size_t ws_size,
                              hipStream_t stream) {
  const float* disease_x   = (const float*)d_in[0];
  const float* drug_emb    = (const float*)d_in[1];
  const float* disease_emb = (const float*)d_in[2];
  const float* attr_emb    = (const float*)d_in[3];
  const float* dis_lin_w   = (const float*)d_in[4];
  const float* dis_lin_b   = (const float*)d_in[5];
  const float* mt_wl  = (const float*)d_in[6];
  const float* mt_bl  = (const float*)d_in[7];
  const float* mt_wr  = (const float*)d_in[8];
  const float* rmt_wl = (const float*)d_in[9];
  const float* rmt_bl = (const float*)d_in[10];
  const float* rmt_wr = (const float*)d_in[11];
  const float* ha_wl  = (const float*)d_in[12];
  const float* ha_bl  = (const float*)d_in[13];
  const float* ha_wr  = (const float*)d_in[14];
  const float* rha_wl = (const float*)d_in[15];
  const float* rha_bl = (const float*)d_in[16];
  const float* rha_wr = (const float*)d_in[17];
  const float* cw0 = (const float*)d_in[18];
  const float* cb0 = (const float*)d_in[19];
  const float* cw1 = (const float*)d_in[20];
  const float* cb1 = (const float*)d_in[21];
  const float* cw2 = (const float*)d_in[22];
  const float* cb2 = (const float*)d_in[23];
  const float* cw3 = (const float*)d_in[24];
  const float* cb3 = (const float*)d_in[25];
  const float* cw4 = (const float*)d_in[26];
  const float* cb4 = (const float*)d_in[27];
  const int* mt_src = (const int*)d_in[28];
  const int* mt_dst = (const int*)d_in[29];
  const int* ha_src = (const int*)d_in[30];
  const int* ha_dst = (const int*)d_in[31];
  const int* ell_src = (const int*)d_in[32];
  const int* ell_dst = (const int*)d_in[33];
  float* out = (float*)d_out;

  const long long ATTR_S = (long long)N_ATTR * HC;
  const long long W_S = HC * HC;

  // ---------- workspace carve ----------
  float* fws = (float*)d_ws;
  size_t o = 0;
  float* x_drug = fws + o; o += (size_t)N_DRUG * HC;
  float* x_dis  = fws + o; o += (size_t)N_DIS * HC;
  float* x_attr = fws + o; o += (size_t)T_ATTR * N_ATTR * HC;
  float* accd   = fws + o; o += (size_t)N_DRUG * HC;   // | accd+biasc+Ucls = 3.84M floats,
  float* biasc  = fws + o; o += 128;                   // | overlaid by hist (3.296M ints)
  float* Ucls   = fws + o; o += (size_t)N_DRUG * 64;   // | during CSR build only
  float* Vcls   = fws + o; o += (size_t)N_DIS * 64;
  // bf16 regions (ushort counts)
  unsigned short* xdb    = (unsigned short*)(fws + o);
  unsigned short* Ytab   = xdb + (size_t)N_DRUG * HC;          // Ydisb + Yattrb contiguous
  unsigned short* Ydisb  = Ytab;
  unsigned short* Yattrb = Ytab + (size_t)N_DIS * HC;
  unsigned short* xdisb  = Yattrb + (size_t)T_ATTR * N_ATTR * HC;
  unsigned short* xab    = xdisb + (size_t)N_DIS * HC;
  unsigned short* m2disb = xab + (size_t)T_ATTR * N_ATTR * HC;
  unsigned short* m2ab   = m2disb + (size_t)N_DIS * HC;
  unsigned short* Wts    = m2ab + (size_t)T_ATTR * N_ATTR * HC;  // 27 * 16384
  unsigned short* Wct    = Wts + 27 * 16384;                     // 16384
  unsigned short* ushort_end = Wct + 16384;
  o += ((size_t)(ushort_end - xdb) + 1) / 2;
  int* iws = (int*)(fws + o);
  int* off = iws;                               // OFF_TOT
  int* vmd   = off + OFF_TOT;                   // 500000
  int* vdrug = vmd + E_MT;                      // 1300000
  int* vhd   = vdrug + (E_MT + T_ATTR * E_HA);  // 800000
  unsigned short* wtab = (unsigned short*)(vhd + (size_t)T_ATTR * E_HA); // WTOT ushorts
  int* csum = (int*)(wtab + WTOT + (WTOT & 1)); // 10*SMAXC ints
  int* hist = (int*)accd;   // 3.296M ints over accd..Ucls (dead during CSR build)

  dim3 b256(256);
  // ---------- CSR build ----------
  k_hist<<<dim3(NB, 1, 18), b256, 0, stream>>>(mt_src, mt_dst, ha_src, ha_dst, hist);
  k_blkpfx<<<dim3((N_DRUG + 255) / 256, 1, 18), b256, 0, stream>>>(hist, off, wtab);
  {
    dim3 sg((180000 + SCH - 1) / SCH, 10);
    k_scan_l1<<<sg, b256, 0, stream>>>(off, csum);
    k_scan_l2<<<10, 64, 0, stream>>>(off, csum);
    k_scan_l3<<<sg, b256, 0, stream>>>(off, csum);
  }
  k_fill2<<<dim3(NB, 1, 18), b256, 0, stream>>>(mt_src, mt_dst, ha_src, ha_dst, hist, off, wtab,
                                                vmd, vdrug, vhd);

  // ---------- node init ----------
  k_dis0<<<N_DIS, 128, 0, stream>>>(disease_x, dis_lin_w, dis_lin_b, disease_emb, x_dis);

  for (int l = 0; l < 2; l++) {
    const float* xd = l ? (const float*)x_drug : drug_emb;
    const float* xa = l ? (const float*)x_attr : attr_emb;
    const float* mt_wl_l  = mt_wl  + (size_t)l * W_S;
    const float* mt_bl_l  = mt_bl  + (size_t)l * HC;
    const float* mt_wr_l  = mt_wr  + (size_t)l * W_S;
    const float* rmt_wl_l = rmt_wl + (size_t)l * W_S;
    const float* ha_wl_l  = ha_wl  + (size_t)l * T_ATTR * W_S;
    const float* ha_bl_l  = ha_bl  + (size_t)l * T_ATTR * HC;
    const float* ha_wr_l  = ha_wr  + (size_t)l * T_ATTR * W_S;
    const float* rha_wl_l = rha_wl + (size_t)l * T_ATTR * W_S;

    // Wct (bf16 transposed) + biasc
    k_wc<<<64, 256, 0, stream>>>(rmt_wr + (size_t)l * W_S, rha_wr + (size_t)l * T_ATTR * W_S,
                                 rmt_bl + (size_t)l * HC, rha_bl + (size_t)l * T_ATTR * HC, Wct, biasc);

    // transpose+bf16 all weight mats for this layer into Wts
    // slots: 0 rmt_wl | 1..8 rha_wl[t] | 9 mt_wl | 10 mt_wr | 11..18 ha_wl[t] | 19..26 ha_wr[t]
    {
      WtJobs W{};
      W.s[0] = rmt_wl_l;
      for (int t = 0; t < T_ATTR; t++) W.s[1 + t] = rha_wl_l + (size_t)t * W_S;
      W.s[9] = mt_wl_l;
      W.s[10] = mt_wr_l;
      for (int t = 0; t < T_ATTR; t++) W.s[11 + t] = ha_wl_l + (size_t)t * W_S;
      for (int t = 0; t < T_ATTR; t++) W.s[19 + t] = ha_wr_l + (size_t)t * W_S;
      k_wt<<<dim3(4, 4, 27), b256, 0, stream>>>(W, Wts);
    }

    // bf16 copies of node features
    k_cvt<<<dim3((N_DRUG * HC / 4 + 255) / 256), b256, 0, stream>>>(xd, xdb, N_DRUG * HC / 4);
    k_cvt<<<dim3((N_DIS * HC / 4 + 255) / 256), b256, 0, stream>>>(x_dis, xdisb, N_DIS * HC / 4);
    k_cvt<<<dim3((T_ATTR * N_ATTR * HC / 4 + 255) / 256), b256, 0, stream>>>(xa, xab, T_ATTR * N_ATTR * HC / 4);

    // pre-transform GEMMs (MFMA): Ydisb = x_dis@rmt_wl, Yattrb_t = xa_t@rha_wl_t  (bf16 out)
    {
      MJobs J{};
      J.j[0] = {xdisb, Wts + 0 * 16384, nullptr, nullptr, nullptr, nullptr, (float*)Ydisb, N_DIS, 0, 1};
      for (int t = 0; t < T_ATTR; t++)
        J.j[1 + t] = {xab + (size_t)t * ATTR_S, Wts + (size_t)(1 + t) * 16384,
                      nullptr, nullptr, nullptr, nullptr,
                      (float*)(Yattrb + (size_t)t * ATTR_S), N_ATTR, 0, 1};
      k_gemm_mfma<<<dim3((N_DIS + 63) / 64, 1, 9), b256, 0, stream>>>(J);
    }

    // all gathers (weighted sums, bf16 tables; m2 outputs bf16, accd f32)
    k_seg_mega<<<dim3((46000 + 3) / 4, 1, 1), b256, 0, stream>>>(
        off, vmd, vdrug, vhd, xdb, Ytab, m2disb, accd, m2ab);

    // combine GEMMs (MFMA, f32 out + leaky)
    {
      MJobs J{};
      J.j[0] = {xdb, Wct, nullptr, nullptr, biasc, accd, x_drug, N_DRUG, 1, 0};
      J.j[1] = {m2disb, Wts + 9 * 16384, xdisb, Wts + 10 * 16384, mt_bl_l, nullptr, x_dis, N_DIS, 1, 0};
      for (int t = 0; t < T_ATTR; t++)
        J.j[2 + t] = {m2ab + (size_t)t * ATTR_S, Wts + (size_t)(11 + t) * 16384,
                      xab + (size_t)t * ATTR_S, Wts + (size_t)(19 + t) * 16384,
                      ha_bl_l + (size_t)t * HC, nullptr, x_attr + (size_t)t * ATTR_S, N_ATTR, 1, 0};
      k_gemm_mfma<<<dim3((N_DRUG + 63) / 64, 1, 10), b256, 0, stream>>>(J);
    }
  }

  // ---------- classifier: U/V precompute then per-edge tail ----------
  {
    G64Job ju = {x_drug, cw0, cb0, Ucls, N_DRUG};
    G64Job jv = {x_dis, cw0 + 128 * 64, nullptr, Vcls, N_DIS};
    k_gemm64<<<dim3((N_DRUG + 63) / 64, 1, 2), b256, 0, stream>>>(ju, jv);
    k_tail<<<dim3((E_LBL + 255) / 256, 1, 1), b256, 0, stream>>>(
        Ucls, Vcls, ell_src, ell_dst,
        cw1, cb1, cw2, cb2, cw3, cb3, cw4, cb4, out, E_LBL);
  }
}

// Round 12
// 443.926 us; speedup vs baseline: 1.6585x; 1.0508x over previous
//
#include <hip/hip_runtime.h>
#include <hip/hip_fp16.h>

#define N_DRUG 20000
#define N_DIS  10000
#define N_ATTR 2000
#define T_ATTR 8
#define E_MT   500000
#define E_HA   100000
#define E_LBL  200000
#define HC     128
#define NB     16   // chunk blocks per edge segment in CSR build
#define BPW    2500 // bins per key-window
#define NSS    84   // sub-segments: 4 (z0) + 8 (z1) + 8 (z2..9) + 64 (z10..17)

__device__ __forceinline__ float leakyf(float x) { return x >= 0.f ? x : 0.01f * x; }

__device__ __forceinline__ unsigned short f2bf(float f) {
  unsigned int u = __float_as_uint(f);
  return (unsigned short)((u + 0x7fffu + ((u >> 16) & 1u)) >> 16);
}
__device__ __forceinline__ float bflo(unsigned int u) { return __uint_as_float(u << 16); }
__device__ __forceinline__ float bfhi(unsigned int u) { return __uint_as_float(u & 0xffff0000u); }

typedef __attribute__((ext_vector_type(8))) short bf16x8;
typedef __attribute__((ext_vector_type(4))) float f32x4;

// ---------------- CSR build ----------------
#define HB0 0
#define HB1 160000
#define HB2(t) (480000 + (t) * 32000)
#define HB10(t) (736000 + (t) * 320000)
#define WB0 0
#define WB1 10000
#define WB2(t) (30000 + (t) * 2000)
#define WB10(t) (46000 + (t) * 20000)
#define WTOT 206000
#define OFF_Z0 0
#define OFF_D  10001
#define OFF_Z2(t) (190002 + (t) * 2001)
#define OFF_TOT 206010
#define SCH 2048
#define SMAXC 128

struct SegB { int bins; int hbase; int wbase; int obase; int ostride; };
__device__ __forceinline__ SegB segb(int z) {
  SegB s;
  if (z == 0)      { s.bins = N_DIS;  s.hbase = HB0;  s.wbase = WB0;  s.obase = OFF_Z0;    s.ostride = 1; }
  else if (z == 1) { s.bins = N_DRUG; s.hbase = HB1;  s.wbase = WB1;  s.obase = OFF_D;     s.ostride = 9; }
  else if (z < 10) { int t = z - 2;  s.bins = N_ATTR; s.hbase = HB2(t);  s.wbase = WB2(t);  s.obase = OFF_Z2(t);   s.ostride = 1; }
  else             { int t = z - 10; s.bins = N_DRUG; s.hbase = HB10(t); s.wbase = WB10(t); s.obase = OFF_D + 1 + t; s.ostride = 9; }
  return s;
}

struct SegE { const int* key; const int* oth; int n; int roff; int* val; };
__device__ __forceinline__ SegE sege(int z,
    const int* mt_src, const int* mt_dst, const int* ha_src, const int* ha_dst,
    int* vmd, int* vdrug, int* vhd) {
  SegE s;
  if (z == 0)      { s.key = mt_dst; s.oth = mt_src; s.n = E_MT; s.roff = 0; s.val = vmd; }
  else if (z == 1) { s.key = mt_src; s.oth = mt_dst; s.n = E_MT; s.roff = 0; s.val = vdrug; }
  else if (z < 10) { int t = z - 2;
    s.key = ha_dst + (size_t)t * E_HA; s.oth = ha_src + (size_t)t * E_HA; s.n = E_HA;
    s.roff = 0; s.val = vhd + (size_t)t * E_HA; }
  else { int t = z - 10;
    s.key = ha_src + (size_t)t * E_HA; s.oth = ha_dst + (size_t)t * E_HA; s.n = E_HA;
    s.roff = 10000 + t * N_ATTR; s.val = vdrug; }
  return s;
}

// sub-segment -> (z, key-window lo)
__device__ __forceinline__ void ss_resolve(int ss, int& z, int& klo) {
  if (ss < 4)       { z = 0; klo = ss * BPW; }
  else if (ss < 12) { z = 1; klo = (ss - 4) * BPW; }
  else if (ss < 20) { z = 2 + (ss - 12); klo = 0; }
  else              { z = 10 + ((ss - 20) >> 3); klo = ((ss - 20) & 7) * BPW; }
}

__global__ __launch_bounds__(256) void k_hist(
    const int* __restrict__ mt_src, const int* __restrict__ mt_dst,
    const int* __restrict__ ha_src, const int* __restrict__ ha_dst,
    int* __restrict__ hist) {
  int z, klo;
  ss_resolve(blockIdx.z, z, klo);
  SegB g = segb(z);
  SegE s = sege(z, mt_src, mt_dst, ha_src, ha_dst, nullptr, nullptr, nullptr);
  int window = min(BPW, g.bins - klo);
  __shared__ int h[BPW];
  int tid = threadIdx.x, b = blockIdx.x;
  for (int i = tid; i < window; i += 256) h[i] = 0;
  __syncthreads();
  int ch = (s.n + NB - 1) / NB;
  int lo = b * ch, hi = min(s.n, lo + ch);
  for (int i = lo + tid; i < hi; i += 256) {
    int r = s.key[i] - klo;
    if ((unsigned)r < (unsigned)window) atomicAdd(&h[r], 1);
  }
  __syncthreads();
  int* hz = hist + g.hbase + (size_t)b * g.bins + klo;
  for (int i = tid; i < window; i += 256) hz[i] = h[i];
}

__global__ __launch_bounds__(256) void k_blkpfx(int* __restrict__ hist, int* __restrict__ off,
                                                unsigned short* __restrict__ wtab) {
  SegB g = segb(blockIdx.z);
  int i = blockIdx.x * 256 + threadIdx.x;
  if (i >= g.bins) return;
  int run = 0;
  #pragma unroll
  for (int b = 0; b < NB; b++) {
    int idx = g.hbase + b * g.bins + i;
    int v = hist[idx];
    hist[idx] = run;
    run += v;
  }
  off[g.obase + i * g.ostride] = run;
  __half hw = __float2half(1.0f / (float)(run > 0 ? run : 1));
  wtab[g.wbase + i] = __half_as_ushort(hw);
}

__device__ __forceinline__ void scan_region(int r, int& base, int& L) {
  if (r == 0)      { base = OFF_Z0; L = 10000; }
  else if (r == 1) { base = OFF_D;  L = 180000; }
  else             { int t = r - 2; base = OFF_Z2(t); L = 2000; }
}

__global__ __launch_bounds__(256) void k_scan_l1(int* __restrict__ off, int* __restrict__ csum) {
  int base, L;
  scan_region(blockIdx.y, base, L);
  int c = blockIdx.x;
  int c0 = c * SCH;
  if (c0 >= L) return;
  int tid = threadIdx.x;
  int i0 = c0 + tid * 8;
  int v[8];
  int s = 0;
  #pragma unroll
  for (int j = 0; j < 8; j++) {
    int i = i0 + j;
    v[j] = (i < L) ? off[base + i] : 0;
    s += v[j];
  }
  __shared__ int ssum[256];
  ssum[tid] = s;
  __syncthreads();
  if (tid == 0) {
    int run = 0;
    #pragma unroll 8
    for (int i = 0; i < 256; i++) { int x = ssum[i]; ssum[i] = run; run += x; }
    csum[blockIdx.y * SMAXC + c] = run;
  }
  __syncthreads();
  int run = ssum[tid];
  #pragma unroll
  for (int j = 0; j < 8; j++) {
    int i = i0 + j;
    if (i < L) { off[base + i] = run; run += v[j]; }
  }
}

__global__ void k_scan_l2(int* __restrict__ off, int* __restrict__ csum) {
  int r = blockIdx.x;
  int base, L;
  scan_region(r, base, L);
  if (threadIdx.x == 0) {
    int nc = (L + SCH - 1) / SCH;
    int run = 0;
    for (int c = 0; c < nc; c++) {
      int v = csum[r * SMAXC + c];
      csum[r * SMAXC + c] = run;
      run += v;
    }
    off[base + L] = run;
  }
}

__global__ __launch_bounds__(256) void k_scan_l3(int* __restrict__ off, const int* __restrict__ csum) {
  int base, L;
  scan_region(blockIdx.y, base, L);
  int c = blockIdx.x;
  int c0 = c * SCH;
  if (c0 >= L || c == 0) return;
  int add = csum[blockIdx.y * SMAXC + c];
  int i0 = c0 + threadIdx.x * 8;
  #pragma unroll
  for (int j = 0; j < 8; j++) {
    int i = i0 + j;
    if (i < L) off[base + i] += add;
  }
}

__global__ __launch_bounds__(256) void k_fill2(
    const int* __restrict__ mt_src, const int* __restrict__ mt_dst,
    const int* __restrict__ ha_src, const int* __restrict__ ha_dst,
    const int* __restrict__ hist, const int* __restrict__ off,
    const unsigned short* __restrict__ wtab,
    int* vmd, int* vdrug, int* vhd) {
  int z, klo;
  ss_resolve(blockIdx.z, z, klo);
  SegB g = segb(z);
  SegE s = sege(z, mt_src, mt_dst, ha_src, ha_dst, vmd, vdrug, vhd);
  int window = min(BPW, g.bins - klo);
  __shared__ int h[BPW];
  __shared__ unsigned short hw[BPW];
  int tid = threadIdx.x, b = blockIdx.x;
  const int* hz = hist + g.hbase + (size_t)b * g.bins + klo;
  for (int i = tid; i < window; i += 256) {
    h[i] = hz[i] + off[g.obase + (klo + i) * g.ostride];
    hw[i] = wtab[g.wbase + klo + i];
  }
  __syncthreads();
  int ch = (s.n + NB - 1) / NB;
  int lo = b * ch, hi = min(s.n, lo + ch);
  for (int i = lo + tid; i < hi; i += 256) {
    int r = s.key[i] - klo;
    if ((unsigned)r < (unsigned)window) {
      int pos = atomicAdd(&h[r], 1);
      s.val[pos] = (int)(((unsigned int)hw[r] << 16) | (unsigned int)(s.oth[i] + s.roff));
    }
  }
}

// ---------------- x_dis init (dual f32 + bf16) ----------------
__global__ void k_dis0(const float* __restrict__ dx, const float* __restrict__ w,
                       const float* __restrict__ b, const float* __restrict__ emb,
                       float* __restrict__ out, unsigned short* __restrict__ outb) {
  int i = blockIdx.x;
  int j = threadIdx.x;
  float s = b[j] + emb[(size_t)i * HC + j];
  #pragma unroll
  for (int k = 0; k < 10; k++) s += dx[i * 10 + k] * w[k * HC + j];
  out[(size_t)i * HC + j] = s;
  outb[(size_t)i * HC + j] = f2bf(s);
}

// ---------------- Wct = bf16 transpose of (rmt_wr + sum_t rha_wr); biasc (per layer) ----------------
__global__ void k_wc(const float* __restrict__ rmt_wr, const float* __restrict__ rha_wr,
                     const float* __restrict__ rmt_bl, const float* __restrict__ rha_bl,
                     unsigned short* __restrict__ Wct, float* __restrict__ biasc) {
  int l = blockIdx.y;
  const float* wr_main = rmt_wr + (size_t)l * HC * HC;
  const float* wr_t = rha_wr + (size_t)l * T_ATTR * HC * HC;
  const float* bl_main = rmt_bl + (size_t)l * HC;
  const float* bl_t = rha_bl + (size_t)l * T_ATTR * HC;
  unsigned short* Wo = Wct + (size_t)l * 16384;
  float* bo = biasc + (size_t)l * 128;
  int i = blockIdx.x * blockDim.x + threadIdx.x;
  if (i < HC * HC) {
    float s = wr_main[i];
    #pragma unroll
    for (int t = 0; t < T_ATTR; t++) s += wr_t[(size_t)t * HC * HC + i];
    int k = i >> 7, n = i & 127;
    Wo[n * 128 + k] = f2bf(s);
  }
  if (i < HC) {
    float s = bl_main[i];
    #pragma unroll
    for (int t = 0; t < T_ATTR; t++) s += bl_t[t * HC + i];
    bo[i] = s;
  }
}

// ---------------- weight transpose f32 [128][128] -> bf16 Wt[n][k], 54 mats ----------------
struct WtJobs { const float* s[54]; };
__global__ __launch_bounds__(256) void k_wt(WtJobs J, unsigned short* __restrict__ dst) {
  const float* src = J.s[blockIdx.z];
  unsigned short* d = dst + (size_t)blockIdx.z * 16384;
  __shared__ float t[32][33];
  int tx = threadIdx.x & 31, ty = threadIdx.x >> 5;
  int i0 = blockIdx.x * 32, j0 = blockIdx.y * 32;
  #pragma unroll
  for (int q = 0; q < 4; q++) {
    int k = i0 + ty + q * 8;
    t[ty + q * 8][tx] = src[k * 128 + j0 + tx];
  }
  __syncthreads();
  #pragma unroll
  for (int q = 0; q < 4; q++) {
    int n = j0 + ty + q * 8;
    d[(size_t)n * 128 + i0 + tx] = f2bf(t[tx][ty + q * 8]);
  }
}

// ---------------- f32 -> bf16 convert ----------------
__global__ __launch_bounds__(256) void k_cvt(const float* __restrict__ src,
                                             unsigned short* __restrict__ dst, int n4) {
  int i = blockIdx.x * 256 + threadIdx.x;
  if (i >= n4) return;
  float4 v = ((const float4*)src)[i];
  uint2 w;
  w.x = (unsigned int)f2bf(v.x) | ((unsigned int)f2bf(v.y) << 16);
  w.y = (unsigned int)f2bf(v.z) | ((unsigned int)f2bf(v.w) << 16);
  ((uint2*)dst)[i] = w;
}

// ---------------- weighted gather ----------------
__device__ __forceinline__ void gacc_w(const unsigned short* __restrict__ T, const int* __restrict__ val,
                                       int b, int e, int lane, float& ax, float& ay) {
  int i = b;
  for (; i + 8 <= e; i += 8) {
    unsigned int pv[8], rv[8];
    #pragma unroll
    for (int q = 0; q < 8; q++) pv[q] = ((const unsigned int*)val)[i + q];
    #pragma unroll
    for (int q = 0; q < 8; q++)
      rv[q] = ((const unsigned int*)(T + (size_t)(pv[q] & 0xffffu) * HC))[lane];
    #pragma unroll
    for (int q = 0; q < 8; q++) {
      float w = __half2float(__ushort_as_half((unsigned short)(pv[q] >> 16)));
      ax = fmaf(w, bflo(rv[q]), ax);
      ay = fmaf(w, bfhi(rv[q]), ay);
    }
  }
  for (; i < e; i++) {
    unsigned int pv = ((const unsigned int*)val)[i];
    unsigned int rv = ((const unsigned int*)(T + (size_t)(pv & 0xffffu) * HC))[lane];
    float w = __half2float(__ushort_as_half((unsigned short)(pv >> 16)));
    ax = fmaf(w, bflo(rv), ax);
    ay = fmaf(w, bfhi(rv), ay);
  }
}

// ---------------- mega segment-mean ----------------
__global__ __launch_bounds__(256) void k_seg_mega(
    const int* __restrict__ off,
    const int* __restrict__ vmd, const int* __restrict__ vdrug, const int* __restrict__ vhd,
    const unsigned short* __restrict__ xdb, const unsigned short* __restrict__ Ytab,
    unsigned short* __restrict__ m2disb, float* __restrict__ accd, unsigned short* __restrict__ m2ab) {
  int lane = threadIdx.x & 63;
  int lane2 = lane * 2;
  int w = blockIdx.x * 4 + (threadIdx.x >> 6);
  if (w < N_DIS) {
    int lo = off[OFF_Z0 + w], hi = off[OFF_Z0 + w + 1];
    float ax = 0.f, ay = 0.f;
    gacc_w(xdb, vmd, lo, hi, lane, ax, ay);
    *(unsigned int*)(m2disb + (size_t)w * HC + lane2) =
        (unsigned int)f2bf(ax) | ((unsigned int)f2bf(ay) << 16);
  } else if (w < N_DIS + N_DRUG) {
    int d = w - N_DIS;
    int lo = off[OFF_D + d * 9], hi = off[OFF_D + d * 9 + 9];
    float ax = 0.f, ay = 0.f;
    gacc_w(Ytab, vdrug, lo, hi, lane, ax, ay);
    *(float2*)(accd + (size_t)d * HC + lane2) = make_float2(ax, ay);
  } else {
    int idx = w - (N_DIS + N_DRUG);
    int t = idx / N_ATTR, r = idx - t * N_ATTR;
    int lo = off[OFF_Z2(t) + r], hi = off[OFF_Z2(t) + r + 1];
    float ax = 0.f, ay = 0.f;
    gacc_w(xdb, vhd + (size_t)t * E_HA, lo, hi, lane, ax, ay);
    *(unsigned int*)(m2ab + ((size_t)t * N_ATTR + r) * HC + lane2) =
        (unsigned int)f2bf(ax) | ((unsigned int)f2bf(ay) << 16);
  }
}

// ---------------- MFMA GEMM with optional dual (f32 + bf16) output ----------------
struct MJob {
  const unsigned short* X1; const unsigned short* Wt1;
  const unsigned short* X2; const unsigned short* Wt2;
  const float* bias; const float* ACC;
  float* D; unsigned short* D2;
  int M; int leaky; int bf16out;
};
struct MJobs { MJob j[10]; };

__global__ __launch_bounds__(256) void k_gemm_mfma(MJobs jobs) {
  MJob jb = jobs.j[blockIdx.z];
  int m0 = blockIdx.x * 64;
  if (m0 >= jb.M) return;
  int wave = threadIdx.x >> 6;
  int lane = threadIdx.x & 63;
  int l15 = lane & 15, g = lane >> 4;
  int m = m0 + wave * 16 + l15;
  bool mok = m < jb.M;
  int mrow = mok ? m : 0;

  f32x4 acc[8] = {};
  #pragma unroll
  for (int part = 0; part < 2; part++) {
    const unsigned short* X = part ? jb.X2 : jb.X1;
    const unsigned short* Wt = part ? jb.Wt2 : jb.Wt1;
    if (!X) break;
    #pragma unroll
    for (int ks = 0; ks < 4; ks++) {
      int k0 = ks * 32 + g * 8;
      bf16x8 xb = {};
      if (mok) xb = *(const bf16x8*)(X + (size_t)mrow * 128 + k0);
      #pragma unroll
      for (int f = 0; f < 8; f++) {
        bf16x8 wb = *(const bf16x8*)(Wt + (size_t)(f * 16 + l15) * 128 + k0);
        acc[f] = __builtin_amdgcn_mfma_f32_16x16x32_bf16(wb, xb, acc[f], 0, 0, 0);
      }
    }
  }
  if (!mok) return;
  #pragma unroll
  for (int f = 0; f < 8; f++) {
    int n0 = f * 16 + 4 * g;
    float r0 = acc[f][0], r1 = acc[f][1], r2 = acc[f][2], r3 = acc[f][3];
    if (jb.bias) {
      float4 bs = *(const float4*)(jb.bias + n0);
      r0 += bs.x; r1 += bs.y; r2 += bs.z; r3 += bs.w;
    }
    if (jb.ACC) {
      float4 a = *(const float4*)(jb.ACC + (size_t)m * 128 + n0);
      r0 += a.x; r1 += a.y; r2 += a.z; r3 += a.w;
    }
    if (jb.leaky) { r0 = leakyf(r0); r1 = leakyf(r1); r2 = leakyf(r2); r3 = leakyf(r3); }
    if (jb.bf16out) {
      unsigned short* Db = (unsigned short*)jb.D;
      uint2 w;
      w.x = (unsigned int)f2bf(r0) | ((unsigned int)f2bf(r1) << 16);
      w.y = (unsigned int)f2bf(r2) | ((unsigned int)f2bf(r3) << 16);
      *(uint2*)(Db + (size_t)m * 128 + n0) = w;
    } else {
      *(float4*)(jb.D + (size_t)m * 128 + n0) = make_float4(r0, r1, r2, r3);
      if (jb.D2) {
        uint2 w;
        w.x = (unsigned int)f2bf(r0) | ((unsigned int)f2bf(r1) << 16);
        w.y = (unsigned int)f2bf(r2) | ((unsigned int)f2bf(r3) << 16);
        *(uint2*)(jb.D2 + (size_t)m * 128 + n0) = w;
      }
    }
  }
}

// ---------------- classifier head GEMMs ----------------
struct G64Job { const float* X; const float* W; const float* bias; float* D; int M; };

__global__ __launch_bounds__(256) void k_gemm64(G64Job j0, G64Job j1) {
  G64Job jb = blockIdx.z ? j1 : j0;
  int m0 = blockIdx.x * 64;
  if (m0 >= jb.M) return;
  __shared__ float As[16][68];
  __shared__ float Bs[16][68];
  int tid = threadIdx.x;
  int tx = tid & 15, ty = tid >> 4;
  float acc[4][4];
  #pragma unroll
  for (int i = 0; i < 4; i++)
    #pragma unroll
    for (int j = 0; j < 4; j++) acc[i][j] = 0.f;

  for (int kk = 0; kk < 128; kk += 16) {
    {
      int r = tid >> 2, kq = (tid & 3) * 4;
      int gr = m0 + r;
      float4 v = make_float4(0.f, 0.f, 0.f, 0.f);
      if (gr < jb.M) v = *(const float4*)(jb.X + (size_t)gr * HC + kk + kq);
      As[kq + 0][r] = v.x; As[kq + 1][r] = v.y; As[kq + 2][r] = v.z; As[kq + 3][r] = v.w;
    }
    {
      int k = tid >> 4, c = (tid & 15) * 4;
      *(float4*)&Bs[k][c] = *(const float4*)(jb.W + (size_t)(kk + k) * 64 + c);
    }
    __syncthreads();
    #pragma unroll
    for (int k = 0; k < 16; k++) {
      float4 a = *(const float4*)&As[k][ty * 4];
      float4 b = *(const float4*)&Bs[k][tx * 4];
      float av[4] = {a.x, a.y, a.z, a.w};
      float bb[4] = {b.x, b.y, b.z, b.w};
      #pragma unroll
      for (int i = 0; i < 4; i++)
        #pragma unroll
        for (int j = 0; j < 4; j++) acc[i][j] += av[i] * bb[j];
    }
    __syncthreads();
  }
  float4 bs = make_float4(0.f, 0.f, 0.f, 0.f);
  if (jb.bias) bs = *(const float4*)(jb.bias + tx * 4);
  #pragma unroll
  for (int i = 0; i < 4; i++) {
    int gr = m0 + ty * 4 + i;
    if (gr < jb.M) {
      float4 r = make_float4(acc[i][0] + bs.x, acc[i][1] + bs.y, acc[i][2] + bs.z, acc[i][3] + bs.w);
      *(float4*)(jb.D + (size_t)gr * 64 + tx * 4) = r;
    }
  }
}

// ---------------- per-edge tail MLP ----------------
__global__ __launch_bounds__(256) void k_tail(
    const float* __restrict__ U, const float* __restrict__ V,
    const int* __restrict__ es, const int* __restrict__ ed,
    const float* __restrict__ cw1, const float* __restrict__ cb1,
    const float* __restrict__ cw2, const float* __restrict__ cb2,
    const float* __restrict__ cw3, const float* __restrict__ cb3,
    const float* __restrict__ cw4, const float* __restrict__ cb4,
    float* __restrict__ out, int n) {
  __shared__ float w1[64 * 32];
  __shared__ float w2[32 * 16];
  __shared__ float w3[16 * 8];
  __shared__ float w4[8];
  __shared__ float b1[32], b2[16], b3[8];
  int tid = threadIdx.x;
  #pragma unroll
  for (int q = 0; q < 8; q++) w1[tid + q * 256] = cw1[tid + q * 256];
  #pragma unroll
  for (int q = 0; q < 2; q++) w2[tid + q * 256] = cw2[tid + q * 256];
  if (tid < 128) w3[tid] = cw3[tid];
  if (tid < 8)  w4[tid] = cw4[tid];
  if (tid < 32) b1[tid] = cb1[tid];
  if (tid < 16) b2[tid] = cb2[tid];
  if (tid < 8)  b3[tid] = cb3[tid];
  __syncthreads();
  int i = blockIdx.x * 256 + tid;
  if (i >= n) return;
  int s = es[i], d = ed[i];
  const float4* up = (const float4*)(U + (size_t)s * 64);
  const float4* vp = (const float4*)(V + (size_t)d * 64);
  float h1[64];
  #pragma unroll
  for (int q = 0; q < 16; q++) {
    float4 a = up[q], b = vp[q];
    h1[4 * q + 0] = leakyf(a.x + b.x);
    h1[4 * q + 1] = leakyf(a.y + b.y);
    h1[4 * q + 2] = leakyf(a.z + b.z);
    h1[4 * q + 3] = leakyf(a.w + b.w);
  }
  float h2[32];
  #pragma unroll
  for (int j = 0; j < 32; j++) h2[j] = b1[j];
  #pragma unroll
  for (int k = 0; k < 64; k++) {
    float hv = h1[k];
    #pragma unroll
    for (int jq = 0; jq < 8; jq++) {
      float4 w = *(const float4*)&w1[k * 32 + jq * 4];
      h2[4 * jq + 0] = fmaf(hv, w.x, h2[4 * jq + 0]);
      h2[4 * jq + 1] = fmaf(hv, w.y, h2[4 * jq + 1]);
      h2[4 * jq + 2] = fmaf(hv, w.z, h2[4 * jq + 2]);
      h2[4 * jq + 3] = fmaf(hv, w.w, h2[4 * jq + 3]);
    }
  }
  float h3[16];
  #pragma unroll
  for (int j = 0; j < 16; j++) h3[j] = b2[j];
  #pragma unroll
  for (int k = 0; k < 32; k++) {
    float hv = leakyf(h2[k]);
    #pragma unroll
    for (int jq = 0; jq < 4; jq++) {
      float4 w = *(const float4*)&w2[k * 16 + jq * 4];
      h3[4 * jq + 0] = fmaf(hv, w.x, h3[4 * jq + 0]);
      h3[4 * jq + 1] = fmaf(hv, w.y, h3[4 * jq + 1]);
      h3[4 * jq + 2] = fmaf(hv, w.z, h3[4 * jq + 2]);
      h3[4 * jq + 3] = fmaf(hv, w.w, h3[4 * jq + 3]);
    }
  }
  float h4[8];
  #pragma unroll
  for (int j = 0; j < 8; j++) h4[j] = b3[j];
  #pragma unroll
  for (int k = 0; k < 16; k++) {
    float hv = leakyf(h3[k]);
    #pragma unroll
    for (int jq = 0; jq < 2; jq++) {
      float4 w = *(const float4*)&w3[k * 8 + jq * 4];
      h4[4 * jq + 0] = fmaf(hv, w.x, h4[4 * jq + 0]);
      h4[4 * jq + 1] = fmaf(hv, w.y, h4[4 * jq + 1]);
      h4[4 * jq + 2] = fmaf(hv, w.z, h4[4 * jq + 2]);
      h4[4 * jq + 3] = fmaf(hv, w.w, h4[4 * jq + 3]);
    }
  }
  float p = cb4[0];
  #pragma unroll
  for (int k = 0; k < 8; k++) p = fmaf(leakyf(h4[k]), w4[k], p);
  out[i] = p;
}

extern "C" void kernel_launch(void* const* d_in, const int* in_sizes, int n_in,
                              void* d_out, int out_size, void* d_ws, size_t ws_size,
                              hipStream_t stream) {
  const float* disease_x   = (const float*)d_in[0];
  const float* drug_emb    = (const float*)d_in[1];
  const float* disease_emb = (const float*)d_in[2];
  const float* attr_emb    = (const float*)d_in[3];
  const float* dis_lin_w   = (const float*)d_in[4];
  const float* dis_lin_b   = (const float*)d_in[5];
  const float* mt_wl  = (const float*)d_in[6];
  const float* mt_bl  = (const float*)d_in[7];
  const float* mt_wr  = (const float*)d_in[8];
  const float* rmt_wl = (const float*)d_in[9];
  const float* rmt_bl = (const float*)d_in[10];
  const float* rmt_wr = (const float*)d_in[11];
  const float* ha_wl  = (const float*)d_in[12];
  const float* ha_bl  = (const float*)d_in[13];
  const float* ha_wr  = (const float*)d_in[14];
  const float* rha_wl = (const float*)d_in[15];
  const float* rha_bl = (const float*)d_in[16];
  const float* rha_wr = (const float*)d_in[17];
  const float* cw0 = (const float*)d_in[18];
  const float* cb0 = (const float*)d_in[19];
  const float* cw1 = (const float*)d_in[20];
  const float* cb1 = (const float*)d_in[21];
  const float* cw2 = (const float*)d_in[22];
  const float* cb2 = (const float*)d_in[23];
  const float* cw3 = (const float*)d_in[24];
  const float* cb3 = (const float*)d_in[25];
  const float* cw4 = (const float*)d_in[26];
  const float* cb4 = (const float*)d_in[27];
  const int* mt_src = (const int*)d_in[28];
  const int* mt_dst = (const int*)d_in[29];
  const int* ha_src = (const int*)d_in[30];
  const int* ha_dst = (const int*)d_in[31];
  const int* ell_src = (const int*)d_in[32];
  const int* ell_dst = (const int*)d_in[33];
  float* out = (float*)d_out;

  const long long ATTR_S = (long long)N_ATTR * HC;
  const long long W_S = HC * HC;

  // ---------- workspace carve ----------
  float* fws = (float*)d_ws;
  size_t o = 0;
  float* x_drug = fws + o; o += (size_t)N_DRUG * HC;
  float* x_dis  = fws + o; o += (size_t)N_DIS * HC;
  float* x_attr = fws + o; o += (size_t)T_ATTR * N_ATTR * HC;
  float* accd   = fws + o; o += (size_t)N_DRUG * HC;   // | accd+biasc+Ucls overlaid by hist
  float* biasc  = fws + o; o += 256;                   // | (3.296M ints) during CSR build
  float* Ucls   = fws + o; o += (size_t)N_DRUG * 64;
  float* Vcls   = fws + o; o += (size_t)N_DIS * 64;
  unsigned short* xdb    = (unsigned short*)(fws + o);
  unsigned short* Ytab   = xdb + (size_t)N_DRUG * HC;
  unsigned short* Ydisb  = Ytab;
  unsigned short* Yattrb = Ytab + (size_t)N_DIS * HC;
  unsigned short* xdisb  = Yattrb + (size_t)T_ATTR * N_ATTR * HC;
  unsigned short* xab    = xdisb + (size_t)N_DIS * HC;
  unsigned short* m2disb = xab + (size_t)T_ATTR * N_ATTR * HC;
  unsigned short* m2ab   = m2disb + (size_t)N_DIS * HC;
  unsigned short* Wts    = m2ab + (size_t)T_ATTR * N_ATTR * HC;  // 54 * 16384
  unsigned short* Wct    = Wts + 54 * 16384;                     // 2 * 16384
  unsigned short* ushort_end = Wct + 2 * 16384;
  o += ((size_t)(ushort_end - xdb) + 1) / 2;
  int* iws = (int*)(fws + o);
  int* off = iws;
  int* vmd   = off + OFF_TOT;
  int* vdrug = vmd + E_MT;
  int* vhd   = vdrug + (E_MT + T_ATTR * E_HA);
  unsigned short* wtab = (unsigned short*)(vhd + (size_t)T_ATTR * E_HA);
  int* csum = (int*)(wtab + WTOT + (WTOT & 1));
  int* hist = (int*)accd;

  dim3 b256(256);
  // ---------- CSR build (key-windowed sub-segments, 15KB LDS) ----------
  k_hist<<<dim3(NB, 1, NSS), b256, 0, stream>>>(mt_src, mt_dst, ha_src, ha_dst, hist);
  k_blkpfx<<<dim3((N_DRUG + 255) / 256, 1, 18), b256, 0, stream>>>(hist, off, wtab);
  {
    dim3 sg((180000 + SCH - 1) / SCH, 10);
    k_scan_l1<<<sg, b256, 0, stream>>>(off, csum);
    k_scan_l2<<<10, 64, 0, stream>>>(off, csum);
    k_scan_l3<<<sg, b256, 0, stream>>>(off, csum);
  }
  k_fill2<<<dim3(NB, 1, NSS), b256, 0, stream>>>(mt_src, mt_dst, ha_src, ha_dst, hist, off, wtab,
                                                 vmd, vdrug, vhd);

  // ---------- weights for both layers (batched) ----------
  k_wc<<<dim3(64, 2), b256, 0, stream>>>(rmt_wr, rha_wr, rmt_bl, rha_bl, Wct, biasc);
  {
    WtJobs W{};
    for (int l = 0; l < 2; l++) {
      const float* rmt_wl_l = rmt_wl + (size_t)l * W_S;
      const float* rha_wl_l = rha_wl + (size_t)l * T_ATTR * W_S;
      const float* mt_wl_l  = mt_wl  + (size_t)l * W_S;
      const float* mt_wr_l  = mt_wr  + (size_t)l * W_S;
      const float* ha_wl_l  = ha_wl  + (size_t)l * T_ATTR * W_S;
      const float* ha_wr_l  = ha_wr  + (size_t)l * T_ATTR * W_S;
      int base = l * 27;
      W.s[base + 0] = rmt_wl_l;
      for (int t = 0; t < T_ATTR; t++) W.s[base + 1 + t] = rha_wl_l + (size_t)t * W_S;
      W.s[base + 9] = mt_wl_l;
      W.s[base + 10] = mt_wr_l;
      for (int t = 0; t < T_ATTR; t++) W.s[base + 11 + t] = ha_wl_l + (size_t)t * W_S;
      for (int t = 0; t < T_ATTR; t++) W.s[base + 19 + t] = ha_wr_l + (size_t)t * W_S;
    }
    k_wt<<<dim3(4, 4, 54), b256, 0, stream>>>(W, Wts);
  }

  // ---------- node init + initial bf16 copies ----------
  k_dis0<<<N_DIS, 128, 0, stream>>>(disease_x, dis_lin_w, dis_lin_b, disease_emb, x_dis, xdisb);
  k_cvt<<<dim3((N_DRUG * HC / 4 + 255) / 256), b256, 0, stream>>>(drug_emb, xdb, N_DRUG * HC / 4);
  k_cvt<<<dim3((T_ATTR * N_ATTR * HC / 4 + 255) / 256), b256, 0, stream>>>(attr_emb, xab, T_ATTR * N_ATTR * HC / 4);

  for (int l = 0; l < 2; l++) {
    const float* mt_bl_l  = mt_bl  + (size_t)l * HC;
    const float* ha_bl_l  = ha_bl  + (size_t)l * T_ATTR * HC;
    const unsigned short* Wts_l = Wts + (size_t)l * 27 * 16384;
    const unsigned short* Wct_l = Wct + (size_t)l * 16384;
    const float* biasc_l = biasc + (size_t)l * 128;

    // pre-transform GEMMs (MFMA): Ydisb = x_dis@rmt_wl, Yattrb_t = xa_t@rha_wl_t (bf16 out)
    {
      MJobs J{};
      J.j[0] = {xdisb, Wts_l + 0 * 16384, nullptr, nullptr, nullptr, nullptr, (float*)Ydisb, nullptr, N_DIS, 0, 1};
      for (int t = 0; t < T_ATTR; t++)
        J.j[1 + t] = {xab + (size_t)t * ATTR_S, Wts_l + (size_t)(1 + t) * 16384,
                      nullptr, nullptr, nullptr, nullptr,
                      (float*)(Yattrb + (size_t)t * ATTR_S), nullptr, N_ATTR, 0, 1};
      k_gemm_mfma<<<dim3((N_DIS + 63) / 64, 1, 9), b256, 0, stream>>>(J);
    }

    // gathers
    k_seg_mega<<<dim3((46000 + 3) / 4, 1, 1), b256, 0, stream>>>(
        off, vmd, vdrug, vhd, xdb, Ytab, m2disb, accd, m2ab);

    // combine GEMMs (MFMA, f32 out + leaky, dual bf16 out for next layer)
    {
      MJobs J{};
      J.j[0] = {xdb, Wct_l, nullptr, nullptr, biasc_l, accd, x_drug, xdb, N_DRUG, 1, 0};
      J.j[1] = {m2disb, Wts_l + 9 * 16384, xdisb, Wts_l + 10 * 16384, mt_bl_l, nullptr, x_dis, xdisb, N_DIS, 1, 0};
      for (int t = 0; t < T_ATTR; t++)
        J.j[2 + t] = {m2ab + (size_t)t * ATTR_S, Wts_l + (size_t)(11 + t) * 16384,
                      xab + (size_t)t * ATTR_S, Wts_l + (size_t)(19 + t) * 16384,
                      ha_bl_l + (size_t)t * HC, nullptr, x_attr + (size_t)t * ATTR_S,
                      xab + (size_t)t * ATTR_S, N_ATTR, 1, 0};
      k_gemm_mfma<<<dim3((N_DRUG + 63) / 64, 1, 10), b256, 0, stream>>>(J);
    }
  }

  // ---------- classifier ----------
  {
    G64Job ju = {x_drug, cw0, cb0, Ucls, N_DRUG};
    G64Job jv = {x_dis, cw0 + 128 * 64, nullptr, Vcls, N_DIS};
    k_gemm64<<<dim3((N_DRUG + 63) / 64, 1, 2), b256, 0, stream>>>(ju, jv);
    k_tail<<<dim3((E_LBL + 255) / 256, 1, 1), b256, 0, stream>>>(
        Ucls, Vcls, ell_src, ell_dst,
        cw1, cb1, cw2, cb2, cw3, cb3, cw4, cb4, out, E_LBL);
  }
}

// Round 13
// 437.381 us; speedup vs baseline: 1.6834x; 1.0150x over previous
//
#include <hip/hip_runtime.h>
#include <hip/hip_fp16.h>

#define N_DRUG 20000
#define N_DIS  10000
#define N_ATTR 2000
#define T_ATTR 8
#define E_MT   500000
#define E_HA   100000
#define E_LBL  200000
#define HC     128
#define NB     16   // chunk blocks per edge segment in CSR build
#define BPW    2500 // bins per key-window
#define NSS    84   // sub-segments

__device__ __forceinline__ float leakyf(float x) { return x >= 0.f ? x : 0.01f * x; }

__device__ __forceinline__ unsigned short f2bf(float f) {
  unsigned int u = __float_as_uint(f);
  return (unsigned short)((u + 0x7fffu + ((u >> 16) & 1u)) >> 16);
}
__device__ __forceinline__ float bflo(unsigned int u) { return __uint_as_float(u << 16); }
__device__ __forceinline__ float bfhi(unsigned int u) { return __uint_as_float(u & 0xffff0000u); }

typedef __attribute__((ext_vector_type(8))) short bf16x8;
typedef __attribute__((ext_vector_type(4))) float f32x4;

// ---------------- CSR build ----------------
#define HB0 0
#define HB1 160000
#define HB2(t) (480000 + (t) * 32000)
#define HB10(t) (736000 + (t) * 320000)
#define WB0 0
#define WB1 10000
#define WB2(t) (30000 + (t) * 2000)
#define WB10(t) (46000 + (t) * 20000)
#define WTOT 206000
#define OFF_Z0 0
#define OFF_D  10001
#define OFF_Z2(t) (190002 + (t) * 2001)
#define OFF_TOT 206010
#define SCH 2048
#define SMAXC 128

struct SegB { int bins; int hbase; int wbase; int obase; int ostride; };
__device__ __forceinline__ SegB segb(int z) {
  SegB s;
  if (z == 0)      { s.bins = N_DIS;  s.hbase = HB0;  s.wbase = WB0;  s.obase = OFF_Z0;    s.ostride = 1; }
  else if (z == 1) { s.bins = N_DRUG; s.hbase = HB1;  s.wbase = WB1;  s.obase = OFF_D;     s.ostride = 9; }
  else if (z < 10) { int t = z - 2;  s.bins = N_ATTR; s.hbase = HB2(t);  s.wbase = WB2(t);  s.obase = OFF_Z2(t);   s.ostride = 1; }
  else             { int t = z - 10; s.bins = N_DRUG; s.hbase = HB10(t); s.wbase = WB10(t); s.obase = OFF_D + 1 + t; s.ostride = 9; }
  return s;
}

struct SegE { const int* key; const int* oth; int n; int roff; int* val; };
__device__ __forceinline__ SegE sege(int z,
    const int* mt_src, const int* mt_dst, const int* ha_src, const int* ha_dst,
    int* vmd, int* vdrug, int* vhd) {
  SegE s;
  if (z == 0)      { s.key = mt_dst; s.oth = mt_src; s.n = E_MT; s.roff = 0; s.val = vmd; }
  else if (z == 1) { s.key = mt_src; s.oth = mt_dst; s.n = E_MT; s.roff = 0; s.val = vdrug; }
  else if (z < 10) { int t = z - 2;
    s.key = ha_dst + (size_t)t * E_HA; s.oth = ha_src + (size_t)t * E_HA; s.n = E_HA;
    s.roff = 0; s.val = vhd + (size_t)t * E_HA; }
  else { int t = z - 10;
    s.key = ha_src + (size_t)t * E_HA; s.oth = ha_dst + (size_t)t * E_HA; s.n = E_HA;
    s.roff = 10000 + t * N_ATTR; s.val = vdrug; }
  return s;
}

__device__ __forceinline__ void ss_resolve(int ss, int& z, int& klo) {
  if (ss < 4)       { z = 0; klo = ss * BPW; }
  else if (ss < 12) { z = 1; klo = (ss - 4) * BPW; }
  else if (ss < 20) { z = 2 + (ss - 12); klo = 0; }
  else              { z = 10 + ((ss - 20) >> 3); klo = ((ss - 20) & 7) * BPW; }
}

__global__ __launch_bounds__(256) void k_hist(
    const int* __restrict__ mt_src, const int* __restrict__ mt_dst,
    const int* __restrict__ ha_src, const int* __restrict__ ha_dst,
    int* __restrict__ hist) {
  int z, klo;
  ss_resolve(blockIdx.z, z, klo);
  SegB g = segb(z);
  SegE s = sege(z, mt_src, mt_dst, ha_src, ha_dst, nullptr, nullptr, nullptr);
  int window = min(BPW, g.bins - klo);
  __shared__ int h[BPW];
  int tid = threadIdx.x, b = blockIdx.x;
  for (int i = tid; i < window; i += 256) h[i] = 0;
  __syncthreads();
  int ch = (s.n + NB - 1) / NB;
  int lo = b * ch, hi = min(s.n, lo + ch);
  for (int i = lo + tid; i < hi; i += 256) {
    int r = s.key[i] - klo;
    if ((unsigned)r < (unsigned)window) atomicAdd(&h[r], 1);
  }
  __syncthreads();
  int* hz = hist + g.hbase + (size_t)b * g.bins + klo;
  for (int i = tid; i < window; i += 256) hz[i] = h[i];
}

__global__ __launch_bounds__(256) void k_blkpfx(int* __restrict__ hist, int* __restrict__ off,
                                                unsigned short* __restrict__ wtab) {
  SegB g = segb(blockIdx.z);
  int i = blockIdx.x * 256 + threadIdx.x;
  if (i >= g.bins) return;
  int run = 0;
  #pragma unroll
  for (int b = 0; b < NB; b++) {
    int idx = g.hbase + b * g.bins + i;
    int v = hist[idx];
    hist[idx] = run;
    run += v;
  }
  off[g.obase + i * g.ostride] = run;
  __half hw = __float2half(1.0f / (float)(run > 0 ? run : 1));
  wtab[g.wbase + i] = __half_as_ushort(hw);
}

__device__ __forceinline__ void scan_region(int r, int& base, int& L) {
  if (r == 0)      { base = OFF_Z0; L = 10000; }
  else if (r == 1) { base = OFF_D;  L = 180000; }
  else             { int t = r - 2; base = OFF_Z2(t); L = 2000; }
}

__global__ __launch_bounds__(256) void k_scan_l1(int* __restrict__ off, int* __restrict__ csum) {
  int base, L;
  scan_region(blockIdx.y, base, L);
  int c = blockIdx.x;
  int c0 = c * SCH;
  if (c0 >= L) return;
  int tid = threadIdx.x;
  int i0 = c0 + tid * 8;
  int v[8];
  int s = 0;
  #pragma unroll
  for (int j = 0; j < 8; j++) {
    int i = i0 + j;
    v[j] = (i < L) ? off[base + i] : 0;
    s += v[j];
  }
  __shared__ int ssum[256];
  ssum[tid] = s;
  __syncthreads();
  if (tid == 0) {
    int run = 0;
    #pragma unroll 8
    for (int i = 0; i < 256; i++) { int x = ssum[i]; ssum[i] = run; run += x; }
    csum[blockIdx.y * SMAXC + c] = run;
  }
  __syncthreads();
  int run = ssum[tid];
  #pragma unroll
  for (int j = 0; j < 8; j++) {
    int i = i0 + j;
    if (i < L) { off[base + i] = run; run += v[j]; }
  }
}

__global__ void k_scan_l2(int* __restrict__ off, int* __restrict__ csum) {
  int r = blockIdx.x;
  int base, L;
  scan_region(r, base, L);
  if (threadIdx.x == 0) {
    int nc = (L + SCH - 1) / SCH;
    int run = 0;
    for (int c = 0; c < nc; c++) {
      int v = csum[r * SMAXC + c];
      csum[r * SMAXC + c] = run;
      run += v;
    }
    off[base + L] = run;
  }
}

__global__ __launch_bounds__(256) void k_scan_l3(int* __restrict__ off, const int* __restrict__ csum) {
  int base, L;
  scan_region(blockIdx.y, base, L);
  int c = blockIdx.x;
  int c0 = c * SCH;
  if (c0 >= L || c == 0) return;
  int add = csum[blockIdx.y * SMAXC + c];
  int i0 = c0 + threadIdx.x * 8;
  #pragma unroll
  for (int j = 0; j < 8; j++) {
    int i = i0 + j;
    if (i < L) off[base + i] += add;
  }
}

__global__ __launch_bounds__(256) void k_fill2(
    const int* __restrict__ mt_src, const int* __restrict__ mt_dst,
    const int* __restrict__ ha_src, const int* __restrict__ ha_dst,
    const int* __restrict__ hist, const int* __restrict__ off,
    const unsigned short* __restrict__ wtab,
    int* vmd, int* vdrug, int* vhd) {
  int z, klo;
  ss_resolve(blockIdx.z, z, klo);
  SegB g = segb(z);
  SegE s = sege(z, mt_src, mt_dst, ha_src, ha_dst, vmd, vdrug, vhd);
  int window = min(BPW, g.bins - klo);
  __shared__ int h[BPW];
  __shared__ unsigned short hw[BPW];
  int tid = threadIdx.x, b = blockIdx.x;
  const int* hz = hist + g.hbase + (size_t)b * g.bins + klo;
  for (int i = tid; i < window; i += 256) {
    h[i] = hz[i] + off[g.obase + (klo + i) * g.ostride];
    hw[i] = wtab[g.wbase + klo + i];
  }
  __syncthreads();
  int ch = (s.n + NB - 1) / NB;
  int lo = b * ch, hi = min(s.n, lo + ch);
  for (int i = lo + tid; i < hi; i += 256) {
    int r = s.key[i] - klo;
    if ((unsigned)r < (unsigned)window) {
      int pos = atomicAdd(&h[r], 1);
      s.val[pos] = (int)(((unsigned int)hw[r] << 16) | (unsigned int)(s.oth[i] + s.roff));
    }
  }
}

// ---------------- x_dis init (dual f32 + bf16) ----------------
__global__ void k_dis0(const float* __restrict__ dx, const float* __restrict__ w,
                       const float* __restrict__ b, const float* __restrict__ emb,
                       float* __restrict__ out, unsigned short* __restrict__ outb) {
  int i = blockIdx.x;
  int j = threadIdx.x;
  float s = b[j] + emb[(size_t)i * HC + j];
  #pragma unroll
  for (int k = 0; k < 10; k++) s += dx[i * 10 + k] * w[k * HC + j];
  out[(size_t)i * HC + j] = s;
  outb[(size_t)i * HC + j] = f2bf(s);
}

// ---------------- Wct + biasc (both layers) ----------------
__global__ void k_wc(const float* __restrict__ rmt_wr, const float* __restrict__ rha_wr,
                     const float* __restrict__ rmt_bl, const float* __restrict__ rha_bl,
                     unsigned short* __restrict__ Wct, float* __restrict__ biasc) {
  int l = blockIdx.y;
  const float* wr_main = rmt_wr + (size_t)l * HC * HC;
  const float* wr_t = rha_wr + (size_t)l * T_ATTR * HC * HC;
  const float* bl_main = rmt_bl + (size_t)l * HC;
  const float* bl_t = rha_bl + (size_t)l * T_ATTR * HC;
  unsigned short* Wo = Wct + (size_t)l * 16384;
  float* bo = biasc + (size_t)l * 128;
  int i = blockIdx.x * blockDim.x + threadIdx.x;
  if (i < HC * HC) {
    float s = wr_main[i];
    #pragma unroll
    for (int t = 0; t < T_ATTR; t++) s += wr_t[(size_t)t * HC * HC + i];
    int k = i >> 7, n = i & 127;
    Wo[n * 128 + k] = f2bf(s);
  }
  if (i < HC) {
    float s = bl_main[i];
    #pragma unroll
    for (int t = 0; t < T_ATTR; t++) s += bl_t[t * HC + i];
    bo[i] = s;
  }
}

// ---------------- weight transpose f32 [128][128] -> bf16 Wt[n][k], 54 mats ----------------
struct WtJobs { const float* s[54]; };
__global__ __launch_bounds__(256) void k_wt(WtJobs J, unsigned short* __restrict__ dst) {
  const float* src = J.s[blockIdx.z];
  unsigned short* d = dst + (size_t)blockIdx.z * 16384;
  __shared__ float t[32][33];
  int tx = threadIdx.x & 31, ty = threadIdx.x >> 5;
  int i0 = blockIdx.x * 32, j0 = blockIdx.y * 32;
  #pragma unroll
  for (int q = 0; q < 4; q++) {
    int k = i0 + ty + q * 8;
    t[ty + q * 8][tx] = src[k * 128 + j0 + tx];
  }
  __syncthreads();
  #pragma unroll
  for (int q = 0; q < 4; q++) {
    int n = j0 + ty + q * 8;
    d[(size_t)n * 128 + i0 + tx] = f2bf(t[tx][ty + q * 8]);
  }
}

// ---------------- f32 -> bf16 convert ----------------
__global__ __launch_bounds__(256) void k_cvt(const float* __restrict__ src,
                                             unsigned short* __restrict__ dst, int n4) {
  int i = blockIdx.x * 256 + threadIdx.x;
  if (i >= n4) return;
  float4 v = ((const float4*)src)[i];
  uint2 w;
  w.x = (unsigned int)f2bf(v.x) | ((unsigned int)f2bf(v.y) << 16);
  w.y = (unsigned int)f2bf(v.z) | ((unsigned int)f2bf(v.w) << 16);
  ((uint2*)dst)[i] = w;
}

// ---------------- weighted gather ----------------
__device__ __forceinline__ void gacc_w(const unsigned short* __restrict__ T, const int* __restrict__ val,
                                       int b, int e, int lane, float& ax, float& ay) {
  int i = b;
  for (; i + 8 <= e; i += 8) {
    unsigned int pv[8], rv[8];
    #pragma unroll
    for (int q = 0; q < 8; q++) pv[q] = ((const unsigned int*)val)[i + q];
    #pragma unroll
    for (int q = 0; q < 8; q++)
      rv[q] = ((const unsigned int*)(T + (size_t)(pv[q] & 0xffffu) * HC))[lane];
    #pragma unroll
    for (int q = 0; q < 8; q++) {
      float w = __half2float(__ushort_as_half((unsigned short)(pv[q] >> 16)));
      ax = fmaf(w, bflo(rv[q]), ax);
      ay = fmaf(w, bfhi(rv[q]), ay);
    }
  }
  for (; i < e; i++) {
    unsigned int pv = ((const unsigned int*)val)[i];
    unsigned int rv = ((const unsigned int*)(T + (size_t)(pv & 0xffffu) * HC))[lane];
    float w = __half2float(__ushort_as_half((unsigned short)(pv >> 16)));
    ax = fmaf(w, bflo(rv), ax);
    ay = fmaf(w, bfhi(rv), ay);
  }
}

// ---------------- mega segment-mean (drug waves first: longest start earliest) ----------------
__global__ __launch_bounds__(256) void k_seg_mega(
    const int* __restrict__ off,
    const int* __restrict__ vmd, const int* __restrict__ vdrug, const int* __restrict__ vhd,
    const unsigned short* __restrict__ xdb, const unsigned short* __restrict__ Ytab,
    unsigned short* __restrict__ m2disb, float* __restrict__ accd, unsigned short* __restrict__ m2ab) {
  int lane = threadIdx.x & 63;
  int lane2 = lane * 2;
  int w = blockIdx.x * 4 + (threadIdx.x >> 6);
  if (w < N_DRUG) {
    int d = w;
    int lo = off[OFF_D + d * 9], hi = off[OFF_D + d * 9 + 9];
    float ax = 0.f, ay = 0.f;
    gacc_w(Ytab, vdrug, lo, hi, lane, ax, ay);
    *(float2*)(accd + (size_t)d * HC + lane2) = make_float2(ax, ay);
  } else if (w < N_DRUG + N_DIS) {
    int d = w - N_DRUG;
    int lo = off[OFF_Z0 + d], hi = off[OFF_Z0 + d + 1];
    float ax = 0.f, ay = 0.f;
    gacc_w(xdb, vmd, lo, hi, lane, ax, ay);
    *(unsigned int*)(m2disb + (size_t)d * HC + lane2) =
        (unsigned int)f2bf(ax) | ((unsigned int)f2bf(ay) << 16);
  } else {
    int idx = w - (N_DRUG + N_DIS);
    int t = idx / N_ATTR, r = idx - t * N_ATTR;
    int lo = off[OFF_Z2(t) + r], hi = off[OFF_Z2(t) + r + 1];
    float ax = 0.f, ay = 0.f;
    gacc_w(xdb, vhd + (size_t)t * E_HA, lo, hi, lane, ax, ay);
    *(unsigned int*)(m2ab + ((size_t)t * N_ATTR + r) * HC + lane2) =
        (unsigned int)f2bf(ax) | ((unsigned int)f2bf(ay) << 16);
  }
}

// ---------------- MFMA GEMM ----------------
struct MJob {
  const unsigned short* X1; const unsigned short* Wt1;
  const unsigned short* X2; const unsigned short* Wt2;
  const float* bias; const float* ACC;
  float* D; unsigned short* D2;
  int M; int leaky; int bf16out;
};
struct MJobs { MJob j[10]; };

__global__ __launch_bounds__(256) void k_gemm_mfma(MJobs jobs) {
  MJob jb = jobs.j[blockIdx.z];
  int m0 = blockIdx.x * 64;
  if (m0 >= jb.M) return;
  int wave = threadIdx.x >> 6;
  int lane = threadIdx.x & 63;
  int l15 = lane & 15, g = lane >> 4;
  int m = m0 + wave * 16 + l15;
  bool mok = m < jb.M;
  int mrow = mok ? m : 0;

  f32x4 acc[8] = {};
  #pragma unroll
  for (int part = 0; part < 2; part++) {
    const unsigned short* X = part ? jb.X2 : jb.X1;
    const unsigned short* Wt = part ? jb.Wt2 : jb.Wt1;
    if (!X) break;
    #pragma unroll
    for (int ks = 0; ks < 4; ks++) {
      int k0 = ks * 32 + g * 8;
      bf16x8 xb = {};
      if (mok) xb = *(const bf16x8*)(X + (size_t)mrow * 128 + k0);
      #pragma unroll
      for (int f = 0; f < 8; f++) {
        bf16x8 wb = *(const bf16x8*)(Wt + (size_t)(f * 16 + l15) * 128 + k0);
        acc[f] = __builtin_amdgcn_mfma_f32_16x16x32_bf16(wb, xb, acc[f], 0, 0, 0);
      }
    }
  }
  if (!mok) return;
  #pragma unroll
  for (int f = 0; f < 8; f++) {
    int n0 = f * 16 + 4 * g;
    float r0 = acc[f][0], r1 = acc[f][1], r2 = acc[f][2], r3 = acc[f][3];
    if (jb.bias) {
      float4 bs = *(const float4*)(jb.bias + n0);
      r0 += bs.x; r1 += bs.y; r2 += bs.z; r3 += bs.w;
    }
    if (jb.ACC) {
      float4 a = *(const float4*)(jb.ACC + (size_t)m * 128 + n0);
      r0 += a.x; r1 += a.y; r2 += a.z; r3 += a.w;
    }
    if (jb.leaky) { r0 = leakyf(r0); r1 = leakyf(r1); r2 = leakyf(r2); r3 = leakyf(r3); }
    if (jb.bf16out) {
      unsigned short* Db = (unsigned short*)jb.D;
      uint2 w;
      w.x = (unsigned int)f2bf(r0) | ((unsigned int)f2bf(r1) << 16);
      w.y = (unsigned int)f2bf(r2) | ((unsigned int)f2bf(r3) << 16);
      *(uint2*)(Db + (size_t)m * 128 + n0) = w;
    } else {
      *(float4*)(jb.D + (size_t)m * 128 + n0) = make_float4(r0, r1, r2, r3);
      if (jb.D2) {
        uint2 w;
        w.x = (unsigned int)f2bf(r0) | ((unsigned int)f2bf(r1) << 16);
        w.y = (unsigned int)f2bf(r2) | ((unsigned int)f2bf(r3) << 16);
        *(uint2*)(jb.D2 + (size_t)m * 128 + n0) = w;
      }
    }
  }
}

// ---------------- classifier head GEMMs (bf16 output for tail) ----------------
struct G64Job { const float* X; const float* W; const float* bias; unsigned short* D; int M; };

__global__ __launch_bounds__(256) void k_gemm64(G64Job j0, G64Job j1) {
  G64Job jb = blockIdx.z ? j1 : j0;
  int m0 = blockIdx.x * 64;
  if (m0 >= jb.M) return;
  __shared__ float As[16][68];
  __shared__ float Bs[16][68];
  int tid = threadIdx.x;
  int tx = tid & 15, ty = tid >> 4;
  float acc[4][4];
  #pragma unroll
  for (int i = 0; i < 4; i++)
    #pragma unroll
    for (int j = 0; j < 4; j++) acc[i][j] = 0.f;

  for (int kk = 0; kk < 128; kk += 16) {
    {
      int r = tid >> 2, kq = (tid & 3) * 4;
      int gr = m0 + r;
      float4 v = make_float4(0.f, 0.f, 0.f, 0.f);
      if (gr < jb.M) v = *(const float4*)(jb.X + (size_t)gr * HC + kk + kq);
      As[kq + 0][r] = v.x; As[kq + 1][r] = v.y; As[kq + 2][r] = v.z; As[kq + 3][r] = v.w;
    }
    {
      int k = tid >> 4, c = (tid & 15) * 4;
      *(float4*)&Bs[k][c] = *(const float4*)(jb.W + (size_t)(kk + k) * 64 + c);
    }
    __syncthreads();
    #pragma unroll
    for (int k = 0; k < 16; k++) {
      float4 a = *(const float4*)&As[k][ty * 4];
      float4 b = *(const float4*)&Bs[k][tx * 4];
      float av[4] = {a.x, a.y, a.z, a.w};
      float bb[4] = {b.x, b.y, b.z, b.w};
      #pragma unroll
      for (int i = 0; i < 4; i++)
        #pragma unroll
        for (int j = 0; j < 4; j++) acc[i][j] += av[i] * bb[j];
    }
    __syncthreads();
  }
  float4 bs = make_float4(0.f, 0.f, 0.f, 0.f);
  if (jb.bias) bs = *(const float4*)(jb.bias + tx * 4);
  #pragma unroll
  for (int i = 0; i < 4; i++) {
    int gr = m0 + ty * 4 + i;
    if (gr < jb.M) {
      uint2 w;
      w.x = (unsigned int)f2bf(acc[i][0] + bs.x) | ((unsigned int)f2bf(acc[i][1] + bs.y) << 16);
      w.y = (unsigned int)f2bf(acc[i][2] + bs.z) | ((unsigned int)f2bf(acc[i][3] + bs.w) << 16);
      *(uint2*)(jb.D + (size_t)gr * 64 + tx * 4) = w;
    }
  }
}

// ---------------- per-edge tail MLP (bf16 U/V rows: 128B each) ----------------
__global__ __launch_bounds__(256) void k_tail(
    const unsigned short* __restrict__ U, const unsigned short* __restrict__ V,
    const int* __restrict__ es, const int* __restrict__ ed,
    const float* __restrict__ cw1, const float* __restrict__ cb1,
    const float* __restrict__ cw2, const float* __restrict__ cb2,
    const float* __restrict__ cw3, const float* __restrict__ cb3,
    const float* __restrict__ cw4, const float* __restrict__ cb4,
    float* __restrict__ out, int n) {
  __shared__ float w1[64 * 32];
  __shared__ float w2[32 * 16];
  __shared__ float w3[16 * 8];
  __shared__ float w4[8];
  __shared__ float b1[32], b2[16], b3[8];
  int tid = threadIdx.x;
  #pragma unroll
  for (int q = 0; q < 8; q++) w1[tid + q * 256] = cw1[tid + q * 256];
  #pragma unroll
  for (int q = 0; q < 2; q++) w2[tid + q * 256] = cw2[tid + q * 256];
  if (tid < 128) w3[tid] = cw3[tid];
  if (tid < 8)  w4[tid] = cw4[tid];
  if (tid < 32) b1[tid] = cb1[tid];
  if (tid < 16) b2[tid] = cb2[tid];
  if (tid < 8)  b3[tid] = cb3[tid];
  __syncthreads();
  int i = blockIdx.x * 256 + tid;
  if (i >= n) return;
  int s = es[i], d = ed[i];
  const uint4* up = (const uint4*)(U + (size_t)s * 64);
  const uint4* vp = (const uint4*)(V + (size_t)d * 64);
  float h1[64];
  #pragma unroll
  for (int q = 0; q < 8; q++) {
    uint4 a = up[q], b = vp[q];
    h1[8 * q + 0] = leakyf(bflo(a.x) + bflo(b.x));
    h1[8 * q + 1] = leakyf(bfhi(a.x) + bfhi(b.x));
    h1[8 * q + 2] = leakyf(bflo(a.y) + bflo(b.y));
    h1[8 * q + 3] = leakyf(bfhi(a.y) + bfhi(b.y));
    h1[8 * q + 4] = leakyf(bflo(a.z) + bflo(b.z));
    h1[8 * q + 5] = leakyf(bfhi(a.z) + bfhi(b.z));
    h1[8 * q + 6] = leakyf(bflo(a.w) + bflo(b.w));
    h1[8 * q + 7] = leakyf(bfhi(a.w) + bfhi(b.w));
  }
  float h2[32];
  #pragma unroll
  for (int j = 0; j < 32; j++) h2[j] = b1[j];
  #pragma unroll
  for (int k = 0; k < 64; k++) {
    float hv = h1[k];
    #pragma unroll
    for (int jq = 0; jq < 8; jq++) {
      float4 w = *(const float4*)&w1[k * 32 + jq * 4];
      h2[4 * jq + 0] = fmaf(hv, w.x, h2[4 * jq + 0]);
      h2[4 * jq + 1] = fmaf(hv, w.y, h2[4 * jq + 1]);
      h2[4 * jq + 2] = fmaf(hv, w.z, h2[4 * jq + 2]);
      h2[4 * jq + 3] = fmaf(hv, w.w, h2[4 * jq + 3]);
    }
  }
  float h3[16];
  #pragma unroll
  for (int j = 0; j < 16; j++) h3[j] = b2[j];
  #pragma unroll
  for (int k = 0; k < 32; k++) {
    float hv = leakyf(h2[k]);
    #pragma unroll
    for (int jq = 0; jq < 4; jq++) {
      float4 w = *(const float4*)&w2[k * 16 + jq * 4];
      h3[4 * jq + 0] = fmaf(hv, w.x, h3[4 * jq + 0]);
      h3[4 * jq + 1] = fmaf(hv, w.y, h3[4 * jq + 1]);
      h3[4 * jq + 2] = fmaf(hv, w.z, h3[4 * jq + 2]);
      h3[4 * jq + 3] = fmaf(hv, w.w, h3[4 * jq + 3]);
    }
  }
  float h4[8];
  #pragma unroll
  for (int j = 0; j < 8; j++) h4[j] = b3[j];
  #pragma unroll
  for (int k = 0; k < 16; k++) {
    float hv = leakyf(h3[k]);
    #pragma unroll
    for (int jq = 0; jq < 2; jq++) {
      float4 w = *(const float4*)&w3[k * 8 + jq * 4];
      h4[4 * jq + 0] = fmaf(hv, w.x, h4[4 * jq + 0]);
      h4[4 * jq + 1] = fmaf(hv, w.y, h4[4 * jq + 1]);
      h4[4 * jq + 2] = fmaf(hv, w.z, h4[4 * jq + 2]);
      h4[4 * jq + 3] = fmaf(hv, w.w, h4[4 * jq + 3]);
    }
  }
  float p = cb4[0];
  #pragma unroll
  for (int k = 0; k < 8; k++) p = fmaf(leakyf(h4[k]), w4[k], p);
  out[i] = p;
}

extern "C" void kernel_launch(void* const* d_in, const int* in_sizes, int n_in,
                              void* d_out, int out_size, void* d_ws, size_t ws_size,
                              hipStream_t stream) {
  const float* disease_x   = (const float*)d_in[0];
  const float* drug_emb    = (const float*)d_in[1];
  const float* disease_emb = (const float*)d_in[2];
  const float* attr_emb    = (const float*)d_in[3];
  const float* dis_lin_w   = (const float*)d_in[4];
  const float* dis_lin_b   = (const float*)d_in[5];
  const float* mt_wl  = (const float*)d_in[6];
  const float* mt_bl  = (const float*)d_in[7];
  const float* mt_wr  = (const float*)d_in[8];
  const float* rmt_wl = (const float*)d_in[9];
  const float* rmt_bl = (const float*)d_in[10];
  const float* rmt_wr = (const float*)d_in[11];
  const float* ha_wl  = (const float*)d_in[12];
  const float* ha_bl  = (const float*)d_in[13];
  const float* ha_wr  = (const float*)d_in[14];
  const float* rha_wl = (const float*)d_in[15];
  const float* rha_bl = (const float*)d_in[16];
  const float* rha_wr = (const float*)d_in[17];
  const float* cw0 = (const float*)d_in[18];
  const float* cb0 = (const float*)d_in[19];
  const float* cw1 = (const float*)d_in[20];
  const float* cb1 = (const float*)d_in[21];
  const float* cw2 = (const float*)d_in[22];
  const float* cb2 = (const float*)d_in[23];
  const float* cw3 = (const float*)d_in[24];
  const float* cb3 = (const float*)d_in[25];
  const float* cw4 = (const float*)d_in[26];
  const float* cb4 = (const float*)d_in[27];
  const int* mt_src = (const int*)d_in[28];
  const int* mt_dst = (const int*)d_in[29];
  const int* ha_src = (const int*)d_in[30];
  const int* ha_dst = (const int*)d_in[31];
  const int* ell_src = (const int*)d_in[32];
  const int* ell_dst = (const int*)d_in[33];
  float* out = (float*)d_out;

  const long long ATTR_S = (long long)N_ATTR * HC;
  const long long W_S = HC * HC;

  // ---------- workspace carve ----------
  float* fws = (float*)d_ws;
  size_t o = 0;
  float* x_drug = fws + o; o += (size_t)N_DRUG * HC;
  float* x_dis  = fws + o; o += (size_t)N_DIS * HC;
  float* x_attr = fws + o; o += (size_t)T_ATTR * N_ATTR * HC;
  float* accd   = fws + o; o += (size_t)N_DRUG * HC;   // | accd..Vcls overlaid by hist
  float* biasc  = fws + o; o += 256;                   // | (3.296M ints) during CSR build
  unsigned short* Ucls = (unsigned short*)(fws + o); o += (size_t)N_DRUG * 64 / 2;
  unsigned short* Vcls = (unsigned short*)(fws + o); o += (size_t)N_DIS * 64 / 2;
  unsigned short* xdb    = (unsigned short*)(fws + o);
  unsigned short* Ytab   = xdb + (size_t)N_DRUG * HC;
  unsigned short* Ydisb  = Ytab;
  unsigned short* Yattrb = Ytab + (size_t)N_DIS * HC;
  unsigned short* xdisb  = Yattrb + (size_t)T_ATTR * N_ATTR * HC;
  unsigned short* xab    = xdisb + (size_t)N_DIS * HC;
  unsigned short* m2disb = xab + (size_t)T_ATTR * N_ATTR * HC;
  unsigned short* m2ab   = m2disb + (size_t)N_DIS * HC;
  unsigned short* Wts    = m2ab + (size_t)T_ATTR * N_ATTR * HC;  // 54 * 16384
  unsigned short* Wct    = Wts + 54 * 16384;                     // 2 * 16384
  unsigned short* ushort_end = Wct + 2 * 16384;
  o += ((size_t)(ushort_end - xdb) + 1) / 2;
  int* iws = (int*)(fws + o);
  int* off = iws;
  int* vmd   = off + OFF_TOT;
  int* vdrug = vmd + E_MT;
  int* vhd   = vdrug + (E_MT + T_ATTR * E_HA);
  unsigned short* wtab = (unsigned short*)(vhd + (size_t)T_ATTR * E_HA);
  int* csum = (int*)(wtab + WTOT + (WTOT & 1));
  int* hist = (int*)accd;   // 3.296M ints over accd+biasc+Ucls+Vcls (dead during CSR build)

  dim3 b256(256);
  // ---------- CSR build ----------
  k_hist<<<dim3(NB, 1, NSS), b256, 0, stream>>>(mt_src, mt_dst, ha_src, ha_dst, hist);
  k_blkpfx<<<dim3((N_DRUG + 255) / 256, 1, 18), b256, 0, stream>>>(hist, off, wtab);
  {
    dim3 sg((180000 + SCH - 1) / SCH, 10);
    k_scan_l1<<<sg, b256, 0, stream>>>(off, csum);
    k_scan_l2<<<10, 64, 0, stream>>>(off, csum);
    k_scan_l3<<<sg, b256, 0, stream>>>(off, csum);
  }
  k_fill2<<<dim3(NB, 1, NSS), b256, 0, stream>>>(mt_src, mt_dst, ha_src, ha_dst, hist, off, wtab,
                                                 vmd, vdrug, vhd);

  // ---------- weights (both layers, batched) ----------
  k_wc<<<dim3(64, 2), b256, 0, stream>>>(rmt_wr, rha_wr, rmt_bl, rha_bl, Wct, biasc);
  {
    WtJobs W{};
    for (int l = 0; l < 2; l++) {
      int base = l * 27;
      W.s[base + 0] = rmt_wl + (size_t)l * W_S;
      for (int t = 0; t < T_ATTR; t++) W.s[base + 1 + t] = rha_wl + (size_t)l * T_ATTR * W_S + (size_t)t * W_S;
      W.s[base + 9] = mt_wl + (size_t)l * W_S;
      W.s[base + 10] = mt_wr + (size_t)l * W_S;
      for (int t = 0; t < T_ATTR; t++) W.s[base + 11 + t] = ha_wl + (size_t)l * T_ATTR * W_S + (size_t)t * W_S;
      for (int t = 0; t < T_ATTR; t++) W.s[base + 19 + t] = ha_wr + (size_t)l * T_ATTR * W_S + (size_t)t * W_S;
    }
    k_wt<<<dim3(4, 4, 54), b256, 0, stream>>>(W, Wts);
  }

  // ---------- node init + initial bf16 copies ----------
  k_dis0<<<N_DIS, 128, 0, stream>>>(disease_x, dis_lin_w, dis_lin_b, disease_emb, x_dis, xdisb);
  k_cvt<<<dim3((N_DRUG * HC / 4 + 255) / 256), b256, 0, stream>>>(drug_emb, xdb, N_DRUG * HC / 4);
  k_cvt<<<dim3((T_ATTR * N_ATTR * HC / 4 + 255) / 256), b256, 0, stream>>>(attr_emb, xab, T_ATTR * N_ATTR * HC / 4);

  for (int l = 0; l < 2; l++) {
    const float* mt_bl_l  = mt_bl  + (size_t)l * HC;
    const float* ha_bl_l  = ha_bl  + (size_t)l * T_ATTR * HC;
    const unsigned short* Wts_l = Wts + (size_t)l * 27 * 16384;
    const unsigned short* Wct_l = Wct + (size_t)l * 16384;
    const float* biasc_l = biasc + (size_t)l * 128;

    // pre-transform GEMMs (MFMA, bf16 out)
    {
      MJobs J{};
      J.j[0] = {xdisb, Wts_l + 0 * 16384, nullptr, nullptr, nullptr, nullptr, (float*)Ydisb, nullptr, N_DIS, 0, 1};
      for (int t = 0; t < T_ATTR; t++)
        J.j[1 + t] = {xab + (size_t)t * ATTR_S, Wts_l + (size_t)(1 + t) * 16384,
                      nullptr, nullptr, nullptr, nullptr,
                      (float*)(Yattrb + (size_t)t * ATTR_S), nullptr, N_ATTR, 0, 1};
      k_gemm_mfma<<<dim3((N_DIS + 63) / 64, 1, 9), b256, 0, stream>>>(J);
    }

    // gathers
    k_seg_mega<<<dim3((46000 + 3) / 4, 1, 1), b256, 0, stream>>>(
        off, vmd, vdrug, vhd, xdb, Ytab, m2disb, accd, m2ab);

    // combine GEMMs (MFMA, f32 + dual bf16 out)
    {
      MJobs J{};
      J.j[0] = {xdb, Wct_l, nullptr, nullptr, biasc_l, accd, x_drug, xdb, N_DRUG, 1, 0};
      J.j[1] = {m2disb, Wts_l + 9 * 16384, xdisb, Wts_l + 10 * 16384, mt_bl_l, nullptr, x_dis, xdisb, N_DIS, 1, 0};
      for (int t = 0; t < T_ATTR; t++)
        J.j[2 + t] = {m2ab + (size_t)t * ATTR_S, Wts_l + (size_t)(11 + t) * 16384,
                      xab + (size_t)t * ATTR_S, Wts_l + (size_t)(19 + t) * 16384,
                      ha_bl_l + (size_t)t * HC, nullptr, x_attr + (size_t)t * ATTR_S,
                      xab + (size_t)t * ATTR_S, N_ATTR, 1, 0};
      k_gemm_mfma<<<dim3((N_DRUG + 63) / 64, 1, 10), b256, 0, stream>>>(J);
    }
  }

  // ---------- classifier ----------
  {
    G64Job ju = {x_drug, cw0, cb0, Ucls, N_DRUG};
    G64Job jv = {x_dis, cw0 + 128 * 64, nullptr, Vcls, N_DIS};
    k_gemm64<<<dim3((N_DRUG + 63) / 64, 1, 2), b256, 0, stream>>>(ju, jv);
    k_tail<<<dim3((E_LBL + 255) / 256, 1, 1), b256, 0, stream>>>(
        Ucls, Vcls, ell_src, ell_dst,
        cw1, cb1, cw2, cb2, cw3, cb3, cw4, cb4, out, E_LBL);
  }
}

// Round 14
// 420.967 us; speedup vs baseline: 1.7490x; 1.0390x over previous
//
#include <hip/hip_runtime.h>
#include <hip/hip_fp16.h>

#define N_DRUG 20000
#define N_DIS  10000
#define N_ATTR 2000
#define T_ATTR 8
#define E_MT   500000
#define E_HA   100000
#define E_LBL  200000
#define HC     128
#define BPW    2500 // bins per key-window
#define NSS    84   // sub-segments
#define NBMAX  80   // chunk blocks for E_MT segments (z0,z1); E_HA segments use 16

__device__ __forceinline__ float leakyf(float x) { return x >= 0.f ? x : 0.01f * x; }

__device__ __forceinline__ unsigned short f2bf(float f) {
  unsigned int u = __float_as_uint(f);
  return (unsigned short)((u + 0x7fffu + ((u >> 16) & 1u)) >> 16);
}
__device__ __forceinline__ float bflo(unsigned int u) { return __uint_as_float(u << 16); }
__device__ __forceinline__ float bfhi(unsigned int u) { return __uint_as_float(u & 0xffff0000u); }

typedef __attribute__((ext_vector_type(8))) short bf16x8;
typedef __attribute__((ext_vector_type(4))) float f32x4;

// ---------------- CSR build ----------------
// hist bases (NBZ x bins per z): z0 80x10000 | z1 80x20000 | z2..9 16x2000 | z10..17 16x20000
#define HB0 0
#define HB1 800000
#define HB2(t) (2400000 + (t) * 32000)
#define HB10(t) (2656000 + (t) * 320000)
#define HTOT 5216000
#define WB0 0
#define WB1 10000
#define WB2(t) (30000 + (t) * 2000)
#define WB10(t) (46000 + (t) * 20000)
#define WTOT 206000
#define OFF_Z0 0
#define OFF_D  10001
#define OFF_Z2(t) (190002 + (t) * 2001)
#define OFF_TOT 206010
#define SCH 2048
#define SMAXC 128

struct SegB { int bins; int hbase; int wbase; int obase; int ostride; int nbz; };
__device__ __forceinline__ SegB segb(int z) {
  SegB s;
  if (z == 0)      { s.bins = N_DIS;  s.hbase = HB0;  s.wbase = WB0;  s.obase = OFF_Z0;    s.ostride = 1; s.nbz = NBMAX; }
  else if (z == 1) { s.bins = N_DRUG; s.hbase = HB1;  s.wbase = WB1;  s.obase = OFF_D;     s.ostride = 9; s.nbz = NBMAX; }
  else if (z < 10) { int t = z - 2;  s.bins = N_ATTR; s.hbase = HB2(t);  s.wbase = WB2(t);  s.obase = OFF_Z2(t);   s.ostride = 1; s.nbz = 16; }
  else             { int t = z - 10; s.bins = N_DRUG; s.hbase = HB10(t); s.wbase = WB10(t); s.obase = OFF_D + 1 + t; s.ostride = 9; s.nbz = 16; }
  return s;
}

struct SegE { const int* key; const int* oth; int n; int roff; int* val; };
__device__ __forceinline__ SegE sege(int z,
    const int* mt_src, const int* mt_dst, const int* ha_src, const int* ha_dst,
    int* vmd, int* vdrug, int* vhd) {
  SegE s;
  if (z == 0)      { s.key = mt_dst; s.oth = mt_src; s.n = E_MT; s.roff = 0; s.val = vmd; }
  else if (z == 1) { s.key = mt_src; s.oth = mt_dst; s.n = E_MT; s.roff = 0; s.val = vdrug; }
  else if (z < 10) { int t = z - 2;
    s.key = ha_dst + (size_t)t * E_HA; s.oth = ha_src + (size_t)t * E_HA; s.n = E_HA;
    s.roff = 0; s.val = vhd + (size_t)t * E_HA; }
  else { int t = z - 10;
    s.key = ha_src + (size_t)t * E_HA; s.oth = ha_dst + (size_t)t * E_HA; s.n = E_HA;
    s.roff = 10000 + t * N_ATTR; s.val = vdrug; }
  return s;
}

__device__ __forceinline__ void ss_resolve(int ss, int& z, int& klo) {
  if (ss < 4)       { z = 0; klo = ss * BPW; }
  else if (ss < 12) { z = 1; klo = (ss - 4) * BPW; }
  else if (ss < 20) { z = 2 + (ss - 12); klo = 0; }
  else              { z = 10 + ((ss - 20) >> 3); klo = ((ss - 20) & 7) * BPW; }
}

__global__ __launch_bounds__(256) void k_hist(
    const int* __restrict__ mt_src, const int* __restrict__ mt_dst,
    const int* __restrict__ ha_src, const int* __restrict__ ha_dst,
    int* __restrict__ hist) {
  int z, klo;
  ss_resolve(blockIdx.z, z, klo);
  SegB g = segb(z);
  int b = blockIdx.x;
  if (b >= g.nbz) return;
  SegE s = sege(z, mt_src, mt_dst, ha_src, ha_dst, nullptr, nullptr, nullptr);
  int window = min(BPW, g.bins - klo);
  __shared__ int h[BPW];
  int tid = threadIdx.x;
  for (int i = tid; i < window; i += 256) h[i] = 0;
  __syncthreads();
  int ch = (s.n + g.nbz - 1) / g.nbz;
  int lo = b * ch, hi = min(s.n, lo + ch);
  for (int i = lo + tid; i < hi; i += 256) {
    int r = s.key[i] - klo;
    if ((unsigned)r < (unsigned)window) atomicAdd(&h[r], 1);
  }
  __syncthreads();
  int* hz = hist + g.hbase + (size_t)b * g.bins + klo;
  for (int i = tid; i < window; i += 256) hz[i] = h[i];
}

__global__ __launch_bounds__(256) void k_blkpfx(int* __restrict__ hist, int* __restrict__ off,
                                                unsigned short* __restrict__ wtab) {
  SegB g = segb(blockIdx.z);
  int i = blockIdx.x * 256 + threadIdx.x;
  if (i >= g.bins) return;
  int run = 0;
  for (int b = 0; b < g.nbz; b++) {
    int idx = g.hbase + b * g.bins + i;
    int v = hist[idx];
    hist[idx] = run;
    run += v;
  }
  off[g.obase + i * g.ostride] = run;
  __half hw = __float2half(1.0f / (float)(run > 0 ? run : 1));
  wtab[g.wbase + i] = __half_as_ushort(hw);
}

__device__ __forceinline__ void scan_region(int r, int& base, int& L) {
  if (r == 0)      { base = OFF_Z0; L = 10000; }
  else if (r == 1) { base = OFF_D;  L = 180000; }
  else             { int t = r - 2; base = OFF_Z2(t); L = 2000; }
}

__global__ __launch_bounds__(256) void k_scan_l1(int* __restrict__ off, int* __restrict__ csum) {
  int base, L;
  scan_region(blockIdx.y, base, L);
  int c = blockIdx.x;
  int c0 = c * SCH;
  if (c0 >= L) return;
  int tid = threadIdx.x;
  int i0 = c0 + tid * 8;
  int v[8];
  int s = 0;
  #pragma unroll
  for (int j = 0; j < 8; j++) {
    int i = i0 + j;
    v[j] = (i < L) ? off[base + i] : 0;
    s += v[j];
  }
  __shared__ int ssum[256];
  ssum[tid] = s;
  __syncthreads();
  if (tid == 0) {
    int run = 0;
    #pragma unroll 8
    for (int i = 0; i < 256; i++) { int x = ssum[i]; ssum[i] = run; run += x; }
    csum[blockIdx.y * SMAXC + c] = run;
  }
  __syncthreads();
  int run = ssum[tid];
  #pragma unroll
  for (int j = 0; j < 8; j++) {
    int i = i0 + j;
    if (i < L) { off[base + i] = run; run += v[j]; }
  }
}

__global__ void k_scan_l2(int* __restrict__ off, int* __restrict__ csum) {
  int r = blockIdx.x;
  int base, L;
  scan_region(r, base, L);
  if (threadIdx.x == 0) {
    int nc = (L + SCH - 1) / SCH;
    int run = 0;
    for (int c = 0; c < nc; c++) {
      int v = csum[r * SMAXC + c];
      csum[r * SMAXC + c] = run;
      run += v;
    }
    off[base + L] = run;
  }
}

__global__ __launch_bounds__(256) void k_scan_l3(int* __restrict__ off, const int* __restrict__ csum) {
  int base, L;
  scan_region(blockIdx.y, base, L);
  int c = blockIdx.x;
  int c0 = c * SCH;
  if (c0 >= L || c == 0) return;
  int add = csum[blockIdx.y * SMAXC + c];
  int i0 = c0 + threadIdx.x * 8;
  #pragma unroll
  for (int j = 0; j < 8; j++) {
    int i = i0 + j;
    if (i < L) off[base + i] += add;
  }
}

__global__ __launch_bounds__(256) void k_fill2(
    const int* __restrict__ mt_src, const int* __restrict__ mt_dst,
    const int* __restrict__ ha_src, const int* __restrict__ ha_dst,
    const int* __restrict__ hist, const int* __restrict__ off,
    const unsigned short* __restrict__ wtab,
    int* vmd, int* vdrug, int* vhd) {
  int z, klo;
  ss_resolve(blockIdx.z, z, klo);
  SegB g = segb(z);
  int b = blockIdx.x;
  if (b >= g.nbz) return;
  SegE s = sege(z, mt_src, mt_dst, ha_src, ha_dst, vmd, vdrug, vhd);
  int window = min(BPW, g.bins - klo);
  __shared__ int h[BPW];
  __shared__ unsigned short hw[BPW];
  int tid = threadIdx.x;
  const int* hz = hist + g.hbase + (size_t)b * g.bins + klo;
  for (int i = tid; i < window; i += 256) {
    h[i] = hz[i] + off[g.obase + (klo + i) * g.ostride];
    hw[i] = wtab[g.wbase + klo + i];
  }
  __syncthreads();
  int ch = (s.n + g.nbz - 1) / g.nbz;
  int lo = b * ch, hi = min(s.n, lo + ch);
  for (int i = lo + tid; i < hi; i += 256) {
    int r = s.key[i] - klo;
    if ((unsigned)r < (unsigned)window) {
      int pos = atomicAdd(&h[r], 1);
      s.val[pos] = (int)(((unsigned int)hw[r] << 16) | (unsigned int)(s.oth[i] + s.roff));
    }
  }
}

// ---------------- x_dis init (dual f32 + bf16) ----------------
__global__ void k_dis0(const float* __restrict__ dx, const float* __restrict__ w,
                       const float* __restrict__ b, const float* __restrict__ emb,
                       float* __restrict__ out, unsigned short* __restrict__ outb) {
  int i = blockIdx.x;
  int j = threadIdx.x;
  float s = b[j] + emb[(size_t)i * HC + j];
  #pragma unroll
  for (int k = 0; k < 10; k++) s += dx[i * 10 + k] * w[k * HC + j];
  out[(size_t)i * HC + j] = s;
  outb[(size_t)i * HC + j] = f2bf(s);
}

// ---------------- Wct + biasc (both layers) ----------------
__global__ void k_wc(const float* __restrict__ rmt_wr, const float* __restrict__ rha_wr,
                     const float* __restrict__ rmt_bl, const float* __restrict__ rha_bl,
                     unsigned short* __restrict__ Wct, float* __restrict__ biasc) {
  int l = blockIdx.y;
  const float* wr_main = rmt_wr + (size_t)l * HC * HC;
  const float* wr_t = rha_wr + (size_t)l * T_ATTR * HC * HC;
  const float* bl_main = rmt_bl + (size_t)l * HC;
  const float* bl_t = rha_bl + (size_t)l * T_ATTR * HC;
  unsigned short* Wo = Wct + (size_t)l * 16384;
  float* bo = biasc + (size_t)l * 128;
  int i = blockIdx.x * blockDim.x + threadIdx.x;
  if (i < HC * HC) {
    float s = wr_main[i];
    #pragma unroll
    for (int t = 0; t < T_ATTR; t++) s += wr_t[(size_t)t * HC * HC + i];
    int k = i >> 7, n = i & 127;
    Wo[n * 128 + k] = f2bf(s);
  }
  if (i < HC) {
    float s = bl_main[i];
    #pragma unroll
    for (int t = 0; t < T_ATTR; t++) s += bl_t[t * HC + i];
    bo[i] = s;
  }
}

// ---------------- weight transpose f32 [128][128] -> bf16 Wt[n][k], 54 mats ----------------
struct WtJobs { const float* s[54]; };
__global__ __launch_bounds__(256) void k_wt(WtJobs J, unsigned short* __restrict__ dst) {
  const float* src = J.s[blockIdx.z];
  unsigned short* d = dst + (size_t)blockIdx.z * 16384;
  __shared__ float t[32][33];
  int tx = threadIdx.x & 31, ty = threadIdx.x >> 5;
  int i0 = blockIdx.x * 32, j0 = blockIdx.y * 32;
  #pragma unroll
  for (int q = 0; q < 4; q++) {
    int k = i0 + ty + q * 8;
    t[ty + q * 8][tx] = src[k * 128 + j0 + tx];
  }
  __syncthreads();
  #pragma unroll
  for (int q = 0; q < 4; q++) {
    int n = j0 + ty + q * 8;
    d[(size_t)n * 128 + i0 + tx] = f2bf(t[tx][ty + q * 8]);
  }
}

// ---------------- f32 -> bf16 convert ----------------
__global__ __launch_bounds__(256) void k_cvt(const float* __restrict__ src,
                                             unsigned short* __restrict__ dst, int n4) {
  int i = blockIdx.x * 256 + threadIdx.x;
  if (i >= n4) return;
  float4 v = ((const float4*)src)[i];
  uint2 w;
  w.x = (unsigned int)f2bf(v.x) | ((unsigned int)f2bf(v.y) << 16);
  w.y = (unsigned int)f2bf(v.z) | ((unsigned int)f2bf(v.w) << 16);
  ((uint2*)dst)[i] = w;
}

// ---------------- weighted gather ----------------
__device__ __forceinline__ void gacc_w(const unsigned short* __restrict__ T, const int* __restrict__ val,
                                       int b, int e, int lane, float& ax, float& ay) {
  int i = b;
  for (; i + 8 <= e; i += 8) {
    unsigned int pv[8], rv[8];
    #pragma unroll
    for (int q = 0; q < 8; q++) pv[q] = ((const unsigned int*)val)[i + q];
    #pragma unroll
    for (int q = 0; q < 8; q++)
      rv[q] = ((const unsigned int*)(T + (size_t)(pv[q] & 0xffffu) * HC))[lane];
    #pragma unroll
    for (int q = 0; q < 8; q++) {
      float w = __half2float(__ushort_as_half((unsigned short)(pv[q] >> 16)));
      ax = fmaf(w, bflo(rv[q]), ax);
      ay = fmaf(w, bfhi(rv[q]), ay);
    }
  }
  for (; i < e; i++) {
    unsigned int pv = ((const unsigned int*)val)[i];
    unsigned int rv = ((const unsigned int*)(T + (size_t)(pv & 0xffffu) * HC))[lane];
    float w = __half2float(__ushort_as_half((unsigned short)(pv >> 16)));
    ax = fmaf(w, bflo(rv), ax);
    ay = fmaf(w, bfhi(rv), ay);
  }
}

// ---------------- mega segment-mean (drug waves first) ----------------
__global__ __launch_bounds__(256) void k_seg_mega(
    const int* __restrict__ off,
    const int* __restrict__ vmd, const int* __restrict__ vdrug, const int* __restrict__ vhd,
    const unsigned short* __restrict__ xdb, const unsigned short* __restrict__ Ytab,
    unsigned short* __restrict__ m2disb, float* __restrict__ accd, unsigned short* __restrict__ m2ab) {
  int lane = threadIdx.x & 63;
  int lane2 = lane * 2;
  int w = blockIdx.x * 4 + (threadIdx.x >> 6);
  if (w < N_DRUG) {
    int d = w;
    int lo = off[OFF_D + d * 9], hi = off[OFF_D + d * 9 + 9];
    float ax = 0.f, ay = 0.f;
    gacc_w(Ytab, vdrug, lo, hi, lane, ax, ay);
    *(float2*)(accd + (size_t)d * HC + lane2) = make_float2(ax, ay);
  } else if (w < N_DRUG + N_DIS) {
    int d = w - N_DRUG;
    int lo = off[OFF_Z0 + d], hi = off[OFF_Z0 + d + 1];
    float ax = 0.f, ay = 0.f;
    gacc_w(xdb, vmd, lo, hi, lane, ax, ay);
    *(unsigned int*)(m2disb + (size_t)d * HC + lane2) =
        (unsigned int)f2bf(ax) | ((unsigned int)f2bf(ay) << 16);
  } else {
    int idx = w - (N_DRUG + N_DIS);
    int t = idx / N_ATTR, r = idx - t * N_ATTR;
    int lo = off[OFF_Z2(t) + r], hi = off[OFF_Z2(t) + r + 1];
    float ax = 0.f, ay = 0.f;
    gacc_w(xdb, vhd + (size_t)t * E_HA, lo, hi, lane, ax, ay);
    *(unsigned int*)(m2ab + ((size_t)t * N_ATTR + r) * HC + lane2) =
        (unsigned int)f2bf(ax) | ((unsigned int)f2bf(ay) << 16);
  }
}

// ---------------- MFMA GEMM ----------------
struct MJob {
  const unsigned short* X1; const unsigned short* Wt1;
  const unsigned short* X2; const unsigned short* Wt2;
  const float* bias; const float* ACC;
  float* D; unsigned short* D2;
  int M; int leaky; int bf16out;
};
struct MJobs { MJob j[10]; };

__global__ __launch_bounds__(256) void k_gemm_mfma(MJobs jobs) {
  MJob jb = jobs.j[blockIdx.z];
  int m0 = blockIdx.x * 64;
  if (m0 >= jb.M) return;
  int wave = threadIdx.x >> 6;
  int lane = threadIdx.x & 63;
  int l15 = lane & 15, g = lane >> 4;
  int m = m0 + wave * 16 + l15;
  bool mok = m < jb.M;
  int mrow = mok ? m : 0;

  f32x4 acc[8] = {};
  #pragma unroll
  for (int part = 0; part < 2; part++) {
    const unsigned short* X = part ? jb.X2 : jb.X1;
    const unsigned short* Wt = part ? jb.Wt2 : jb.Wt1;
    if (!X) break;
    #pragma unroll
    for (int ks = 0; ks < 4; ks++) {
      int k0 = ks * 32 + g * 8;
      bf16x8 xb = {};
      if (mok) xb = *(const bf16x8*)(X + (size_t)mrow * 128 + k0);
      #pragma unroll
      for (int f = 0; f < 8; f++) {
        bf16x8 wb = *(const bf16x8*)(Wt + (size_t)(f * 16 + l15) * 128 + k0);
        acc[f] = __builtin_amdgcn_mfma_f32_16x16x32_bf16(wb, xb, acc[f], 0, 0, 0);
      }
    }
  }
  if (!mok) return;
  #pragma unroll
  for (int f = 0; f < 8; f++) {
    int n0 = f * 16 + 4 * g;
    float r0 = acc[f][0], r1 = acc[f][1], r2 = acc[f][2], r3 = acc[f][3];
    if (jb.bias) {
      float4 bs = *(const float4*)(jb.bias + n0);
      r0 += bs.x; r1 += bs.y; r2 += bs.z; r3 += bs.w;
    }
    if (jb.ACC) {
      float4 a = *(const float4*)(jb.ACC + (size_t)m * 128 + n0);
      r0 += a.x; r1 += a.y; r2 += a.z; r3 += a.w;
    }
    if (jb.leaky) { r0 = leakyf(r0); r1 = leakyf(r1); r2 = leakyf(r2); r3 = leakyf(r3); }
    if (jb.bf16out) {
      unsigned short* Db = (unsigned short*)jb.D;
      uint2 w;
      w.x = (unsigned int)f2bf(r0) | ((unsigned int)f2bf(r1) << 16);
      w.y = (unsigned int)f2bf(r2) | ((unsigned int)f2bf(r3) << 16);
      *(uint2*)(Db + (size_t)m * 128 + n0) = w;
    } else {
      *(float4*)(jb.D + (size_t)m * 128 + n0) = make_float4(r0, r1, r2, r3);
      if (jb.D2) {
        uint2 w;
        w.x = (unsigned int)f2bf(r0) | ((unsigned int)f2bf(r1) << 16);
        w.y = (unsigned int)f2bf(r2) | ((unsigned int)f2bf(r3) << 16);
        *(uint2*)(jb.D2 + (size_t)m * 128 + n0) = w;
      }
    }
  }
}

// ---------------- classifier head GEMMs (bf16 output for tail) ----------------
struct G64Job { const float* X; const float* W; const float* bias; unsigned short* D; int M; };

__global__ __launch_bounds__(256) void k_gemm64(G64Job j0, G64Job j1) {
  G64Job jb = blockIdx.z ? j1 : j0;
  int m0 = blockIdx.x * 64;
  if (m0 >= jb.M) return;
  __shared__ float As[16][68];
  __shared__ float Bs[16][68];
  int tid = threadIdx.x;
  int tx = tid & 15, ty = tid >> 4;
  float acc[4][4];
  #pragma unroll
  for (int i = 0; i < 4; i++)
    #pragma unroll
    for (int j = 0; j < 4; j++) acc[i][j] = 0.f;

  for (int kk = 0; kk < 128; kk += 16) {
    {
      int r = tid >> 2, kq = (tid & 3) * 4;
      int gr = m0 + r;
      float4 v = make_float4(0.f, 0.f, 0.f, 0.f);
      if (gr < jb.M) v = *(const float4*)(jb.X + (size_t)gr * HC + kk + kq);
      As[kq + 0][r] = v.x; As[kq + 1][r] = v.y; As[kq + 2][r] = v.z; As[kq + 3][r] = v.w;
    }
    {
      int k = tid >> 4, c = (tid & 15) * 4;
      *(float4*)&Bs[k][c] = *(const float4*)(jb.W + (size_t)(kk + k) * 64 + c);
    }
    __syncthreads();
    #pragma unroll
    for (int k = 0; k < 16; k++) {
      float4 a = *(const float4*)&As[k][ty * 4];
      float4 b = *(const float4*)&Bs[k][tx * 4];
      float av[4] = {a.x, a.y, a.z, a.w};
      float bb[4] = {b.x, b.y, b.z, b.w};
      #pragma unroll
      for (int i = 0; i < 4; i++)
        #pragma unroll
        for (int j = 0; j < 4; j++) acc[i][j] += av[i] * bb[j];
    }
    __syncthreads();
  }
  float4 bs = make_float4(0.f, 0.f, 0.f, 0.f);
  if (jb.bias) bs = *(const float4*)(jb.bias + tx * 4);
  #pragma unroll
  for (int i = 0; i < 4; i++) {
    int gr = m0 + ty * 4 + i;
    if (gr < jb.M) {
      uint2 w;
      w.x = (unsigned int)f2bf(acc[i][0] + bs.x) | ((unsigned int)f2bf(acc[i][1] + bs.y) << 16);
      w.y = (unsigned int)f2bf(acc[i][2] + bs.z) | ((unsigned int)f2bf(acc[i][3] + bs.w) << 16);
      *(uint2*)(jb.D + (size_t)gr * 64 + tx * 4) = w;
    }
  }
}

// ---------------- per-edge tail MLP (bf16 U/V rows) ----------------
__global__ __launch_bounds__(256) void k_tail(
    const unsigned short* __restrict__ U, const unsigned short* __restrict__ V,
    const int* __restrict__ es, const int* __restrict__ ed,
    const float* __restrict__ cw1, const float* __restrict__ cb1,
    const float* __restrict__ cw2, const float* __restrict__ cb2,
    const float* __restrict__ cw3, const float* __restrict__ cb3,
    const float* __restrict__ cw4, const float* __restrict__ cb4,
    float* __restrict__ out, int n) {
  __shared__ float w1[64 * 32];
  __shared__ float w2[32 * 16];
  __shared__ float w3[16 * 8];
  __shared__ float w4[8];
  __shared__ float b1[32], b2[16], b3[8];
  int tid = threadIdx.x;
  #pragma unroll
  for (int q = 0; q < 8; q++) w1[tid + q * 256] = cw1[tid + q * 256];
  #pragma unroll
  for (int q = 0; q < 2; q++) w2[tid + q * 256] = cw2[tid + q * 256];
  if (tid < 128) w3[tid] = cw3[tid];
  if (tid < 8)  w4[tid] = cw4[tid];
  if (tid < 32) b1[tid] = cb1[tid];
  if (tid < 16) b2[tid] = cb2[tid];
  if (tid < 8)  b3[tid] = cb3[tid];
  __syncthreads();
  int i = blockIdx.x * 256 + tid;
  if (i >= n) return;
  int s = es[i], d = ed[i];
  const uint4* up = (const uint4*)(U + (size_t)s * 64);
  const uint4* vp = (const uint4*)(V + (size_t)d * 64);
  float h1[64];
  #pragma unroll
  for (int q = 0; q < 8; q++) {
    uint4 a = up[q], b = vp[q];
    h1[8 * q + 0] = leakyf(bflo(a.x) + bflo(b.x));
    h1[8 * q + 1] = leakyf(bfhi(a.x) + bfhi(b.x));
    h1[8 * q + 2] = leakyf(bflo(a.y) + bflo(b.y));
    h1[8 * q + 3] = leakyf(bfhi(a.y) + bfhi(b.y));
    h1[8 * q + 4] = leakyf(bflo(a.z) + bflo(b.z));
    h1[8 * q + 5] = leakyf(bfhi(a.z) + bfhi(b.z));
    h1[8 * q + 6] = leakyf(bflo(a.w) + bflo(b.w));
    h1[8 * q + 7] = leakyf(bfhi(a.w) + bfhi(b.w));
  }
  float h2[32];
  #pragma unroll
  for (int j = 0; j < 32; j++) h2[j] = b1[j];
  #pragma unroll
  for (int k = 0; k < 64; k++) {
    float hv = h1[k];
    #pragma unroll
    for (int jq = 0; jq < 8; jq++) {
      float4 w = *(const float4*)&w1[k * 32 + jq * 4];
      h2[4 * jq + 0] = fmaf(hv, w.x, h2[4 * jq + 0]);
      h2[4 * jq + 1] = fmaf(hv, w.y, h2[4 * jq + 1]);
      h2[4 * jq + 2] = fmaf(hv, w.z, h2[4 * jq + 2]);
      h2[4 * jq + 3] = fmaf(hv, w.w, h2[4 * jq + 3]);
    }
  }
  float h3[16];
  #pragma unroll
  for (int j = 0; j < 16; j++) h3[j] = b2[j];
  #pragma unroll
  for (int k = 0; k < 32; k++) {
    float hv = leakyf(h2[k]);
    #pragma unroll
    for (int jq = 0; jq < 4; jq++) {
      float4 w = *(const float4*)&w2[k * 16 + jq * 4];
      h3[4 * jq + 0] = fmaf(hv, w.x, h3[4 * jq + 0]);
      h3[4 * jq + 1] = fmaf(hv, w.y, h3[4 * jq + 1]);
      h3[4 * jq + 2] = fmaf(hv, w.z, h3[4 * jq + 2]);
      h3[4 * jq + 3] = fmaf(hv, w.w, h3[4 * jq + 3]);
    }
  }
  float h4[8];
  #pragma unroll
  for (int j = 0; j < 8; j++) h4[j] = b3[j];
  #pragma unroll
  for (int k = 0; k < 16; k++) {
    float hv = leakyf(h3[k]);
    #pragma unroll
    for (int jq = 0; jq < 2; jq++) {
      float4 w = *(const float4*)&w3[k * 8 + jq * 4];
      h4[4 * jq + 0] = fmaf(hv, w.x, h4[4 * jq + 0]);
      h4[4 * jq + 1] = fmaf(hv, w.y, h4[4 * jq + 1]);
      h4[4 * jq + 2] = fmaf(hv, w.z, h4[4 * jq + 2]);
      h4[4 * jq + 3] = fmaf(hv, w.w, h4[4 * jq + 3]);
    }
  }
  float p = cb4[0];
  #pragma unroll
  for (int k = 0; k < 8; k++) p = fmaf(leakyf(h4[k]), w4[k], p);
  out[i] = p;
}

extern "C" void kernel_launch(void* const* d_in, const int* in_sizes, int n_in,
                              void* d_out, int out_size, void* d_ws, size_t ws_size,
                              hipStream_t stream) {
  const float* disease_x   = (const float*)d_in[0];
  const float* drug_emb    = (const float*)d_in[1];
  const float* disease_emb = (const float*)d_in[2];
  const float* attr_emb    = (const float*)d_in[3];
  const float* dis_lin_w   = (const float*)d_in[4];
  const float* dis_lin_b   = (const float*)d_in[5];
  const float* mt_wl  = (const float*)d_in[6];
  const float* mt_bl  = (const float*)d_in[7];
  const float* mt_wr  = (const float*)d_in[8];
  const float* rmt_wl = (const float*)d_in[9];
  const float* rmt_bl = (const float*)d_in[10];
  const float* rmt_wr = (const float*)d_in[11];
  const float* ha_wl  = (const float*)d_in[12];
  const float* ha_bl  = (const float*)d_in[13];
  const float* ha_wr  = (const float*)d_in[14];
  const float* rha_wl = (const float*)d_in[15];
  const float* rha_bl = (const float*)d_in[16];
  const float* rha_wr = (const float*)d_in[17];
  const float* cw0 = (const float*)d_in[18];
  const float* cb0 = (const float*)d_in[19];
  const float* cw1 = (const float*)d_in[20];
  const float* cb1 = (const float*)d_in[21];
  const float* cw2 = (const float*)d_in[22];
  const float* cb2 = (const float*)d_in[23];
  const float* cw3 = (const float*)d_in[24];
  const float* cb3 = (const float*)d_in[25];
  const float* cw4 = (const float*)d_in[26];
  const float* cb4 = (const float*)d_in[27];
  const int* mt_src = (const int*)d_in[28];
  const int* mt_dst = (const int*)d_in[29];
  const int* ha_src = (const int*)d_in[30];
  const int* ha_dst = (const int*)d_in[31];
  const int* ell_src = (const int*)d_in[32];
  const int* ell_dst = (const int*)d_in[33];
  float* out = (float*)d_out;

  const long long ATTR_S = (long long)N_ATTR * HC;
  const long long W_S = HC * HC;

  // ---------- workspace carve ----------
  float* fws = (float*)d_ws;
  size_t o = 0;
  float* x_drug = fws + o; o += (size_t)N_DRUG * HC;   // | x_drug+x_dis+x_attr (5.888M floats)
  float* x_dis  = fws + o; o += (size_t)N_DIS * HC;    // | overlaid by hist (5.216M ints)
  float* x_attr = fws + o; o += (size_t)T_ATTR * N_ATTR * HC;
  float* accd   = fws + o; o += (size_t)N_DRUG * HC;
  float* biasc  = fws + o; o += 256;
  unsigned short* Ucls = (unsigned short*)(fws + o); o += (size_t)N_DRUG * 64 / 2;
  unsigned short* Vcls = (unsigned short*)(fws + o); o += (size_t)N_DIS * 64 / 2;
  unsigned short* xdb    = (unsigned short*)(fws + o);
  unsigned short* Ytab   = xdb + (size_t)N_DRUG * HC;
  unsigned short* Ydisb  = Ytab;
  unsigned short* Yattrb = Ytab + (size_t)N_DIS * HC;
  unsigned short* xdisb  = Yattrb + (size_t)T_ATTR * N_ATTR * HC;
  unsigned short* xab    = xdisb + (size_t)N_DIS * HC;
  unsigned short* m2disb = xab + (size_t)T_ATTR * N_ATTR * HC;
  unsigned short* m2ab   = m2disb + (size_t)N_DIS * HC;
  unsigned short* Wts    = m2ab + (size_t)T_ATTR * N_ATTR * HC;  // 54 * 16384
  unsigned short* Wct    = Wts + 54 * 16384;                     // 2 * 16384
  unsigned short* ushort_end = Wct + 2 * 16384;
  o += ((size_t)(ushort_end - xdb) + 1) / 2;
  int* iws = (int*)(fws + o);
  int* off = iws;
  int* vmd   = off + OFF_TOT;
  int* vdrug = vmd + E_MT;
  int* vhd   = vdrug + (E_MT + T_ATTR * E_HA);
  unsigned short* wtab = (unsigned short*)(vhd + (size_t)T_ATTR * E_HA);
  int* csum = (int*)(wtab + WTOT + (WTOT & 1));
  int* hist = (int*)fws;   // 5.216M ints over x_drug..x_attr (dead during CSR build)

  dim3 b256(256);
  // ---------- CSR build (balanced chunking: every block ~6250 edges) ----------
  k_hist<<<dim3(NBMAX, 1, NSS), b256, 0, stream>>>(mt_src, mt_dst, ha_src, ha_dst, hist);
  k_blkpfx<<<dim3((N_DRUG + 255) / 256, 1, 18), b256, 0, stream>>>(hist, off, wtab);
  {
    dim3 sg((180000 + SCH - 1) / SCH, 10);
    k_scan_l1<<<sg, b256, 0, stream>>>(off, csum);
    k_scan_l2<<<10, 64, 0, stream>>>(off, csum);
    k_scan_l3<<<sg, b256, 0, stream>>>(off, csum);
  }
  k_fill2<<<dim3(NBMAX, 1, NSS), b256, 0, stream>>>(mt_src, mt_dst, ha_src, ha_dst, hist, off, wtab,
                                                    vmd, vdrug, vhd);

  // ---------- weights (both layers, batched) ----------
  k_wc<<<dim3(64, 2), b256, 0, stream>>>(rmt_wr, rha_wr, rmt_bl, rha_bl, Wct, biasc);
  {
    WtJobs W{};
    for (int l = 0; l < 2; l++) {
      int base = l * 27;
      W.s[base + 0] = rmt_wl + (size_t)l * W_S;
      for (int t = 0; t < T_ATTR; t++) W.s[base + 1 + t] = rha_wl + (size_t)l * T_ATTR * W_S + (size_t)t * W_S;
      W.s[base + 9] = mt_wl + (size_t)l * W_S;
      W.s[base + 10] = mt_wr + (size_t)l * W_S;
      for (int t = 0; t < T_ATTR; t++) W.s[base + 11 + t] = ha_wl + (size_t)l * T_ATTR * W_S + (size_t)t * W_S;
      for (int t = 0; t < T_ATTR; t++) W.s[base + 19 + t] = ha_wr + (size_t)l * T_ATTR * W_S + (size_t)t * W_S;
    }
    k_wt<<<dim3(4, 4, 54), b256, 0, stream>>>(W, Wts);
  }

  // ---------- node init + initial bf16 copies ----------
  k_dis0<<<N_DIS, 128, 0, stream>>>(disease_x, dis_lin_w, dis_lin_b, disease_emb, x_dis, xdisb);
  k_cvt<<<dim3((N_DRUG * HC / 4 + 255) / 256), b256, 0, stream>>>(drug_emb, xdb, N_DRUG * HC / 4);
  k_cvt<<<dim3((T_ATTR * N_ATTR * HC / 4 + 255) / 256), b256, 0, stream>>>(attr_emb, xab, T_ATTR * N_ATTR * HC / 4);

  for (int l = 0; l < 2; l++) {
    const float* mt_bl_l  = mt_bl  + (size_t)l * HC;
    const float* ha_bl_l  = ha_bl  + (size_t)l * T_ATTR * HC;
    const unsigned short* Wts_l = Wts + (size_t)l * 27 * 16384;
    const unsigned short* Wct_l = Wct + (size_t)l * 16384;
    const float* biasc_l = biasc + (size_t)l * 128;

    // pre-transform GEMMs (MFMA, bf16 out)
    {
      MJobs J{};
      J.j[0] = {xdisb, Wts_l + 0 * 16384, nullptr, nullptr, nullptr, nullptr, (float*)Ydisb, nullptr, N_DIS, 0, 1};
      for (int t = 0; t < T_ATTR; t++)
        J.j[1 + t] = {xab + (size_t)t * ATTR_S, Wts_l + (size_t)(1 + t) * 16384,
                      nullptr, nullptr, nullptr, nullptr,
                      (float*)(Yattrb + (size_t)t * ATTR_S), nullptr, N_ATTR, 0, 1};
      k_gemm_mfma<<<dim3((N_DIS + 63) / 64, 1, 9), b256, 0, stream>>>(J);
    }

    // gathers
    k_seg_mega<<<dim3((46000 + 3) / 4, 1, 1), b256, 0, stream>>>(
        off, vmd, vdrug, vhd, xdb, Ytab, m2disb, accd, m2ab);

    // combine GEMMs (MFMA, f32 + dual bf16 out)
    {
      MJobs J{};
      J.j[0] = {xdb, Wct_l, nullptr, nullptr, biasc_l, accd, x_drug, xdb, N_DRUG, 1, 0};
      J.j[1] = {m2disb, Wts_l + 9 * 16384, xdisb, Wts_l + 10 * 16384, mt_bl_l, nullptr, x_dis, xdisb, N_DIS, 1, 0};
      for (int t = 0; t < T_ATTR; t++)
        J.j[2 + t] = {m2ab + (size_t)t * ATTR_S, Wts_l + (size_t)(11 + t) * 16384,
                      xab + (size_t)t * ATTR_S, Wts_l + (size_t)(19 + t) * 16384,
                      ha_bl_l + (size_t)t * HC, nullptr, x_attr + (size_t)t * ATTR_S,
                      xab + (size_t)t * ATTR_S, N_ATTR, 1, 0};
      k_gemm_mfma<<<dim3((N_DRUG + 63) / 64, 1, 10), b256, 0, stream>>>(J);
    }
  }

  // ---------- classifier ----------
  {
    G64Job ju = {x_drug, cw0, cb0, Ucls, N_DRUG};
    G64Job jv = {x_dis, cw0 + 128 * 64, nullptr, Vcls, N_DIS};
    k_gemm64<<<dim3((N_DRUG + 63) / 64, 1, 2), b256, 0, stream>>>(ju, jv);
    k_tail<<<dim3((E_LBL + 255) / 256, 1, 1), b256, 0, stream>>>(
        Ucls, Vcls, ell_src, ell_dst,
        cw1, cb1, cw2, cb2, cw3, cb3, cw4, cb4, out, E_LBL);
  }
}